// Round 13
// baseline (462.660 us; speedup 1.0000x reference)
//
#include <hip/hip_runtime.h>
#include <hip/hip_bf16.h>

#define LSEQ 318
#define NBATCH 128
#define NE (NBATCH * LSEQ)
#define FC1K 35616
#define NKBLK 224   // 224 * 159 == 35616
#define KCH 159
#define NSLOT 32
#define SLOTW 256   // floats per slot row

typedef __attribute__((ext_vector_type(4))) float f32x4;
typedef __attribute__((ext_vector_type(8))) short bf16x8;
typedef __attribute__((ext_vector_type(4))) unsigned int u32x4;

__device__ inline unsigned short f2bf(float v) {
  unsigned int a = __builtin_bit_cast(unsigned int, v);
  return (unsigned short)((a + 0x7FFFu + ((a >> 16) & 1u)) >> 16);
}
__device__ inline float bf2f(unsigned short u) {
  unsigned int a = ((unsigned int)u) << 16;
  return __builtin_bit_cast(float, a);
}
__device__ inline unsigned int packbf2(float lo, float hi) {
  return (unsigned int)f2bf(lo) | ((unsigned int)f2bf(hi) << 16);
}
__device__ inline bf16x8 ldfrag(const unsigned int* xb, int j0) {
  u32x4 uu = {xb[j0], xb[j0 + 1], xb[j0 + 2], xb[j0 + 3]};
  return __builtin_bit_cast(bf16x8, uu);
}

// per-channel affine from NSLOT partial stats: sum over slots, then
// scale=g*rsqrt(var+eps), shift=b-m*scale
__device__ inline void load_affine16(const float* pstat, const float* g, const float* b,
                                     float* sc, float* sh, int C) {
  for (int c = threadIdx.x; c < C; c += blockDim.x) {
    if (pstat) {
      float s1 = 0.f, s2 = 0.f;
#pragma unroll
      for (int s = 0; s < NSLOT; ++s) {
        s1 += pstat[s * SLOTW + 2 * c];
        s2 += pstat[s * SLOTW + 2 * c + 1];
      }
      float m = s1 * (1.f / NE);
      float var = s2 * (1.f / NE) - m * m;
      float sv = g[c] * rsqrtf(var + 1e-5f);
      sc[c] = sv; sh[c] = b[c] - m * sv;
    } else { sc[c] = 1.f; sh[c] = 0.f; }
  }
}

// ---------------------------------------------------------------------------
// Stem (round-8 VERIFIED math): conv1d + b0 + maxpool16 -> P0 [n][l][16]
// channels-last + slot stats. Rolling rings, p<10, reload p<9.
// ---------------------------------------------------------------------------
__global__ __launch_bounds__(256) void stem_mfma(
    const float* __restrict__ x, const float* __restrict__ w,
    const float* __restrict__ b0, float* __restrict__ pre,
    float* __restrict__ pstat)
{
  __shared__ __align__(16) unsigned short wsh[16 * 1736];
  __shared__ __align__(16) unsigned int xs2[2 * 1520];
  int t = threadIdx.x;
  int pblk = blockIdx.x, n = blockIdx.y;
  int P0 = pblk * 1280;

  for (int e = t; e < 16 * 868; e += 256) {
    int co = e / 868, kd = e - co * 868;
    int k = kd * 2;
    float v0 = (k < 1700) ? w[co * 1700 + k] : 0.f;
    float v1 = (k + 1 < 1700) ? w[co * 1700 + k + 1] : 0.f;
    ((unsigned int*)wsh)[e] = packbf2(v0, v1);
  }
  const float* xn = x + (size_t)n * 5087;
  for (int i = t; i < 1520; i += 256) {
    int m = 2 * i;
    int g0 = P0 - 850 + m;
    float v0 = (g0 >= 0 && g0 < 5087) ? xn[g0] : 0.f;
    float v1 = (g0 + 1 >= 0 && g0 + 1 < 5087) ? xn[g0 + 1] : 0.f;
    float v2 = (g0 + 2 >= 0 && g0 + 2 < 5087) ? xn[g0 + 2] : 0.f;
    xs2[i] = packbf2(v0, v1);
    xs2[1520 + i] = packbf2(v1, v2);
  }
  __syncthreads();

  int wv = t >> 6, lane = t & 63;
  int row = lane & 15, grp = lane >> 4;
  int tb = wv * 20;
  const unsigned int* xb = xs2 + (row & 1) * 1520;
  int eb0 = 16 * tb + row + 8 * grp;

  f32x4 acc[20];
#pragma unroll
  for (int i = 0; i < 20; ++i) acc[i] = (f32x4){0.f, 0.f, 0.f, 0.f};

  for (int kg = 0; kg < 6; ++kg) {
    bf16x8 bf[9];
#pragma unroll
    for (int c = 0; c < 9; ++c)
      bf[c] = *reinterpret_cast<const bf16x8*>(&wsh[row * 1736 + kg * 288 + c * 32 + grp * 8]);
    int eb = eb0 + 288 * kg;
    bf16x8 re[9], ro[9];
#pragma unroll
    for (int c = 0; c < 9; ++c) {
      re[c] = ldfrag(xb, (eb + 32 * c) >> 1);
      ro[c] = ldfrag(xb, (eb + 16 + 32 * c) >> 1);
    }
#pragma unroll
    for (int p = 0; p < 10; ++p) {
#pragma unroll
      for (int c = 0; c < 9; ++c)
        acc[2 * p] = __builtin_amdgcn_mfma_f32_16x16x32_bf16(re[c], bf[c], acc[2 * p], 0, 0, 0);
#pragma unroll
      for (int c = 0; c < 9; ++c)
        acc[2 * p + 1] = __builtin_amdgcn_mfma_f32_16x16x32_bf16(ro[c], bf[c], acc[2 * p + 1], 0, 0, 0);
      if (p < 9) {
#pragma unroll
        for (int c = 0; c < 8; ++c) { re[c] = re[c + 1]; ro[c] = ro[c + 1]; }
        re[8] = ldfrag(xb, (eb + 32 * p + 288) >> 1);
        ro[8] = ldfrag(xb, (eb + 32 * p + 304) >> 1);
      }
    }
  }

  float b0v = b0[row];
  float ssum = 0.f, ssq = 0.f;
#pragma unroll
  for (int mt = 0; mt < 20; ++mt) {
    int q = pblk * 80 + tb + mt;
    f32x4 d = acc[mt];
    float m = fmaxf(fmaxf(d[0], d[1]), fmaxf(d[2], d[3]));
    m = fmaxf(m, __shfl_xor(m, 16));
    m = fmaxf(m, __shfl_xor(m, 32));
    if (lane < 16 && q < LSEQ) {
      float val = m + b0v;
      pre[((size_t)n * LSEQ + q) * 16 + lane] = val;
      ssum += val; ssq += val * val;
    }
  }
  if (lane < 16) {
    float* slot = pstat + (n & (NSLOT - 1)) * SLOTW;
    atomicAdd(&slot[2 * lane], ssum);
    atomicAdd(&slot[2 * lane + 1], ssq);
  }
}

// ---------------------------------------------------------------------------
// ista_stage (round-8 verified; MODE 0 only), slot stats.
// ---------------------------------------------------------------------------
template <int CIN, int MODE>
__global__ __launch_bounds__(256) void ista_stage(
    const float* __restrict__ t2,
    const float* __restrict__ fiP, const float* __restrict__ fiStats,
    const float* __restrict__ fiG, const float* __restrict__ fiB, int fiRelu,
    const float* __restrict__ fi1P, const float* __restrict__ fi1Stats,
    const float* __restrict__ fi1G, const float* __restrict__ fi1B, int fi1Relu,
    const float* __restrict__ F, const float* __restrict__ cs,
    const float* __restrict__ bv,
    float* __restrict__ P, float* __restrict__ statsOut)
{
  const int CT = CIN + 32;
  const int K3 = 3 * CIN;
  const int KPAD = ((K3 + 31) / 32) * 32;
  const int KROWP = KPAD + (((KPAD / 8) % 2 == 0) ? 8 : 0);
  const int CINP = CIN + (((CIN / 8) % 2 == 0) ? 8 : 0);
  const int TS = 128, ROWS = TS + 3;
  const int KSTEPS = KPAD / 32;

  __shared__ __align__(16) unsigned short sW[32 * KROWP];
  __shared__ __align__(16) unsigned short sS[ROWS * CINP];
  __shared__ float scF[CIN], shF[CIN];
  __shared__ float sc1[CT], sh1[CT], sbv[CT];
  __shared__ float lstat[2 * CT];

  int t = threadIdx.x;
  int l0 = blockIdx.x * TS, n = blockIdx.y;

  load_affine16(fiStats, fiG, fiB, scF, shF, CIN);
  load_affine16(fi1Stats, fi1G, fi1B, sc1, sh1, CT);
  for (int c = t; c < CT; c += 256) sbv[c] = bv[c];
  for (int c = t; c < 2 * CT; c += 256) lstat[c] = 0.f;
  __syncthreads();

  for (int e = t; e < 32 * (KPAD / 8); e += 256) {
    int co = e / (KPAD / 8), kc = (e - co * (KPAD / 8)) * 8;
    int dt = kc / CIN, ci = kc - dt * CIN;
    bf16x8 v;
    if (dt < 3) {
#pragma unroll
      for (int jj = 0; jj < 8; ++jj)
        v[jj] = (short)f2bf(F[((size_t)co * CIN + ci + jj) * 3 + dt]);
    } else {
#pragma unroll
      for (int jj = 0; jj < 8; ++jj) v[jj] = 0;
    }
    *reinterpret_cast<bf16x8*>(&sW[co * KROWP + kc]) = v;
  }
  const float* fib = fiP + (size_t)n * LSEQ * CIN;
  const float* t2b = MODE ? (t2 + (size_t)n * LSEQ * CIN) : nullptr;
  const int NCH8 = CIN / 8;
  for (int e = t; e < ROWS * NCH8; e += 256) {
    int r = e / NCH8, c8 = (e - r * NCH8) * 8;
    int gl = l0 - 1 + r;
    bf16x8 v;
    if (gl >= 0 && gl < LSEQ) {
      const float* p = fib + (size_t)gl * CIN + c8;
#pragma unroll
      for (int jj = 0; jj < 8; ++jj) {
        float f = scF[c8 + jj] * p[jj] + shF[c8 + jj];
        if (fiRelu) f = fmaxf(f, 0.f);
        if (MODE) f = t2b[(size_t)gl * CIN + c8 + jj] - f;
        v[jj] = (short)f2bf(f);
      }
    } else {
#pragma unroll
      for (int jj = 0; jj < 8; ++jj) v[jj] = 0;
    }
    *reinterpret_cast<bf16x8*>(&sS[r * CINP + c8]) = v;
  }
  __syncthreads();

  int wv = t >> 6, lane = t & 63, col = lane & 15, grp = lane >> 4;
  float cV = cs[0];

  bf16x8 a[2][KSTEPS];
#pragma unroll
  for (int m = 0; m < 2; ++m)
#pragma unroll
    for (int ks = 0; ks < KSTEPS; ++ks)
      a[m][ks] = *reinterpret_cast<const bf16x8*>(&sW[(m * 16 + col) * KROWP + ks * 32 + grp * 8]);

  f32x4 acc[2][2];
#pragma unroll
  for (int m = 0; m < 2; ++m)
#pragma unroll
    for (int nf = 0; nf < 2; ++nf) acc[m][nf] = (f32x4){0.f, 0.f, 0.f, 0.f};

#pragma unroll
  for (int ks = 0; ks < KSTEPS; ++ks) {
    int kkb = ks * 32 + grp * 8;
    int dt = kkb / CIN, ci = kkb - dt * CIN;
#pragma unroll
    for (int nf = 0; nf < 2; ++nf) {
      int row = wv * 32 + nf * 16 + col + dt;
      bf16x8 bfrag = *reinterpret_cast<const bf16x8*>(&sS[row * CINP + ci]);
      acc[0][nf] = __builtin_amdgcn_mfma_f32_16x16x32_bf16(a[0][ks], bfrag, acc[0][nf], 0, 0, 0);
      acc[1][nf] = __builtin_amdgcn_mfma_f32_16x16x32_bf16(a[1][ks], bfrag, acc[1][nf], 0, 0, 0);
    }
  }

  const float* fi1b = fi1P ? (fi1P + (size_t)n * LSEQ * CT) : nullptr;
  float* Pb = P + (size_t)n * LSEQ * CT;
  float ts1[2][4], ts2[2][4];
#pragma unroll
  for (int m = 0; m < 2; ++m)
#pragma unroll
    for (int i = 0; i < 4; ++i) { ts1[m][i] = 0.f; ts2[m][i] = 0.f; }

#pragma unroll
  for (int nf = 0; nf < 2; ++nf) {
    int siteL = wv * 32 + nf * 16 + col;
    int gl = l0 + siteL;
    bool valid = (gl < LSEQ);
#pragma unroll
    for (int m = 0; m < 2; ++m) {
      int ch0 = CIN + m * 16 + grp * 4;
      f32x4 f1v = {0.f, 0.f, 0.f, 0.f};
      if (MODE && valid) {
        f1v = *reinterpret_cast<const f32x4*>(&fi1b[(size_t)gl * CT + ch0]);
#pragma unroll
        for (int i = 0; i < 4; ++i) {
          float f = sc1[ch0 + i] * f1v[i] + sh1[ch0 + i];
          if (fi1Relu) f = fmaxf(f, 0.f);
          f1v[i] = f;
        }
      }
      f32x4 pre4;
#pragma unroll
      for (int i = 0; i < 4; ++i) {
        float pv = MODE ? (f1v[i] - cV * acc[m][nf][i] + sbv[ch0 + i])
                        : (cV * acc[m][nf][i] + sbv[ch0 + i]);
        pre4[i] = pv;
        if (valid) { ts1[m][i] += pv; ts2[m][i] += pv * pv; }
      }
      if (valid) *reinterpret_cast<f32x4*>(&Pb[(size_t)gl * CT + ch0]) = pre4;
    }
  }
#pragma unroll
  for (int m = 0; m < 2; ++m)
#pragma unroll
    for (int i = 0; i < 4; ++i) {
      float s1 = ts1[m][i], s2 = ts2[m][i];
      s1 += __shfl_xor(s1, 1); s2 += __shfl_xor(s2, 1);
      s1 += __shfl_xor(s1, 2); s2 += __shfl_xor(s2, 2);
      s1 += __shfl_xor(s1, 4); s2 += __shfl_xor(s2, 4);
      s1 += __shfl_xor(s1, 8); s2 += __shfl_xor(s2, 8);
      if (col == 0) {
        int ch = CIN + m * 16 + grp * 4 + i;
        atomicAdd(&lstat[2 * ch], s1);
        atomicAdd(&lstat[2 * ch + 1], s2);
      }
    }

  {
    const int Q = CIN / 4;
    const int SPT = 256 / Q;
    int quad = t % Q, srow = t / Q;
    if (srow < SPT) {
      int c0 = quad * 4;
      float hb1[4] = {0.f, 0.f, 0.f, 0.f}, hb2[4] = {0.f, 0.f, 0.f, 0.f};
      for (int site = srow; site < TS; site += SPT) {
        int gl = l0 + site;
        if (gl >= LSEQ) break;
        float sv[4];
#pragma unroll
        for (int j = 0; j < 4; ++j) sv[j] = bf2f((unsigned short)sS[(site + 1) * CINP + c0 + j]);
        f32x4 pr;
        if (MODE) {
          f32x4 f1 = *reinterpret_cast<const f32x4*>(&fi1b[(size_t)gl * CT + c0]);
#pragma unroll
          for (int j = 0; j < 4; ++j) {
            float f = sc1[c0 + j] * f1[j] + sh1[c0 + j];
            if (fi1Relu) f = fmaxf(f, 0.f);
            pr[j] = f - cV * sv[j] + sbv[c0 + j];
          }
        } else {
#pragma unroll
          for (int j = 0; j < 4; ++j) pr[j] = cV * sv[j] + sbv[c0 + j];
        }
        *reinterpret_cast<f32x4*>(&Pb[(size_t)gl * CT + c0]) = pr;
#pragma unroll
        for (int j = 0; j < 4; ++j) { hb1[j] += pr[j]; hb2[j] += pr[j] * pr[j]; }
      }
#pragma unroll
      for (int j = 0; j < 4; ++j) {
        atomicAdd(&lstat[2 * (c0 + j)], hb1[j]);
        atomicAdd(&lstat[2 * (c0 + j) + 1], hb2[j]);
      }
    }
  }
  __syncthreads();
  float* slot = statsOut + (n & (NSLOT - 1)) * SLOTW;
  for (int ch = t; ch < CT; ch += 256) {
    atomicAdd(&slot[2 * ch], lstat[2 * ch]);
    atomicAdd(&slot[2 * ch + 1], lstat[2 * ch + 1]);
  }
}

// ---------------------------------------------------------------------------
// bwd_fused (verified): R2 = convT80(act(f3)); R1 = convT48(R2). Slot affine.
// ---------------------------------------------------------------------------
__global__ __launch_bounds__(256) void bwd_fused(
    const float* __restrict__ f3P, const float* __restrict__ st3,
    const float* __restrict__ g3, const float* __restrict__ b3,
    const float* __restrict__ F2, const float* __restrict__ F1,
    float* __restrict__ R2, float* __restrict__ R1)
{
  __shared__ __align__(16) unsigned short X3[130 * 40];
  __shared__ __align__(16) unsigned short sW2[80 * 104];
  __shared__ __align__(16) unsigned short sW1[48 * 104];
  __shared__ __align__(16) unsigned short R2t[130 * 40];
  __shared__ __align__(16) float R2h[128 * 52];
  __shared__ float sc3[112], sh3[112];
  int t = threadIdx.x;
  int l0 = blockIdx.x * 126, n = blockIdx.y;
  load_affine16(st3, g3, b3, sc3, sh3, 112);
  __syncthreads();

  const float* f3b = f3P + (size_t)n * LSEQ * 112;
  for (int e = t; e < 130 * 4; e += 256) {
    int r = e >> 2, c8 = (e & 3) * 8;
    int gl = l0 - 2 + r;
    bf16x8 v;
    if (gl >= 0 && gl < LSEQ) {
      const float* p = f3b + (size_t)gl * 112 + 80 + c8;
#pragma unroll
      for (int jj = 0; jj < 8; ++jj)
        v[jj] = (short)f2bf(fmaxf(sc3[80 + c8 + jj] * p[jj] + sh3[80 + c8 + jj], 0.f));
    } else {
#pragma unroll
      for (int jj = 0; jj < 8; ++jj) v[jj] = 0;
    }
    *reinterpret_cast<bf16x8*>(&X3[r * 40 + c8]) = v;
  }
  for (int e = t; e < 80 * 12; e += 256) {
    int co = e / 12, kc = (e - co * 12) * 8;
    int dt = kc >> 5, j0 = kc & 31;
    bf16x8 v;
#pragma unroll
    for (int jj = 0; jj < 8; ++jj)
      v[jj] = (short)f2bf(F2[((size_t)(j0 + jj) * 80 + co) * 3 + (2 - dt)]);
    *reinterpret_cast<bf16x8*>(&sW2[co * 104 + kc]) = v;
  }
  for (int e = t; e < 48 * 12; e += 256) {
    int co = e / 12, kc = (e - co * 12) * 8;
    int dt = kc >> 5, j0 = kc & 31;
    bf16x8 v;
#pragma unroll
    for (int jj = 0; jj < 8; ++jj)
      v[jj] = (short)f2bf(F1[((size_t)(j0 + jj) * 48 + co) * 3 + (2 - dt)]);
    *reinterpret_cast<bf16x8*>(&sW1[co * 104 + kc]) = v;
  }
  if (t < 10) {
    int r = 128 + t / 5, c8 = (t % 5) * 8;
    bf16x8 z;
#pragma unroll
    for (int jj = 0; jj < 8; ++jj) z[jj] = 0;
    *reinterpret_cast<bf16x8*>(&R2t[r * 40 + c8]) = z;
  }
  __syncthreads();

  int wv = t >> 6, lane = t & 63, col = lane & 15, grp = lane >> 4;
  f32x4 acc2[5][2];
#pragma unroll
  for (int m = 0; m < 5; ++m)
#pragma unroll
    for (int nf = 0; nf < 2; ++nf) acc2[m][nf] = (f32x4){0.f, 0.f, 0.f, 0.f};
#pragma unroll
  for (int ks = 0; ks < 3; ++ks) {
    bf16x8 bA = *reinterpret_cast<const bf16x8*>(&X3[(wv * 32 + col + ks) * 40 + grp * 8]);
    bf16x8 bB = *reinterpret_cast<const bf16x8*>(&X3[(wv * 32 + 16 + col + ks) * 40 + grp * 8]);
#pragma unroll
    for (int m = 0; m < 5; ++m) {
      bf16x8 af = *reinterpret_cast<const bf16x8*>(&sW2[(m * 16 + col) * 104 + ks * 32 + grp * 8]);
      acc2[m][0] = __builtin_amdgcn_mfma_f32_16x16x32_bf16(af, bA, acc2[m][0], 0, 0, 0);
      acc2[m][1] = __builtin_amdgcn_mfma_f32_16x16x32_bf16(af, bB, acc2[m][1], 0, 0, 0);
    }
  }
#pragma unroll
  for (int nf = 0; nf < 2; ++nf) {
    int sr = wv * 32 + nf * 16 + col;
    int gl = l0 - 1 + sr;
    bool v = (gl >= 0 && gl < LSEQ);
#pragma unroll
    for (int m = 0; m < 5; ++m) {
      int c0 = m * 16 + grp * 4;
      f32x4 o = {0.f, 0.f, 0.f, 0.f};
      if (v) {
        f32x4 hv = *reinterpret_cast<const f32x4*>(&f3b[(size_t)gl * 112 + c0]);
#pragma unroll
        for (int i = 0; i < 4; ++i)
          o[i] = fmaxf(sc3[c0 + i] * hv[i] + sh3[c0 + i], 0.f) + acc2[m][nf][i];
        *reinterpret_cast<f32x4*>(&R2[((size_t)n * LSEQ + gl) * 80 + c0]) = o;
      }
      if (c0 < 48) {
        *reinterpret_cast<f32x4*>(&R2h[sr * 52 + c0]) = o;
      } else {
        int j = c0 - 48;
        *reinterpret_cast<unsigned int*>(&R2t[sr * 40 + j]) = packbf2(o[0], o[1]);
        *reinterpret_cast<unsigned int*>(&R2t[sr * 40 + j + 2]) = packbf2(o[2], o[3]);
      }
    }
  }
  __syncthreads();

  f32x4 acc1[3][2];
#pragma unroll
  for (int m = 0; m < 3; ++m)
#pragma unroll
    for (int nf = 0; nf < 2; ++nf) acc1[m][nf] = (f32x4){0.f, 0.f, 0.f, 0.f};
#pragma unroll
  for (int ks = 0; ks < 3; ++ks) {
    bf16x8 bA = *reinterpret_cast<const bf16x8*>(&R2t[(wv * 32 + col + ks) * 40 + grp * 8]);
    bf16x8 bB = *reinterpret_cast<const bf16x8*>(&R2t[(wv * 32 + 16 + col + ks) * 40 + grp * 8]);
#pragma unroll
    for (int m = 0; m < 3; ++m) {
      bf16x8 af = *reinterpret_cast<const bf16x8*>(&sW1[(m * 16 + col) * 104 + ks * 32 + grp * 8]);
      acc1[m][0] = __builtin_amdgcn_mfma_f32_16x16x32_bf16(af, bA, acc1[m][0], 0, 0, 0);
      acc1[m][1] = __builtin_amdgcn_mfma_f32_16x16x32_bf16(af, bB, acc1[m][1], 0, 0, 0);
    }
  }
#pragma unroll
  for (int nf = 0; nf < 2; ++nf) {
    int osr = wv * 32 + nf * 16 + col;
    int gl = l0 + osr;
    if (osr < 126 && gl < LSEQ) {
#pragma unroll
      for (int m = 0; m < 3; ++m) {
        int c0 = m * 16 + grp * 4;
        f32x4 h = *reinterpret_cast<const f32x4*>(&R2h[(osr + 1) * 52 + c0]);
        f32x4 o;
#pragma unroll
        for (int i = 0; i < 4; ++i) o[i] = h[i] + acc1[m][nf][i];
        *reinterpret_cast<f32x4*>(&R1[((size_t)n * LSEQ + gl) * 48 + c0]) = o;
      }
    }
  }
}

// ---------------------------------------------------------------------------
// fwd_fused (round-11 verified TS=62, 128-thread, sWT/sWC LDS union):
// t2 = convT(act1(fi1)) in-LDS; s = t2 - actP(fPrev);
// pre = act1(fi1) - c*[s; conv(s)] + bv; write P + slot stats. grid (6,128).
// ---------------------------------------------------------------------------
template <int CIN>
__global__ __launch_bounds__(128) void fwd_fused(
    const float* __restrict__ fi1P, const float* __restrict__ fi1S,
    const float* __restrict__ fi1G, const float* __restrict__ fi1B, int fi1Relu,
    const float* __restrict__ fPP, const float* __restrict__ fPS,
    const float* __restrict__ fPG, const float* __restrict__ fPB, int fPRelu,
    const float* __restrict__ F, const float* __restrict__ cs,
    const float* __restrict__ bv,
    float* __restrict__ P, float* __restrict__ statsOut)
{
  const int CT = CIN + 32;
  const int K3 = 3 * CIN;
  const int KPAD = ((K3 + 31) / 32) * 32;
  const int KROWP = KPAD + (((KPAD / 8) % 2 == 0) ? 8 : 0);
  const int CINP = CIN + (((CIN / 8) % 2 == 0) ? 8 : 0);
  const int KSTEPS = KPAD / 32;
  const int MFT = CIN / 16;
  const int TS = 62;
  const int WSIZE = (CIN * 104 > 32 * KROWP) ? CIN * 104 : 32 * KROWP;

  __shared__ __align__(16) unsigned short X1[66 * 40];
  __shared__ __align__(16) unsigned short sS[67 * CINP];
  __shared__ __align__(16) unsigned short sWU[WSIZE];  // sWT then sWC
  __shared__ float scP[CIN], shP[CIN];
  __shared__ float sc1[CT], sh1[CT], sbv[CT];
  __shared__ float lstat[2 * CT];

  int t = threadIdx.x;
  int l0 = blockIdx.x * TS, n = blockIdx.y;

  load_affine16(fPS, fPG, fPB, scP, shP, CIN);
  load_affine16(fi1S, fi1G, fi1B, sc1, sh1, CT);
  for (int c = t; c < CT; c += 128) sbv[c] = bv[c];
  for (int c = t; c < 2 * CT; c += 128) lstat[c] = 0.f;

  const float* fi1b = fi1P + (size_t)n * LSEQ * CT;
  const float* fPb = fPP + (size_t)n * LSEQ * CIN;
  for (int e = t; e < 66 * 4; e += 128) {
    int r = e >> 2, c8 = (e & 3) * 8;
    int gl = l0 - 2 + r;
    bf16x8 v;
    if (gl >= 0 && gl < LSEQ) {
      const float* p = fi1b + (size_t)gl * CT + CIN + c8;
#pragma unroll
      for (int jj = 0; jj < 8; ++jj) {
        float f = sc1[CIN + c8 + jj] * p[jj] + sh1[CIN + c8 + jj];
        if (fi1Relu) f = fmaxf(f, 0.f);
        v[jj] = (short)f2bf(f);
      }
    } else {
#pragma unroll
      for (int jj = 0; jj < 8; ++jj) v[jj] = 0;
    }
    *reinterpret_cast<bf16x8*>(&X1[r * 40 + c8]) = v;
  }
  for (int e = t; e < CIN * 12; e += 128) {
    int co = e / 12, kc = (e - co * 12) * 8;
    int dt = kc >> 5, j0 = kc & 31;
    bf16x8 v;
#pragma unroll
    for (int jj = 0; jj < 8; ++jj)
      v[jj] = (short)f2bf(F[((size_t)(j0 + jj) * CIN + co) * 3 + (2 - dt)]);
    *reinterpret_cast<bf16x8*>(&sWU[co * 104 + kc]) = v;
  }
  __syncthreads();

  int wv = t >> 6, lane = t & 63, col = lane & 15, grp = lane >> 4;
  float cV = cs[0];

  // phase 2: convT -> s (sS rows 0..63, gl = l0-1+sr)
  {
    f32x4 accT[MFT][2];
#pragma unroll
    for (int m = 0; m < MFT; ++m)
#pragma unroll
      for (int nf = 0; nf < 2; ++nf) accT[m][nf] = (f32x4){0.f, 0.f, 0.f, 0.f};
#pragma unroll
    for (int ks = 0; ks < 3; ++ks) {
      bf16x8 bA = *reinterpret_cast<const bf16x8*>(&X1[(wv * 32 + col + ks) * 40 + grp * 8]);
      bf16x8 bB = *reinterpret_cast<const bf16x8*>(&X1[(wv * 32 + 16 + col + ks) * 40 + grp * 8]);
#pragma unroll
      for (int m = 0; m < MFT; ++m) {
        bf16x8 af = *reinterpret_cast<const bf16x8*>(&sWU[(m * 16 + col) * 104 + ks * 32 + grp * 8]);
        accT[m][0] = __builtin_amdgcn_mfma_f32_16x16x32_bf16(af, bA, accT[m][0], 0, 0, 0);
        accT[m][1] = __builtin_amdgcn_mfma_f32_16x16x32_bf16(af, bB, accT[m][1], 0, 0, 0);
      }
    }
#pragma unroll
    for (int nf = 0; nf < 2; ++nf) {
      int sr = wv * 32 + nf * 16 + col;   // 0..63
      int gl = l0 - 1 + sr;
      bool v = (gl >= 0 && gl < LSEQ);
#pragma unroll
      for (int m = 0; m < MFT; ++m) {
        int c0 = m * 16 + grp * 4;
        f32x4 sv = {0.f, 0.f, 0.f, 0.f};
        if (v) {
          f32x4 base = *reinterpret_cast<const f32x4*>(&fi1b[(size_t)gl * CT + c0]);
          f32x4 pv = *reinterpret_cast<const f32x4*>(&fPb[(size_t)gl * CIN + c0]);
#pragma unroll
          for (int i = 0; i < 4; ++i) {
            float tbv = sc1[c0 + i] * base[i] + sh1[c0 + i];
            if (fi1Relu) tbv = fmaxf(tbv, 0.f);
            float t2v = tbv + accT[m][nf][i];
            float fp = scP[c0 + i] * pv[i] + shP[c0 + i];
            if (fPRelu) fp = fmaxf(fp, 0.f);
            sv[i] = t2v - fp;
          }
        }
        *reinterpret_cast<unsigned int*>(&sS[sr * CINP + c0]) = packbf2(sv[0], sv[1]);
        *reinterpret_cast<unsigned int*>(&sS[sr * CINP + c0 + 2]) = packbf2(sv[2], sv[3]);
      }
    }
  }
  __syncthreads();

  // stage sWC (conv weights) into sWU (sWT dead) + zero pad rows 64..66
  for (int e = t; e < 32 * (KPAD / 8); e += 128) {
    int co = e / (KPAD / 8), kc = (e - co * (KPAD / 8)) * 8;
    int dt = kc / CIN, ci = kc - dt * CIN;
    bf16x8 v;
    if (dt < 3) {
#pragma unroll
      for (int jj = 0; jj < 8; ++jj)
        v[jj] = (short)f2bf(F[((size_t)co * CIN + ci + jj) * 3 + dt]);
    } else {
#pragma unroll
      for (int jj = 0; jj < 8; ++jj) v[jj] = 0;
    }
    *reinterpret_cast<bf16x8*>(&sWU[co * KROWP + kc]) = v;
  }
  for (int e = t; e < 3 * (CINP / 8); e += 128) {
    int r = 64 + e / (CINP / 8), c8 = (e % (CINP / 8)) * 8;
    bf16x8 z;
#pragma unroll
    for (int jj = 0; jj < 8; ++jj) z[jj] = 0;
    *reinterpret_cast<bf16x8*>(&sS[r * CINP + c8]) = z;
  }
  __syncthreads();

  // phase 3: conv(s) + epilogue (tail)
  bf16x8 aW[2][KSTEPS];
#pragma unroll
  for (int m = 0; m < 2; ++m)
#pragma unroll
    for (int ks = 0; ks < KSTEPS; ++ks)
      aW[m][ks] = *reinterpret_cast<const bf16x8*>(&sWU[(m * 16 + col) * KROWP + ks * 32 + grp * 8]);

  f32x4 accC[2][2];
#pragma unroll
  for (int m = 0; m < 2; ++m)
#pragma unroll
    for (int nf = 0; nf < 2; ++nf) accC[m][nf] = (f32x4){0.f, 0.f, 0.f, 0.f};
#pragma unroll
  for (int ks = 0; ks < KSTEPS; ++ks) {
    int kkb = ks * 32 + grp * 8;
    int dt = kkb / CIN, ci = kkb - dt * CIN;
#pragma unroll
    for (int nf = 0; nf < 2; ++nf) {
      int row = wv * 32 + nf * 16 + col + dt;  // <= 66
      bf16x8 bfrag = *reinterpret_cast<const bf16x8*>(&sS[row * CINP + ci]);
      accC[0][nf] = __builtin_amdgcn_mfma_f32_16x16x32_bf16(aW[0][ks], bfrag, accC[0][nf], 0, 0, 0);
      accC[1][nf] = __builtin_amdgcn_mfma_f32_16x16x32_bf16(aW[1][ks], bfrag, accC[1][nf], 0, 0, 0);
    }
  }

  float* Pb = P + (size_t)n * LSEQ * CT;
  float ts1[2][4], ts2[2][4];
#pragma unroll
  for (int m = 0; m < 2; ++m)
#pragma unroll
    for (int i = 0; i < 4; ++i) { ts1[m][i] = 0.f; ts2[m][i] = 0.f; }

#pragma unroll
  for (int nf = 0; nf < 2; ++nf) {
    int osr = wv * 32 + nf * 16 + col;
    int gl = l0 + osr;
    bool owned = (osr < TS) && (gl < LSEQ);
#pragma unroll
    for (int m = 0; m < 2; ++m) {
      int ch0 = CIN + m * 16 + grp * 4;
      f32x4 f1v = {0.f, 0.f, 0.f, 0.f};
      if (owned) {
        f1v = *reinterpret_cast<const f32x4*>(&fi1b[(size_t)gl * CT + ch0]);
#pragma unroll
        for (int i = 0; i < 4; ++i) {
          float f = sc1[ch0 + i] * f1v[i] + sh1[ch0 + i];
          if (fi1Relu) f = fmaxf(f, 0.f);
          f1v[i] = f;
        }
      }
      f32x4 pre4;
#pragma unroll
      for (int i = 0; i < 4; ++i) {
        float pv = f1v[i] - cV * accC[m][nf][i] + sbv[ch0 + i];
        pre4[i] = pv;
        if (owned) { ts1[m][i] += pv; ts2[m][i] += pv * pv; }
      }
      if (owned) *reinterpret_cast<f32x4*>(&Pb[(size_t)gl * CT + ch0]) = pre4;
    }
  }
#pragma unroll
  for (int m = 0; m < 2; ++m)
#pragma unroll
    for (int i = 0; i < 4; ++i) {
      float s1 = ts1[m][i], s2 = ts2[m][i];
      s1 += __shfl_xor(s1, 1); s2 += __shfl_xor(s2, 1);
      s1 += __shfl_xor(s1, 2); s2 += __shfl_xor(s2, 2);
      s1 += __shfl_xor(s1, 4); s2 += __shfl_xor(s2, 4);
      s1 += __shfl_xor(s1, 8); s2 += __shfl_xor(s2, 8);
      if (col == 0) {
        int ch = CIN + m * 16 + grp * 4 + i;
        atomicAdd(&lstat[2 * ch], s1);
        atomicAdd(&lstat[2 * ch + 1], s2);
      }
    }

  // head: pre = act1(fi1) - c*s + bv (s from sS, row = site+1)
  {
    const int Q = CIN / 4;
    const int SPT = 128 / Q;
    int quad = t % Q, srow = t / Q;
    if (srow < SPT) {
      int c0 = quad * 4;
      float hb1[4] = {0.f, 0.f, 0.f, 0.f}, hb2[4] = {0.f, 0.f, 0.f, 0.f};
      for (int site = srow; site < TS; site += SPT) {
        int gl = l0 + site;
        if (gl >= LSEQ) break;
        float sv[4];
#pragma unroll
        for (int j = 0; j < 4; ++j) sv[j] = bf2f((unsigned short)sS[(site + 1) * CINP + c0 + j]);
        f32x4 f1 = *reinterpret_cast<const f32x4*>(&fi1b[(size_t)gl * CT + c0]);
        f32x4 pr;
#pragma unroll
        for (int j = 0; j < 4; ++j) {
          float f = sc1[c0 + j] * f1[j] + sh1[c0 + j];
          if (fi1Relu) f = fmaxf(f, 0.f);
          pr[j] = f - cV * sv[j] + sbv[c0 + j];
        }
        *reinterpret_cast<f32x4*>(&Pb[(size_t)gl * CT + c0]) = pr;
#pragma unroll
        for (int j = 0; j < 4; ++j) { hb1[j] += pr[j]; hb2[j] += pr[j] * pr[j]; }
      }
#pragma unroll
      for (int j = 0; j < 4; ++j) {
        atomicAdd(&lstat[2 * (c0 + j)], hb1[j]);
        atomicAdd(&lstat[2 * (c0 + j) + 1], hb2[j]);
      }
    }
  }
  __syncthreads();
  float* slot = statsOut + (n & (NSLOT - 1)) * SLOTW;
  for (int ch = t; ch < CT; ch += 128) {
    atomicAdd(&slot[2 * ch], lstat[2 * ch]);
    atomicAdd(&slot[2 * ch + 1], lstat[2 * ch + 1]);
  }
}

// eSE fused: mean over l + 1x1 conv + hsigmoid -> am[n][c]
__global__ __launch_bounds__(256) void ese_fused(
    const float* __restrict__ z, const float* __restrict__ stats,
    const float* __restrict__ g, const float* __restrict__ b,
    const float* __restrict__ W, const float* __restrict__ eb,
    float* __restrict__ am)
{
  __shared__ float sc[112], sh[112];
  __shared__ float red[224];
  __shared__ float smL[112];
  int n = blockIdx.x, t = threadIdx.x;
  load_affine16(stats, g, b, sc, sh, 112);
  __syncthreads();
  float acc = 0.f;
  if (t < 224) {
    int c = t % 112, p = t / 112;
    const float* zb = z + (size_t)n * LSEQ * 112;
    float scv = sc[c], shv = sh[c];
    for (int l = p; l < LSEQ; l += 2)
      acc += fmaxf(scv * zb[(size_t)l * 112 + c] + shv, 0.f);
    red[t] = acc;
  }
  __syncthreads();
  if (t < 112) smL[t] = (red[t] + red[t + 112]) * (1.f / LSEQ);
  __syncthreads();
  if (t < 112) {
    float a = eb[t] + 3.0f;
    for (int cc = 0; cc < 112; ++cc) a = fmaf(smL[cc], W[t * 112 + cc], a);
    a = fminf(fmaxf(a, 0.f), 6.f) * (1.f / 6.f);
    am[n * 112 + t] = a;
  }
}

// ---- fc1 path (verified) ----
__global__ __launch_bounds__(256) void zb_pack(
    const float* __restrict__ P3, const float* __restrict__ stats,
    const float* __restrict__ g, const float* __restrict__ b,
    const float* __restrict__ am, unsigned short* __restrict__ zb)
{
  __shared__ float sc[112], sh[112];
  __shared__ unsigned short sT[112 * 72];
  int t = threadIdx.x;
  int lt = blockIdx.x, n = blockIdx.y;
  int l0 = lt * 64;
  load_affine16(stats, g, b, sc, sh, 112);
  __syncthreads();
  const float* zr = P3 + ((size_t)n * LSEQ + l0) * 112;
  const float* amr = am + n * 112;
  for (int e = t; e < 64 * 112; e += 256) {
    int l = e / 112, c = e - (e / 112) * 112;
    float v = 0.f;
    if (l0 + l < LSEQ) v = fmaxf(sc[c] * zr[(size_t)l * 112 + c] + sh[c], 0.f) * amr[c];
    sT[c * 72 + l] = f2bf(v);
  }
  __syncthreads();
  unsigned short* zo = zb + (size_t)n * FC1K;
  for (int e = t; e < 112 * 8; e += 256) {
    int c = e >> 3, seg = e & 7;
    int l = seg * 8;
    int gl = l0 + l;
    if (gl >= LSEQ) continue;
    if (gl + 8 <= LSEQ) {
      bf16x8 v = *reinterpret_cast<const bf16x8*>(&sT[c * 72 + l]);
      *reinterpret_cast<bf16x8*>(&zo[(size_t)c * LSEQ + gl]) = v;
    } else {
      for (int jj = 0; jj < 8 && gl + jj < LSEQ; ++jj)
        zo[(size_t)c * LSEQ + gl + jj] = sT[c * 72 + l + jj];
    }
  }
}

__global__ __launch_bounds__(256) void wb_pack(const float* __restrict__ w1,
                                               unsigned short* __restrict__ wb)
{
  size_t i = (size_t)blockIdx.x * 256 + threadIdx.x;
  if (i >= (size_t)128 * FC1K / 8) return;
  const float* p = w1 + i * 8;
  bf16x8 v;
#pragma unroll
  for (int jj = 0; jj < 8; ++jj) v[jj] = (short)f2bf(p[jj]);
  *reinterpret_cast<bf16x8*>(&wb[i * 8]) = v;
}

__global__ __launch_bounds__(256) void fc1_mfma(
    const unsigned short* __restrict__ zb,
    const unsigned short* __restrict__ wb,
    float* __restrict__ parts)
{
  const int SLOT = 104;
  __shared__ __align__(16) unsigned short sA[128 * SLOT];
  __shared__ __align__(16) unsigned short sB[128 * SLOT];
  int t = threadIdx.x, b = blockIdx.x;
  int k0 = b * KCH;
  int wv = t >> 6, lane = t & 63, col = lane & 15, grp = lane >> 4;
  int jq = (wv >> 1) * 64, nq = (wv & 1) * 64;

  f32x4 acc[4][4];
#pragma unroll
  for (int m = 0; m < 4; ++m)
#pragma unroll
    for (int nn = 0; nn < 4; ++nn) acc[m][nn] = (f32x4){0.f, 0.f, 0.f, 0.f};

#pragma unroll
  for (int half = 0; half < 2; ++half) {
    int kh = k0 + half * 96;
    int kwid = half ? (KCH - 96) : 96;
    int nslots = half ? 8 : 12;
    __syncthreads();
    for (int e = t; e < 128 * 12; e += 256) {
      int row = e / 12, g2 = e - (e / 12) * 12;
      int kk = g2 * 8;
      bf16x8 va = {0, 0, 0, 0, 0, 0, 0, 0}, vb2 = va;
      if (g2 < nslots) {
        va = *reinterpret_cast<const bf16x8*>(&wb[(size_t)row * FC1K + kh + kk]);
        vb2 = *reinterpret_cast<const bf16x8*>(&zb[(size_t)row * FC1K + kh + kk]);
#pragma unroll
        for (int jj = 0; jj < 8; ++jj)
          if (kk + jj >= kwid) { va[jj] = 0; vb2[jj] = 0; }
      }
      *reinterpret_cast<bf16x8*>(&sA[row * SLOT + kk]) = va;
      *reinterpret_cast<bf16x8*>(&sB[row * SLOT + kk]) = vb2;
    }
    __syncthreads();
    int ksteps = half ? 2 : 3;
    for (int ks = 0; ks < ksteps; ++ks) {
      bf16x8 af[4], bfr[4];
#pragma unroll
      for (int m = 0; m < 4; ++m)
        af[m] = *reinterpret_cast<const bf16x8*>(&sA[(jq + m * 16 + col) * SLOT + ks * 32 + grp * 8]);
#pragma unroll
      for (int nn = 0; nn < 4; ++nn)
        bfr[nn] = *reinterpret_cast<const bf16x8*>(&sB[(nq + nn * 16 + col) * SLOT + ks * 32 + grp * 8]);
#pragma unroll
      for (int m = 0; m < 4; ++m)
#pragma unroll
        for (int nn = 0; nn < 4; ++nn)
          acc[m][nn] = __builtin_amdgcn_mfma_f32_16x16x32_bf16(af[m], bfr[nn], acc[m][nn], 0, 0, 0);
    }
  }
  float* pb = parts + (size_t)b * 16384;
#pragma unroll
  for (int nn = 0; nn < 4; ++nn)
#pragma unroll
    for (int m = 0; m < 4; ++m)
      *reinterpret_cast<f32x4*>(&pb[(nq + nn * 16 + col) * 128 + jq + m * 16 + grp * 4]) = acc[m][nn];
}

__global__ __launch_bounds__(256) void fc1_red(const float* __restrict__ parts,
                                               float* __restrict__ y1)
{
  int o = blockIdx.x * 256 + threadIdx.x;
  float s = 0.f;
  for (int b = 0; b < NKBLK; ++b) s += parts[(size_t)b * 16384 + o];
  y1[o] = s;
}

__global__ __launch_bounds__(128) void fc2_lsm(const float* __restrict__ y1,
                                               const float* __restrict__ b1,
                                               const float* __restrict__ w2,
                                               const float* __restrict__ b2,
                                               float* __restrict__ out)
{
  int n = blockIdx.x;
  int t = threadIdx.x;
  __shared__ float part[10][128];
  float v = fmaxf(y1[n * 128 + t] + b1[t], 0.f);
#pragma unroll
  for (int k = 0; k < 10; ++k) part[k][t] = v * w2[k * 128 + t];
  __syncthreads();
  for (int st = 64; st > 0; st >>= 1) {
    if (t < st) {
#pragma unroll
      for (int k = 0; k < 10; ++k) part[k][t] += part[k][t + st];
    }
    __syncthreads();
  }
  if (t == 0) {
    float lg[10];
    float mx = -1e30f;
#pragma unroll
    for (int k = 0; k < 10; ++k) { lg[k] = part[k][0] + b2[k]; mx = fmaxf(mx, lg[k]); }
    float s = 0.f;
#pragma unroll
    for (int k = 0; k < 10; ++k) s += expf(lg[k] - mx);
    float ls = logf(s) + mx;
#pragma unroll
    for (int k = 0; k < 10; ++k) {
      out[n * 10 + k] = lg[k] - ls;
      out[1280 + n * 10 + k] = lg[k];
    }
  }
}

extern "C" void kernel_launch(void* const* d_in, const int* in_sizes, int n_in,
                              void* d_out, int out_size, void* d_ws, size_t ws_size,
                              hipStream_t stream)
{
  (void)in_sizes; (void)n_in; (void)out_size; (void)ws_size;
  const float* x       = (const float*)d_in[0];
  const float* filter0 = (const float*)d_in[1];
  const float* b0      = (const float*)d_in[2];
  const float* bn0_g   = (const float*)d_in[3];
  const float* bn0_b   = (const float*)d_in[4];
  const float* ese_w   = (const float*)d_in[5];
  const float* ese_b   = (const float*)d_in[6];
  const float* fc1_w   = (const float*)d_in[7];
  const float* fc1_b   = (const float*)d_in[8];
  const float* fc2_w   = (const float*)d_in[9];
  const float* fc2_b   = (const float*)d_in[10];
  const float* F[3]    = {(const float*)d_in[11], (const float*)d_in[16], (const float*)d_in[21]};
  const float* bv[3]   = {(const float*)d_in[12], (const float*)d_in[17], (const float*)d_in[22]};
  const float* g1[3]   = {(const float*)d_in[13], (const float*)d_in[18], (const float*)d_in[23]};
  const float* be1[3]  = {(const float*)d_in[14], (const float*)d_in[19], (const float*)d_in[24]};
  const float* cs[3]   = {(const float*)d_in[15], (const float*)d_in[20], (const float*)d_in[25]};

  const size_t NL = (size_t)NBATCH * LSEQ;
  const int SLOTSZ = NSLOT * SLOTW;          // 8192 floats per stage
  float* wsf = (float*)d_ws;
  size_t o = 0;
  float* SS  = wsf + o;  o += 13 * SLOTSZ;
  float* y1  = wsf + o;  o += 128 * 128;
  float* P0  = wsf + o;  o += NL * 16;
  float* P3A = wsf + o;  o += NL * 112;
  float* P3B = wsf + o;  o += NL * 112;
  float* am  = wsf + o;  o += 128 * 112;
  size_t reuse0 = o;             // P1,P2,R1,R2 region = NL*256 floats
  float* P1  = wsf + o;  o += NL * 48;
  float* P2  = wsf + o;  o += NL * 80;
  float* R1  = wsf + o;  o += NL * 48;
  float* R2  = wsf + o;  o += NL * 80;

  // fc1 scratch aliases P1/P2/R1/R2 (dead at fc1 time): 8.23M floats <= NL*256
  unsigned short* zb = (unsigned short*)(wsf + reuse0);
  unsigned short* wb = zb + (size_t)128 * FC1K;
  float* parts = wsf + reuse0 + (size_t)128 * FC1K;

  hipMemsetAsync(SS, 0, 13 * SLOTSZ * sizeof(float), stream);

  // ---- stem -> P0 + stats slot 0
  stem_mfma<<<dim3(4, 128), 256, 0, stream>>>(x, filter0, b0, P0, SS);

  // ---- init stages (MODE 0)
  float* s1 = SS + 1 * SLOTSZ;
  ista_stage<16, 0><<<dim3(3, 128), 256, 0, stream>>>(
      nullptr, P0, SS, bn0_g, bn0_b, 0,
      nullptr, nullptr, nullptr, nullptr, 0,
      F[0], cs[0], bv[0], P1, s1);
  float* s2 = SS + 2 * SLOTSZ;
  ista_stage<48, 0><<<dim3(3, 128), 256, 0, stream>>>(
      nullptr, P1, s1, g1[0], be1[0], 1,
      nullptr, nullptr, nullptr, nullptr, 0,
      F[1], cs[1], bv[1], P2, s2);
  float* s3 = SS + 3 * SLOTSZ;
  ista_stage<80, 0><<<dim3(3, 128), 256, 0, stream>>>(
      nullptr, P2, s2, g1[1], be1[1], 1,
      nullptr, nullptr, nullptr, nullptr, 0,
      F[2], cs[2], bv[2], P3A, s3);

  float* P3cur = P3A;
  float* P3nxt = P3B;
  const float* st3 = s3;

  // ---- unfolding
  for (int u = 0; u < 3; ++u) {
    bwd_fused<<<dim3(3, 128), 256, 0, stream>>>(
        P3cur, st3, g1[2], be1[2], F[2], F[1], R2, R1);
    float* sA = SS + (4 + 3 * u) * SLOTSZ;
    fwd_fused<16><<<dim3(6, 128), 128, 0, stream>>>(
        R1, nullptr, nullptr, nullptr, 0,
        P0, SS, bn0_g, bn0_b, 0,
        F[0], cs[0], bv[0], P1, sA);
    float* sB = SS + (5 + 3 * u) * SLOTSZ;
    fwd_fused<48><<<dim3(6, 128), 128, 0, stream>>>(
        R2, nullptr, nullptr, nullptr, 0,
        P1, sA, g1[0], be1[0], 1,
        F[1], cs[1], bv[1], P2, sB);
    float* sC = SS + (6 + 3 * u) * SLOTSZ;
    fwd_fused<80><<<dim3(6, 128), 128, 0, stream>>>(
        P3cur, st3, g1[2], be1[2], 1,
        P2, sB, g1[1], be1[1], 1,
        F[2], cs[2], bv[2], P3nxt, sC);
    st3 = sC;
    float* tmp = P3cur; P3cur = P3nxt; P3nxt = tmp;
  }

  // ---- eSE (fused mean + act)
  ese_fused<<<128, 256, 0, stream>>>(P3cur, st3, g1[2], be1[2], ese_w, ese_b, am);

  // ---- fc1 (bf16 MFMA split-K) + fc2 + log_softmax
  wb_pack<<<(int)(((size_t)128 * FC1K / 8 + 255) / 256), 256, 0, stream>>>(fc1_w, wb);
  zb_pack<<<dim3(5, 128), 256, 0, stream>>>(P3cur, st3, g1[2], be1[2], am, zb);
  fc1_mfma<<<NKBLK, 256, 0, stream>>>(zb, wb, parts);
  fc1_red<<<64, 256, 0, stream>>>(parts, y1);
  fc2_lsm<<<128, 128, 0, stream>>>(y1, fc1_b, fc2_w, fc2_b, (float*)d_out);
}

// Round 14
// 436.594 us; speedup vs baseline: 1.0597x; 1.0597x over previous
//
#include <hip/hip_runtime.h>
#include <hip/hip_bf16.h>

#define LSEQ 318
#define NBATCH 128
#define NE (NBATCH * LSEQ)
#define FC1K 35616
#define NKBLK 224   // 224 * 159 == 35616
#define KCH 159
#define NSLOT 16
#define SLOTW 256   // floats per slot row

typedef __attribute__((ext_vector_type(4))) float f32x4;
typedef __attribute__((ext_vector_type(8))) short bf16x8;
typedef __attribute__((ext_vector_type(4))) unsigned int u32x4;

__device__ inline unsigned short f2bf(float v) {
  unsigned int a = __builtin_bit_cast(unsigned int, v);
  return (unsigned short)((a + 0x7FFFu + ((a >> 16) & 1u)) >> 16);
}
__device__ inline float bf2f(unsigned short u) {
  unsigned int a = ((unsigned int)u) << 16;
  return __builtin_bit_cast(float, a);
}
__device__ inline unsigned int packbf2(float lo, float hi) {
  return (unsigned int)f2bf(lo) | ((unsigned int)f2bf(hi) << 16);
}
__device__ inline bf16x8 ldfrag(const unsigned int* xb, int j0) {
  u32x4 uu = {xb[j0], xb[j0 + 1], xb[j0 + 2], xb[j0 + 3]};
  return __builtin_bit_cast(bf16x8, uu);
}

// per-channel affine from NSLOT partial stats
__device__ inline void load_affine16(const float* pstat, const float* g, const float* b,
                                     float* sc, float* sh, int C) {
  for (int c = threadIdx.x; c < C; c += blockDim.x) {
    if (pstat) {
      float s1 = 0.f, s2 = 0.f;
#pragma unroll
      for (int s = 0; s < NSLOT; ++s) {
        s1 += pstat[s * SLOTW + 2 * c];
        s2 += pstat[s * SLOTW + 2 * c + 1];
      }
      float m = s1 * (1.f / NE);
      float var = s2 * (1.f / NE) - m * m;
      float sv = g[c] * rsqrtf(var + 1e-5f);
      sc[c] = sv; sh[c] = b[c] - m * sv;
    } else { sc[c] = 1.f; sh[c] = 0.f; }
  }
}

// pre-pack stem W (f32 [16][1700]) -> bf16 [16][1736] (zero-pad tail)
__global__ __launch_bounds__(256) void wstem_pack(const float* __restrict__ w,
                                                  unsigned short* __restrict__ wsb)
{
  int i = blockIdx.x * 256 + threadIdx.x;  // dword index over 16*868
  if (i >= 16 * 868) return;
  int co = i / 868, kd = (i - co * 868) * 2;
  float v0 = (kd < 1700) ? w[co * 1700 + kd] : 0.f;
  float v1 = (kd + 1 < 1700) ? w[co * 1700 + kd + 1] : 0.f;
  ((unsigned int*)wsb)[i] = packbf2(v0, v1);
}

// ---------------------------------------------------------------------------
// Stem (round-8 VERIFIED math, W pre-packed): conv1d + b0 + maxpool16 ->
// P0 [n][l][16] channels-last + slot stats. Rolling rings, p<10, reload p<9.
// ---------------------------------------------------------------------------
__global__ __launch_bounds__(256) void stem_mfma(
    const float* __restrict__ x, const unsigned short* __restrict__ wsb,
    const float* __restrict__ b0, float* __restrict__ pre,
    float* __restrict__ pstat)
{
  __shared__ __align__(16) unsigned short wsh[16 * 1736];
  __shared__ __align__(16) unsigned int xs2[2 * 1520];
  int t = threadIdx.x;
  int pblk = blockIdx.x, n = blockIdx.y;
  int P0 = pblk * 1280;

  for (int e = t; e < 16 * 217; e += 256)   // pure bf16x8 copy (layout identical)
    *reinterpret_cast<bf16x8*>(&wsh[e * 8]) = *reinterpret_cast<const bf16x8*>(&wsb[e * 8]);
  const float* xn = x + (size_t)n * 5087;
  for (int i = t; i < 1520; i += 256) {
    int m = 2 * i;
    int g0 = P0 - 850 + m;
    float v0 = (g0 >= 0 && g0 < 5087) ? xn[g0] : 0.f;
    float v1 = (g0 + 1 >= 0 && g0 + 1 < 5087) ? xn[g0 + 1] : 0.f;
    float v2 = (g0 + 2 >= 0 && g0 + 2 < 5087) ? xn[g0 + 2] : 0.f;
    xs2[i] = packbf2(v0, v1);
    xs2[1520 + i] = packbf2(v1, v2);
  }
  __syncthreads();

  int wv = t >> 6, lane = t & 63;
  int row = lane & 15, grp = lane >> 4;
  int tb = wv * 20;
  const unsigned int* xb = xs2 + (row & 1) * 1520;
  int eb0 = 16 * tb + row + 8 * grp;

  f32x4 acc[20];
#pragma unroll
  for (int i = 0; i < 20; ++i) acc[i] = (f32x4){0.f, 0.f, 0.f, 0.f};

  for (int kg = 0; kg < 6; ++kg) {
    bf16x8 bf[9];
#pragma unroll
    for (int c = 0; c < 9; ++c)
      bf[c] = *reinterpret_cast<const bf16x8*>(&wsh[row * 1736 + kg * 288 + c * 32 + grp * 8]);
    int eb = eb0 + 288 * kg;
    bf16x8 re[9], ro[9];
#pragma unroll
    for (int c = 0; c < 9; ++c) {
      re[c] = ldfrag(xb, (eb + 32 * c) >> 1);
      ro[c] = ldfrag(xb, (eb + 16 + 32 * c) >> 1);
    }
#pragma unroll
    for (int p = 0; p < 10; ++p) {
#pragma unroll
      for (int c = 0; c < 9; ++c)
        acc[2 * p] = __builtin_amdgcn_mfma_f32_16x16x32_bf16(re[c], bf[c], acc[2 * p], 0, 0, 0);
#pragma unroll
      for (int c = 0; c < 9; ++c)
        acc[2 * p + 1] = __builtin_amdgcn_mfma_f32_16x16x32_bf16(ro[c], bf[c], acc[2 * p + 1], 0, 0, 0);
      if (p < 9) {
#pragma unroll
        for (int c = 0; c < 8; ++c) { re[c] = re[c + 1]; ro[c] = ro[c + 1]; }
        re[8] = ldfrag(xb, (eb + 32 * p + 288) >> 1);
        ro[8] = ldfrag(xb, (eb + 32 * p + 304) >> 1);
      }
    }
  }

  float b0v = b0[row];
  float ssum = 0.f, ssq = 0.f;
#pragma unroll
  for (int mt = 0; mt < 20; ++mt) {
    int q = pblk * 80 + tb + mt;
    f32x4 d = acc[mt];
    float m = fmaxf(fmaxf(d[0], d[1]), fmaxf(d[2], d[3]));
    m = fmaxf(m, __shfl_xor(m, 16));
    m = fmaxf(m, __shfl_xor(m, 32));
    if (lane < 16 && q < LSEQ) {
      float val = m + b0v;
      pre[((size_t)n * LSEQ + q) * 16 + lane] = val;
      ssum += val; ssq += val * val;
    }
  }
  if (lane < 16) {
    float* slot = pstat + (n & (NSLOT - 1)) * SLOTW;
    atomicAdd(&slot[2 * lane], ssum);
    atomicAdd(&slot[2 * lane + 1], ssq);
  }
}

// ---------------------------------------------------------------------------
// ista_stage (round-8 verified; MODE 0 only), slot stats.
// ---------------------------------------------------------------------------
template <int CIN, int MODE>
__global__ __launch_bounds__(256) void ista_stage(
    const float* __restrict__ t2,
    const float* __restrict__ fiP, const float* __restrict__ fiStats,
    const float* __restrict__ fiG, const float* __restrict__ fiB, int fiRelu,
    const float* __restrict__ fi1P, const float* __restrict__ fi1Stats,
    const float* __restrict__ fi1G, const float* __restrict__ fi1B, int fi1Relu,
    const float* __restrict__ F, const float* __restrict__ cs,
    const float* __restrict__ bv,
    float* __restrict__ P, float* __restrict__ statsOut)
{
  const int CT = CIN + 32;
  const int K3 = 3 * CIN;
  const int KPAD = ((K3 + 31) / 32) * 32;
  const int KROWP = KPAD + (((KPAD / 8) % 2 == 0) ? 8 : 0);
  const int CINP = CIN + (((CIN / 8) % 2 == 0) ? 8 : 0);
  const int TS = 128, ROWS = TS + 3;
  const int KSTEPS = KPAD / 32;

  __shared__ __align__(16) unsigned short sW[32 * KROWP];
  __shared__ __align__(16) unsigned short sS[ROWS * CINP];
  __shared__ float scF[CIN], shF[CIN];
  __shared__ float sc1[CT], sh1[CT], sbv[CT];
  __shared__ float lstat[2 * CT];

  int t = threadIdx.x;
  int l0 = blockIdx.x * TS, n = blockIdx.y;

  load_affine16(fiStats, fiG, fiB, scF, shF, CIN);
  load_affine16(fi1Stats, fi1G, fi1B, sc1, sh1, CT);
  for (int c = t; c < CT; c += 256) sbv[c] = bv[c];
  for (int c = t; c < 2 * CT; c += 256) lstat[c] = 0.f;
  __syncthreads();

  for (int e = t; e < 32 * (KPAD / 8); e += 256) {
    int co = e / (KPAD / 8), kc = (e - co * (KPAD / 8)) * 8;
    int dt = kc / CIN, ci = kc - dt * CIN;
    bf16x8 v;
    if (dt < 3) {
#pragma unroll
      for (int jj = 0; jj < 8; ++jj)
        v[jj] = (short)f2bf(F[((size_t)co * CIN + ci + jj) * 3 + dt]);
    } else {
#pragma unroll
      for (int jj = 0; jj < 8; ++jj) v[jj] = 0;
    }
    *reinterpret_cast<bf16x8*>(&sW[co * KROWP + kc]) = v;
  }
  const float* fib = fiP + (size_t)n * LSEQ * CIN;
  const float* t2b = MODE ? (t2 + (size_t)n * LSEQ * CIN) : nullptr;
  const int NCH8 = CIN / 8;
  for (int e = t; e < ROWS * NCH8; e += 256) {
    int r = e / NCH8, c8 = (e - r * NCH8) * 8;
    int gl = l0 - 1 + r;
    bf16x8 v;
    if (gl >= 0 && gl < LSEQ) {
      const float* p = fib + (size_t)gl * CIN + c8;
#pragma unroll
      for (int jj = 0; jj < 8; ++jj) {
        float f = scF[c8 + jj] * p[jj] + shF[c8 + jj];
        if (fiRelu) f = fmaxf(f, 0.f);
        if (MODE) f = t2b[(size_t)gl * CIN + c8 + jj] - f;
        v[jj] = (short)f2bf(f);
      }
    } else {
#pragma unroll
      for (int jj = 0; jj < 8; ++jj) v[jj] = 0;
    }
    *reinterpret_cast<bf16x8*>(&sS[r * CINP + c8]) = v;
  }
  __syncthreads();

  int wv = t >> 6, lane = t & 63, col = lane & 15, grp = lane >> 4;
  float cV = cs[0];

  bf16x8 a[2][KSTEPS];
#pragma unroll
  for (int m = 0; m < 2; ++m)
#pragma unroll
    for (int ks = 0; ks < KSTEPS; ++ks)
      a[m][ks] = *reinterpret_cast<const bf16x8*>(&sW[(m * 16 + col) * KROWP + ks * 32 + grp * 8]);

  f32x4 acc[2][2];
#pragma unroll
  for (int m = 0; m < 2; ++m)
#pragma unroll
    for (int nf = 0; nf < 2; ++nf) acc[m][nf] = (f32x4){0.f, 0.f, 0.f, 0.f};

#pragma unroll
  for (int ks = 0; ks < KSTEPS; ++ks) {
    int kkb = ks * 32 + grp * 8;
    int dt = kkb / CIN, ci = kkb - dt * CIN;
#pragma unroll
    for (int nf = 0; nf < 2; ++nf) {
      int row = wv * 32 + nf * 16 + col + dt;
      bf16x8 bfrag = *reinterpret_cast<const bf16x8*>(&sS[row * CINP + ci]);
      acc[0][nf] = __builtin_amdgcn_mfma_f32_16x16x32_bf16(a[0][ks], bfrag, acc[0][nf], 0, 0, 0);
      acc[1][nf] = __builtin_amdgcn_mfma_f32_16x16x32_bf16(a[1][ks], bfrag, acc[1][nf], 0, 0, 0);
    }
  }

  const float* fi1b = fi1P ? (fi1P + (size_t)n * LSEQ * CT) : nullptr;
  float* Pb = P + (size_t)n * LSEQ * CT;
  float ts1[2][4], ts2[2][4];
#pragma unroll
  for (int m = 0; m < 2; ++m)
#pragma unroll
    for (int i = 0; i < 4; ++i) { ts1[m][i] = 0.f; ts2[m][i] = 0.f; }

#pragma unroll
  for (int nf = 0; nf < 2; ++nf) {
    int siteL = wv * 32 + nf * 16 + col;
    int gl = l0 + siteL;
    bool valid = (gl < LSEQ);
#pragma unroll
    for (int m = 0; m < 2; ++m) {
      int ch0 = CIN + m * 16 + grp * 4;
      f32x4 f1v = {0.f, 0.f, 0.f, 0.f};
      if (MODE && valid) {
        f1v = *reinterpret_cast<const f32x4*>(&fi1b[(size_t)gl * CT + ch0]);
#pragma unroll
        for (int i = 0; i < 4; ++i) {
          float f = sc1[ch0 + i] * f1v[i] + sh1[ch0 + i];
          if (fi1Relu) f = fmaxf(f, 0.f);
          f1v[i] = f;
        }
      }
      f32x4 pre4;
#pragma unroll
      for (int i = 0; i < 4; ++i) {
        float pv = MODE ? (f1v[i] - cV * acc[m][nf][i] + sbv[ch0 + i])
                        : (cV * acc[m][nf][i] + sbv[ch0 + i]);
        pre4[i] = pv;
        if (valid) { ts1[m][i] += pv; ts2[m][i] += pv * pv; }
      }
      if (valid) *reinterpret_cast<f32x4*>(&Pb[(size_t)gl * CT + ch0]) = pre4;
    }
  }
#pragma unroll
  for (int m = 0; m < 2; ++m)
#pragma unroll
    for (int i = 0; i < 4; ++i) {
      float s1 = ts1[m][i], s2 = ts2[m][i];
      s1 += __shfl_xor(s1, 1); s2 += __shfl_xor(s2, 1);
      s1 += __shfl_xor(s1, 2); s2 += __shfl_xor(s2, 2);
      s1 += __shfl_xor(s1, 4); s2 += __shfl_xor(s2, 4);
      s1 += __shfl_xor(s1, 8); s2 += __shfl_xor(s2, 8);
      if (col == 0) {
        int ch = CIN + m * 16 + grp * 4 + i;
        atomicAdd(&lstat[2 * ch], s1);
        atomicAdd(&lstat[2 * ch + 1], s2);
      }
    }

  {
    const int Q = CIN / 4;
    const int SPT = 256 / Q;
    int quad = t % Q, srow = t / Q;
    if (srow < SPT) {
      int c0 = quad * 4;
      float hb1[4] = {0.f, 0.f, 0.f, 0.f}, hb2[4] = {0.f, 0.f, 0.f, 0.f};
      for (int site = srow; site < TS; site += SPT) {
        int gl = l0 + site;
        if (gl >= LSEQ) break;
        float sv[4];
#pragma unroll
        for (int j = 0; j < 4; ++j) sv[j] = bf2f((unsigned short)sS[(site + 1) * CINP + c0 + j]);
        f32x4 pr;
        if (MODE) {
          f32x4 f1 = *reinterpret_cast<const f32x4*>(&fi1b[(size_t)gl * CT + c0]);
#pragma unroll
          for (int j = 0; j < 4; ++j) {
            float f = sc1[c0 + j] * f1[j] + sh1[c0 + j];
            if (fi1Relu) f = fmaxf(f, 0.f);
            pr[j] = f - cV * sv[j] + sbv[c0 + j];
          }
        } else {
#pragma unroll
          for (int j = 0; j < 4; ++j) pr[j] = cV * sv[j] + sbv[c0 + j];
        }
        *reinterpret_cast<f32x4*>(&Pb[(size_t)gl * CT + c0]) = pr;
#pragma unroll
        for (int j = 0; j < 4; ++j) { hb1[j] += pr[j]; hb2[j] += pr[j] * pr[j]; }
      }
#pragma unroll
      for (int j = 0; j < 4; ++j) {
        atomicAdd(&lstat[2 * (c0 + j)], hb1[j]);
        atomicAdd(&lstat[2 * (c0 + j) + 1], hb2[j]);
      }
    }
  }
  __syncthreads();
  float* slot = statsOut + (n & (NSLOT - 1)) * SLOTW;
  for (int ch = t; ch < CT; ch += 256) {
    atomicAdd(&slot[2 * ch], lstat[2 * ch]);
    atomicAdd(&slot[2 * ch + 1], lstat[2 * ch + 1]);
  }
}

// ---------------------------------------------------------------------------
// bwd_fused (verified): R2 = convT80(act(f3)); R1 = convT48(R2). Slot affine.
// ---------------------------------------------------------------------------
__global__ __launch_bounds__(256) void bwd_fused(
    const float* __restrict__ f3P, const float* __restrict__ st3,
    const float* __restrict__ g3, const float* __restrict__ b3,
    const float* __restrict__ F2, const float* __restrict__ F1,
    float* __restrict__ R2, float* __restrict__ R1)
{
  __shared__ __align__(16) unsigned short X3[130 * 40];
  __shared__ __align__(16) unsigned short sW2[80 * 104];
  __shared__ __align__(16) unsigned short sW1[48 * 104];
  __shared__ __align__(16) unsigned short R2t[130 * 40];
  __shared__ __align__(16) float R2h[128 * 52];
  __shared__ float sc3[112], sh3[112];
  int t = threadIdx.x;
  int l0 = blockIdx.x * 126, n = blockIdx.y;
  load_affine16(st3, g3, b3, sc3, sh3, 112);
  __syncthreads();

  const float* f3b = f3P + (size_t)n * LSEQ * 112;
  for (int e = t; e < 130 * 4; e += 256) {
    int r = e >> 2, c8 = (e & 3) * 8;
    int gl = l0 - 2 + r;
    bf16x8 v;
    if (gl >= 0 && gl < LSEQ) {
      const float* p = f3b + (size_t)gl * 112 + 80 + c8;
#pragma unroll
      for (int jj = 0; jj < 8; ++jj)
        v[jj] = (short)f2bf(fmaxf(sc3[80 + c8 + jj] * p[jj] + sh3[80 + c8 + jj], 0.f));
    } else {
#pragma unroll
      for (int jj = 0; jj < 8; ++jj) v[jj] = 0;
    }
    *reinterpret_cast<bf16x8*>(&X3[r * 40 + c8]) = v;
  }
  for (int e = t; e < 80 * 12; e += 256) {
    int co = e / 12, kc = (e - co * 12) * 8;
    int dt = kc >> 5, j0 = kc & 31;
    bf16x8 v;
#pragma unroll
    for (int jj = 0; jj < 8; ++jj)
      v[jj] = (short)f2bf(F2[((size_t)(j0 + jj) * 80 + co) * 3 + (2 - dt)]);
    *reinterpret_cast<bf16x8*>(&sW2[co * 104 + kc]) = v;
  }
  for (int e = t; e < 48 * 12; e += 256) {
    int co = e / 12, kc = (e - co * 12) * 8;
    int dt = kc >> 5, j0 = kc & 31;
    bf16x8 v;
#pragma unroll
    for (int jj = 0; jj < 8; ++jj)
      v[jj] = (short)f2bf(F1[((size_t)(j0 + jj) * 48 + co) * 3 + (2 - dt)]);
    *reinterpret_cast<bf16x8*>(&sW1[co * 104 + kc]) = v;
  }
  if (t < 10) {
    int r = 128 + t / 5, c8 = (t % 5) * 8;
    bf16x8 z;
#pragma unroll
    for (int jj = 0; jj < 8; ++jj) z[jj] = 0;
    *reinterpret_cast<bf16x8*>(&R2t[r * 40 + c8]) = z;
  }
  __syncthreads();

  int wv = t >> 6, lane = t & 63, col = lane & 15, grp = lane >> 4;
  f32x4 acc2[5][2];
#pragma unroll
  for (int m = 0; m < 5; ++m)
#pragma unroll
    for (int nf = 0; nf < 2; ++nf) acc2[m][nf] = (f32x4){0.f, 0.f, 0.f, 0.f};
#pragma unroll
  for (int ks = 0; ks < 3; ++ks) {
    bf16x8 bA = *reinterpret_cast<const bf16x8*>(&X3[(wv * 32 + col + ks) * 40 + grp * 8]);
    bf16x8 bB = *reinterpret_cast<const bf16x8*>(&X3[(wv * 32 + 16 + col + ks) * 40 + grp * 8]);
#pragma unroll
    for (int m = 0; m < 5; ++m) {
      bf16x8 af = *reinterpret_cast<const bf16x8*>(&sW2[(m * 16 + col) * 104 + ks * 32 + grp * 8]);
      acc2[m][0] = __builtin_amdgcn_mfma_f32_16x16x32_bf16(af, bA, acc2[m][0], 0, 0, 0);
      acc2[m][1] = __builtin_amdgcn_mfma_f32_16x16x32_bf16(af, bB, acc2[m][1], 0, 0, 0);
    }
  }
#pragma unroll
  for (int nf = 0; nf < 2; ++nf) {
    int sr = wv * 32 + nf * 16 + col;
    int gl = l0 - 1 + sr;
    bool v = (gl >= 0 && gl < LSEQ);
#pragma unroll
    for (int m = 0; m < 5; ++m) {
      int c0 = m * 16 + grp * 4;
      f32x4 o = {0.f, 0.f, 0.f, 0.f};
      if (v) {
        f32x4 hv = *reinterpret_cast<const f32x4*>(&f3b[(size_t)gl * 112 + c0]);
#pragma unroll
        for (int i = 0; i < 4; ++i)
          o[i] = fmaxf(sc3[c0 + i] * hv[i] + sh3[c0 + i], 0.f) + acc2[m][nf][i];
        *reinterpret_cast<f32x4*>(&R2[((size_t)n * LSEQ + gl) * 80 + c0]) = o;
      }
      if (c0 < 48) {
        *reinterpret_cast<f32x4*>(&R2h[sr * 52 + c0]) = o;
      } else {
        int j = c0 - 48;
        *reinterpret_cast<unsigned int*>(&R2t[sr * 40 + j]) = packbf2(o[0], o[1]);
        *reinterpret_cast<unsigned int*>(&R2t[sr * 40 + j + 2]) = packbf2(o[2], o[3]);
      }
    }
  }
  __syncthreads();

  f32x4 acc1[3][2];
#pragma unroll
  for (int m = 0; m < 3; ++m)
#pragma unroll
    for (int nf = 0; nf < 2; ++nf) acc1[m][nf] = (f32x4){0.f, 0.f, 0.f, 0.f};
#pragma unroll
  for (int ks = 0; ks < 3; ++ks) {
    bf16x8 bA = *reinterpret_cast<const bf16x8*>(&R2t[(wv * 32 + col + ks) * 40 + grp * 8]);
    bf16x8 bB = *reinterpret_cast<const bf16x8*>(&R2t[(wv * 32 + 16 + col + ks) * 40 + grp * 8]);
#pragma unroll
    for (int m = 0; m < 3; ++m) {
      bf16x8 af = *reinterpret_cast<const bf16x8*>(&sW1[(m * 16 + col) * 104 + ks * 32 + grp * 8]);
      acc1[m][0] = __builtin_amdgcn_mfma_f32_16x16x32_bf16(af, bA, acc1[m][0], 0, 0, 0);
      acc1[m][1] = __builtin_amdgcn_mfma_f32_16x16x32_bf16(af, bB, acc1[m][1], 0, 0, 0);
    }
  }
#pragma unroll
  for (int nf = 0; nf < 2; ++nf) {
    int osr = wv * 32 + nf * 16 + col;
    int gl = l0 + osr;
    if (osr < 126 && gl < LSEQ) {
#pragma unroll
      for (int m = 0; m < 3; ++m) {
        int c0 = m * 16 + grp * 4;
        f32x4 h = *reinterpret_cast<const f32x4*>(&R2h[(osr + 1) * 52 + c0]);
        f32x4 o;
#pragma unroll
        for (int i = 0; i < 4; ++i) o[i] = h[i] + acc1[m][nf][i];
        *reinterpret_cast<f32x4*>(&R1[((size_t)n * LSEQ + gl) * 48 + c0]) = o;
      }
    }
  }
}

// ---------------------------------------------------------------------------
// fwd_fused (round-12 verified 256-thread TS=126), slot stats.
// ---------------------------------------------------------------------------
template <int CIN>
__global__ __launch_bounds__(256) void fwd_fused(
    const float* __restrict__ fi1P, const float* __restrict__ fi1S,
    const float* __restrict__ fi1G, const float* __restrict__ fi1B, int fi1Relu,
    const float* __restrict__ fPP, const float* __restrict__ fPS,
    const float* __restrict__ fPG, const float* __restrict__ fPB, int fPRelu,
    const float* __restrict__ F, const float* __restrict__ cs,
    const float* __restrict__ bv,
    float* __restrict__ P, float* __restrict__ statsOut)
{
  const int CT = CIN + 32;
  const int K3 = 3 * CIN;
  const int KPAD = ((K3 + 31) / 32) * 32;
  const int KROWP = KPAD + (((KPAD / 8) % 2 == 0) ? 8 : 0);
  const int CINP = CIN + (((CIN / 8) % 2 == 0) ? 8 : 0);
  const int KSTEPS = KPAD / 32;
  const int MFT = CIN / 16;
  const int TS = 126;

  __shared__ __align__(16) unsigned short X1[130 * 40];
  __shared__ __align__(16) unsigned short sS[131 * CINP];
  __shared__ __align__(16) unsigned short sWT[CIN * 104];
  __shared__ __align__(16) unsigned short sWC[32 * KROWP];
  __shared__ float scP[CIN], shP[CIN];
  __shared__ float sc1[CT], sh1[CT], sbv[CT];
  __shared__ float lstat[2 * CT];

  int t = threadIdx.x;
  int l0 = blockIdx.x * TS, n = blockIdx.y;

  load_affine16(fPS, fPG, fPB, scP, shP, CIN);
  load_affine16(fi1S, fi1G, fi1B, sc1, sh1, CT);
  for (int c = t; c < CT; c += 256) sbv[c] = bv[c];
  for (int c = t; c < 2 * CT; c += 256) lstat[c] = 0.f;
  __syncthreads();

  const float* fi1b = fi1P + (size_t)n * LSEQ * CT;
  const float* fPb = fPP + (size_t)n * LSEQ * CIN;
  for (int e = t; e < 130 * 4; e += 256) {
    int r = e >> 2, c8 = (e & 3) * 8;
    int gl = l0 - 2 + r;
    bf16x8 v;
    if (gl >= 0 && gl < LSEQ) {
      const float* p = fi1b + (size_t)gl * CT + CIN + c8;
#pragma unroll
      for (int jj = 0; jj < 8; ++jj) {
        float f = sc1[CIN + c8 + jj] * p[jj] + sh1[CIN + c8 + jj];
        if (fi1Relu) f = fmaxf(f, 0.f);
        v[jj] = (short)f2bf(f);
      }
    } else {
#pragma unroll
      for (int jj = 0; jj < 8; ++jj) v[jj] = 0;
    }
    *reinterpret_cast<bf16x8*>(&X1[r * 40 + c8]) = v;
  }
  for (int e = t; e < CIN * 12; e += 256) {
    int co = e / 12, kc = (e - co * 12) * 8;
    int dt = kc >> 5, j0 = kc & 31;
    bf16x8 v;
#pragma unroll
    for (int jj = 0; jj < 8; ++jj)
      v[jj] = (short)f2bf(F[((size_t)(j0 + jj) * CIN + co) * 3 + (2 - dt)]);
    *reinterpret_cast<bf16x8*>(&sWT[co * 104 + kc]) = v;
  }
  for (int e = t; e < 32 * (KPAD / 8); e += 256) {
    int co = e / (KPAD / 8), kc = (e - co * (KPAD / 8)) * 8;
    int dt = kc / CIN, ci = kc - dt * CIN;
    bf16x8 v;
    if (dt < 3) {
#pragma unroll
      for (int jj = 0; jj < 8; ++jj)
        v[jj] = (short)f2bf(F[((size_t)co * CIN + ci + jj) * 3 + dt]);
    } else {
#pragma unroll
      for (int jj = 0; jj < 8; ++jj) v[jj] = 0;
    }
    *reinterpret_cast<bf16x8*>(&sWC[co * KROWP + kc]) = v;
  }
  for (int e = t; e < 3 * (CINP / 8); e += 256) {
    int r = 128 + e / (CINP / 8), c8 = (e % (CINP / 8)) * 8;
    bf16x8 z;
#pragma unroll
    for (int jj = 0; jj < 8; ++jj) z[jj] = 0;
    *reinterpret_cast<bf16x8*>(&sS[r * CINP + c8]) = z;
  }
  __syncthreads();

  int wv = t >> 6, lane = t & 63, col = lane & 15, grp = lane >> 4;
  float cV = cs[0];

  // phase 2: convT -> s (sS rows 0..127, gl = l0-1+sr)
  {
    f32x4 accT[MFT][2];
#pragma unroll
    for (int m = 0; m < MFT; ++m)
#pragma unroll
      for (int nf = 0; nf < 2; ++nf) accT[m][nf] = (f32x4){0.f, 0.f, 0.f, 0.f};
#pragma unroll
    for (int ks = 0; ks < 3; ++ks) {
      bf16x8 bA = *reinterpret_cast<const bf16x8*>(&X1[(wv * 32 + col + ks) * 40 + grp * 8]);
      bf16x8 bB = *reinterpret_cast<const bf16x8*>(&X1[(wv * 32 + 16 + col + ks) * 40 + grp * 8]);
#pragma unroll
      for (int m = 0; m < MFT; ++m) {
        bf16x8 af = *reinterpret_cast<const bf16x8*>(&sWT[(m * 16 + col) * 104 + ks * 32 + grp * 8]);
        accT[m][0] = __builtin_amdgcn_mfma_f32_16x16x32_bf16(af, bA, accT[m][0], 0, 0, 0);
        accT[m][1] = __builtin_amdgcn_mfma_f32_16x16x32_bf16(af, bB, accT[m][1], 0, 0, 0);
      }
    }
#pragma unroll
    for (int nf = 0; nf < 2; ++nf) {
      int sr = wv * 32 + nf * 16 + col;
      int gl = l0 - 1 + sr;
      bool v = (gl >= 0 && gl < LSEQ);
#pragma unroll
      for (int m = 0; m < MFT; ++m) {
        int c0 = m * 16 + grp * 4;
        f32x4 sv = {0.f, 0.f, 0.f, 0.f};
        if (v) {
          f32x4 base = *reinterpret_cast<const f32x4*>(&fi1b[(size_t)gl * CT + c0]);
          f32x4 pv = *reinterpret_cast<const f32x4*>(&fPb[(size_t)gl * CIN + c0]);
#pragma unroll
          for (int i = 0; i < 4; ++i) {
            float tbv = sc1[c0 + i] * base[i] + sh1[c0 + i];
            if (fi1Relu) tbv = fmaxf(tbv, 0.f);
            float t2v = tbv + accT[m][nf][i];
            float fp = scP[c0 + i] * pv[i] + shP[c0 + i];
            if (fPRelu) fp = fmaxf(fp, 0.f);
            sv[i] = t2v - fp;
          }
        }
        *reinterpret_cast<unsigned int*>(&sS[sr * CINP + c0]) = packbf2(sv[0], sv[1]);
        *reinterpret_cast<unsigned int*>(&sS[sr * CINP + c0 + 2]) = packbf2(sv[2], sv[3]);
      }
    }
  }
  __syncthreads();

  // phase 3: conv(s) + epilogue (tail)
  bf16x8 aW[2][KSTEPS];
#pragma unroll
  for (int m = 0; m < 2; ++m)
#pragma unroll
    for (int ks = 0; ks < KSTEPS; ++ks)
      aW[m][ks] = *reinterpret_cast<const bf16x8*>(&sWC[(m * 16 + col) * KROWP + ks * 32 + grp * 8]);

  f32x4 accC[2][2];
#pragma unroll
  for (int m = 0; m < 2; ++m)
#pragma unroll
    for (int nf = 0; nf < 2; ++nf) accC[m][nf] = (f32x4){0.f, 0.f, 0.f, 0.f};
#pragma unroll
  for (int ks = 0; ks < KSTEPS; ++ks) {
    int kkb = ks * 32 + grp * 8;
    int dt = kkb / CIN, ci = kkb - dt * CIN;
#pragma unroll
    for (int nf = 0; nf < 2; ++nf) {
      int row = wv * 32 + nf * 16 + col + dt;
      bf16x8 bfrag = *reinterpret_cast<const bf16x8*>(&sS[row * CINP + ci]);
      accC[0][nf] = __builtin_amdgcn_mfma_f32_16x16x32_bf16(aW[0][ks], bfrag, accC[0][nf], 0, 0, 0);
      accC[1][nf] = __builtin_amdgcn_mfma_f32_16x16x32_bf16(aW[1][ks], bfrag, accC[1][nf], 0, 0, 0);
    }
  }

  float* Pb = P + (size_t)n * LSEQ * CT;
  float ts1[2][4], ts2[2][4];
#pragma unroll
  for (int m = 0; m < 2; ++m)
#pragma unroll
    for (int i = 0; i < 4; ++i) { ts1[m][i] = 0.f; ts2[m][i] = 0.f; }

#pragma unroll
  for (int nf = 0; nf < 2; ++nf) {
    int osr = wv * 32 + nf * 16 + col;
    int gl = l0 + osr;
    bool owned = (osr < TS) && (gl < LSEQ);
#pragma unroll
    for (int m = 0; m < 2; ++m) {
      int ch0 = CIN + m * 16 + grp * 4;
      f32x4 f1v = {0.f, 0.f, 0.f, 0.f};
      if (owned) {
        f1v = *reinterpret_cast<const f32x4*>(&fi1b[(size_t)gl * CT + ch0]);
#pragma unroll
        for (int i = 0; i < 4; ++i) {
          float f = sc1[ch0 + i] * f1v[i] + sh1[ch0 + i];
          if (fi1Relu) f = fmaxf(f, 0.f);
          f1v[i] = f;
        }
      }
      f32x4 pre4;
#pragma unroll
      for (int i = 0; i < 4; ++i) {
        float pv = f1v[i] - cV * accC[m][nf][i] + sbv[ch0 + i];
        pre4[i] = pv;
        if (owned) { ts1[m][i] += pv; ts2[m][i] += pv * pv; }
      }
      if (owned) *reinterpret_cast<f32x4*>(&Pb[(size_t)gl * CT + ch0]) = pre4;
    }
  }
#pragma unroll
  for (int m = 0; m < 2; ++m)
#pragma unroll
    for (int i = 0; i < 4; ++i) {
      float s1 = ts1[m][i], s2 = ts2[m][i];
      s1 += __shfl_xor(s1, 1); s2 += __shfl_xor(s2, 1);
      s1 += __shfl_xor(s1, 2); s2 += __shfl_xor(s2, 2);
      s1 += __shfl_xor(s1, 4); s2 += __shfl_xor(s2, 4);
      s1 += __shfl_xor(s1, 8); s2 += __shfl_xor(s2, 8);
      if (col == 0) {
        int ch = CIN + m * 16 + grp * 4 + i;
        atomicAdd(&lstat[2 * ch], s1);
        atomicAdd(&lstat[2 * ch + 1], s2);
      }
    }

  // head: pre = act1(fi1) - c*s + bv (s from sS, row = site+1)
  {
    const int Q = CIN / 4;
    const int SPT = 256 / Q;
    int quad = t % Q, srow = t / Q;
    if (srow < SPT) {
      int c0 = quad * 4;
      float hb1[4] = {0.f, 0.f, 0.f, 0.f}, hb2[4] = {0.f, 0.f, 0.f, 0.f};
      for (int site = srow; site < TS; site += SPT) {
        int gl = l0 + site;
        if (gl >= LSEQ) break;
        float sv[4];
#pragma unroll
        for (int j = 0; j < 4; ++j) sv[j] = bf2f((unsigned short)sS[(site + 1) * CINP + c0 + j]);
        f32x4 f1 = *reinterpret_cast<const f32x4*>(&fi1b[(size_t)gl * CT + c0]);
        f32x4 pr;
#pragma unroll
        for (int j = 0; j < 4; ++j) {
          float f = sc1[c0 + j] * f1[j] + sh1[c0 + j];
          if (fi1Relu) f = fmaxf(f, 0.f);
          pr[j] = f - cV * sv[j] + sbv[c0 + j];
        }
        *reinterpret_cast<f32x4*>(&Pb[(size_t)gl * CT + c0]) = pr;
#pragma unroll
        for (int j = 0; j < 4; ++j) { hb1[j] += pr[j]; hb2[j] += pr[j] * pr[j]; }
      }
#pragma unroll
      for (int j = 0; j < 4; ++j) {
        atomicAdd(&lstat[2 * (c0 + j)], hb1[j]);
        atomicAdd(&lstat[2 * (c0 + j) + 1], hb2[j]);
      }
    }
  }
  __syncthreads();
  float* slot = statsOut + (n & (NSLOT - 1)) * SLOTW;
  for (int ch = t; ch < CT; ch += 256) {
    atomicAdd(&slot[2 * ch], lstat[2 * ch]);
    atomicAdd(&slot[2 * ch + 1], lstat[2 * ch + 1]);
  }
}

// eSE fused: mean over l + 1x1 conv + hsigmoid -> am[n][c]
__global__ __launch_bounds__(256) void ese_fused(
    const float* __restrict__ z, const float* __restrict__ stats,
    const float* __restrict__ g, const float* __restrict__ b,
    const float* __restrict__ W, const float* __restrict__ eb,
    float* __restrict__ am)
{
  __shared__ float sc[112], sh[112];
  __shared__ float red[224];
  __shared__ float smL[112];
  int n = blockIdx.x, t = threadIdx.x;
  load_affine16(stats, g, b, sc, sh, 112);
  __syncthreads();
  float acc = 0.f;
  if (t < 224) {
    int c = t % 112, p = t / 112;
    const float* zb = z + (size_t)n * LSEQ * 112;
    float scv = sc[c], shv = sh[c];
    for (int l = p; l < LSEQ; l += 2)
      acc += fmaxf(scv * zb[(size_t)l * 112 + c] + shv, 0.f);
    red[t] = acc;
  }
  __syncthreads();
  if (t < 112) smL[t] = (red[t] + red[t + 112]) * (1.f / LSEQ);
  __syncthreads();
  if (t < 112) {
    float a = eb[t] + 3.0f;
    for (int cc = 0; cc < 112; ++cc) a = fmaf(smL[cc], W[t * 112 + cc], a);
    a = fminf(fmaxf(a, 0.f), 6.f) * (1.f / 6.f);
    am[n * 112 + t] = a;
  }
}

// ---- fc1 path (verified) ----
__global__ __launch_bounds__(256) void zb_pack(
    const float* __restrict__ P3, const float* __restrict__ stats,
    const float* __restrict__ g, const float* __restrict__ b,
    const float* __restrict__ am, unsigned short* __restrict__ zb)
{
  __shared__ float sc[112], sh[112];
  __shared__ unsigned short sT[112 * 72];
  int t = threadIdx.x;
  int lt = blockIdx.x, n = blockIdx.y;
  int l0 = lt * 64;
  load_affine16(stats, g, b, sc, sh, 112);
  __syncthreads();
  const float* zr = P3 + ((size_t)n * LSEQ + l0) * 112;
  const float* amr = am + n * 112;
  for (int e = t; e < 64 * 112; e += 256) {
    int l = e / 112, c = e - (e / 112) * 112;
    float v = 0.f;
    if (l0 + l < LSEQ) v = fmaxf(sc[c] * zr[(size_t)l * 112 + c] + sh[c], 0.f) * amr[c];
    sT[c * 72 + l] = f2bf(v);
  }
  __syncthreads();
  unsigned short* zo = zb + (size_t)n * FC1K;
  for (int e = t; e < 112 * 8; e += 256) {
    int c = e >> 3, seg = e & 7;
    int l = seg * 8;
    int gl = l0 + l;
    if (gl >= LSEQ) continue;
    if (gl + 8 <= LSEQ) {
      bf16x8 v = *reinterpret_cast<const bf16x8*>(&sT[c * 72 + l]);
      *reinterpret_cast<bf16x8*>(&zo[(size_t)c * LSEQ + gl]) = v;
    } else {
      for (int jj = 0; jj < 8 && gl + jj < LSEQ; ++jj)
        zo[(size_t)c * LSEQ + gl + jj] = sT[c * 72 + l + jj];
    }
  }
}

__global__ __launch_bounds__(256) void wb_pack(const float* __restrict__ w1,
                                               unsigned short* __restrict__ wb)
{
  size_t i = (size_t)blockIdx.x * 256 + threadIdx.x;
  if (i >= (size_t)128 * FC1K / 8) return;
  const float* p = w1 + i * 8;
  bf16x8 v;
#pragma unroll
  for (int jj = 0; jj < 8; ++jj) v[jj] = (short)f2bf(p[jj]);
  *reinterpret_cast<bf16x8*>(&wb[i * 8]) = v;
}

__global__ __launch_bounds__(256) void fc1_mfma(
    const unsigned short* __restrict__ zb,
    const unsigned short* __restrict__ wb,
    float* __restrict__ parts)
{
  const int SLOT = 104;
  __shared__ __align__(16) unsigned short sA[128 * SLOT];
  __shared__ __align__(16) unsigned short sB[128 * SLOT];
  int t = threadIdx.x, b = blockIdx.x;
  int k0 = b * KCH;
  int wv = t >> 6, lane = t & 63, col = lane & 15, grp = lane >> 4;
  int jq = (wv >> 1) * 64, nq = (wv & 1) * 64;

  f32x4 acc[4][4];
#pragma unroll
  for (int m = 0; m < 4; ++m)
#pragma unroll
    for (int nn = 0; nn < 4; ++nn) acc[m][nn] = (f32x4){0.f, 0.f, 0.f, 0.f};

#pragma unroll
  for (int half = 0; half < 2; ++half) {
    int kh = k0 + half * 96;
    int kwid = half ? (KCH - 96) : 96;
    int nslots = half ? 8 : 12;
    __syncthreads();
    for (int e = t; e < 128 * 12; e += 256) {
      int row = e / 12, g2 = e - (e / 12) * 12;
      int kk = g2 * 8;
      bf16x8 va = {0, 0, 0, 0, 0, 0, 0, 0}, vb2 = va;
      if (g2 < nslots) {
        va = *reinterpret_cast<const bf16x8*>(&wb[(size_t)row * FC1K + kh + kk]);
        vb2 = *reinterpret_cast<const bf16x8*>(&zb[(size_t)row * FC1K + kh + kk]);
#pragma unroll
        for (int jj = 0; jj < 8; ++jj)
          if (kk + jj >= kwid) { va[jj] = 0; vb2[jj] = 0; }
      }
      *reinterpret_cast<bf16x8*>(&sA[row * SLOT + kk]) = va;
      *reinterpret_cast<bf16x8*>(&sB[row * SLOT + kk]) = vb2;
    }
    __syncthreads();
    int ksteps = half ? 2 : 3;
    for (int ks = 0; ks < ksteps; ++ks) {
      bf16x8 af[4], bfr[4];
#pragma unroll
      for (int m = 0; m < 4; ++m)
        af[m] = *reinterpret_cast<const bf16x8*>(&sA[(jq + m * 16 + col) * SLOT + ks * 32 + grp * 8]);
#pragma unroll
      for (int nn = 0; nn < 4; ++nn)
        bfr[nn] = *reinterpret_cast<const bf16x8*>(&sB[(nq + nn * 16 + col) * SLOT + ks * 32 + grp * 8]);
#pragma unroll
      for (int m = 0; m < 4; ++m)
#pragma unroll
        for (int nn = 0; nn < 4; ++nn)
          acc[m][nn] = __builtin_amdgcn_mfma_f32_16x16x32_bf16(af[m], bfr[nn], acc[m][nn], 0, 0, 0);
    }
  }
  float* pb = parts + (size_t)b * 16384;
#pragma unroll
  for (int nn = 0; nn < 4; ++nn)
#pragma unroll
    for (int m = 0; m < 4; ++m)
      *reinterpret_cast<f32x4*>(&pb[(nq + nn * 16 + col) * 128 + jq + m * 16 + grp * 4]) = acc[m][nn];
}

__global__ __launch_bounds__(256) void fc1_red(const float* __restrict__ parts,
                                               float* __restrict__ y1)
{
  int o = blockIdx.x * 256 + threadIdx.x;
  float s = 0.f;
  for (int b = 0; b < NKBLK; ++b) s += parts[(size_t)b * 16384 + o];
  y1[o] = s;
}

__global__ __launch_bounds__(128) void fc2_lsm(const float* __restrict__ y1,
                                               const float* __restrict__ b1,
                                               const float* __restrict__ w2,
                                               const float* __restrict__ b2,
                                               float* __restrict__ out)
{
  int n = blockIdx.x;
  int t = threadIdx.x;
  __shared__ float part[10][128];
  float v = fmaxf(y1[n * 128 + t] + b1[t], 0.f);
#pragma unroll
  for (int k = 0; k < 10; ++k) part[k][t] = v * w2[k * 128 + t];
  __syncthreads();
  for (int st = 64; st > 0; st >>= 1) {
    if (t < st) {
#pragma unroll
      for (int k = 0; k < 10; ++k) part[k][t] += part[k][t + st];
    }
    __syncthreads();
  }
  if (t == 0) {
    float lg[10];
    float mx = -1e30f;
#pragma unroll
    for (int k = 0; k < 10; ++k) { lg[k] = part[k][0] + b2[k]; mx = fmaxf(mx, lg[k]); }
    float s = 0.f;
#pragma unroll
    for (int k = 0; k < 10; ++k) s += expf(lg[k] - mx);
    float ls = logf(s) + mx;
#pragma unroll
    for (int k = 0; k < 10; ++k) {
      out[n * 10 + k] = lg[k] - ls;
      out[1280 + n * 10 + k] = lg[k];
    }
  }
}

extern "C" void kernel_launch(void* const* d_in, const int* in_sizes, int n_in,
                              void* d_out, int out_size, void* d_ws, size_t ws_size,
                              hipStream_t stream)
{
  (void)in_sizes; (void)n_in; (void)out_size; (void)ws_size;
  const float* x       = (const float*)d_in[0];
  const float* filter0 = (const float*)d_in[1];
  const float* b0      = (const float*)d_in[2];
  const float* bn0_g   = (const float*)d_in[3];
  const float* bn0_b   = (const float*)d_in[4];
  const float* ese_w   = (const float*)d_in[5];
  const float* ese_b   = (const float*)d_in[6];
  const float* fc1_w   = (const float*)d_in[7];
  const float* fc1_b   = (const float*)d_in[8];
  const float* fc2_w   = (const float*)d_in[9];
  const float* fc2_b   = (const float*)d_in[10];
  const float* F[3]    = {(const float*)d_in[11], (const float*)d_in[16], (const float*)d_in[21]};
  const float* bv[3]   = {(const float*)d_in[12], (const float*)d_in[17], (const float*)d_in[22]};
  const float* g1[3]   = {(const float*)d_in[13], (const float*)d_in[18], (const float*)d_in[23]};
  const float* be1[3]  = {(const float*)d_in[14], (const float*)d_in[19], (const float*)d_in[24]};
  const float* cs[3]   = {(const float*)d_in[15], (const float*)d_in[20], (const float*)d_in[25]};

  const size_t NL = (size_t)NBATCH * LSEQ;
  const int SLOTSZ = NSLOT * SLOTW;          // 4096 floats per stage
  float* wsf = (float*)d_ws;
  size_t o = 0;
  float* SS  = wsf + o;  o += 13 * SLOTSZ;
  float* y1  = wsf + o;  o += 128 * 128;
  float* wsbF = wsf + o; o += 16 * 868;      // stem W bf16 (16*1736 ushorts)
  float* P0  = wsf + o;  o += NL * 16;
  float* P3A = wsf + o;  o += NL * 112;
  float* P3B = wsf + o;  o += NL * 112;
  float* am  = wsf + o;  o += 128 * 112;
  size_t reuse0 = o;             // P1,P2,R1,R2 region = NL*256 floats
  float* P1  = wsf + o;  o += NL * 48;
  float* P2  = wsf + o;  o += NL * 80;
  float* R1  = wsf + o;  o += NL * 48;
  float* R2  = wsf + o;  o += NL * 80;

  unsigned short* wsb = (unsigned short*)wsbF;
  // fc1 scratch aliases P1/P2/R1/R2 (dead at fc1 time): 8.23M floats <= NL*256
  unsigned short* zb = (unsigned short*)(wsf + reuse0);
  unsigned short* wb = zb + (size_t)128 * FC1K;
  float* parts = wsf + reuse0 + (size_t)128 * FC1K;

  hipMemsetAsync(SS, 0, 13 * SLOTSZ * sizeof(float), stream);

  // ---- stem W pre-pack + stem -> P0 + stats slot 0
  wstem_pack<<<(16 * 868 + 255) / 256, 256, 0, stream>>>(filter0, wsb);
  stem_mfma<<<dim3(4, 128), 256, 0, stream>>>(x, wsb, b0, P0, SS);

  // ---- init stages (MODE 0)
  float* s1 = SS + 1 * SLOTSZ;
  ista_stage<16, 0><<<dim3(3, 128), 256, 0, stream>>>(
      nullptr, P0, SS, bn0_g, bn0_b, 0,
      nullptr, nullptr, nullptr, nullptr, 0,
      F[0], cs[0], bv[0], P1, s1);
  float* s2 = SS + 2 * SLOTSZ;
  ista_stage<48, 0><<<dim3(3, 128), 256, 0, stream>>>(
      nullptr, P1, s1, g1[0], be1[0], 1,
      nullptr, nullptr, nullptr, nullptr, 0,
      F[1], cs[1], bv[1], P2, s2);
  float* s3 = SS + 3 * SLOTSZ;
  ista_stage<80, 0><<<dim3(3, 128), 256, 0, stream>>>(
      nullptr, P2, s2, g1[1], be1[1], 1,
      nullptr, nullptr, nullptr, nullptr, 0,
      F[2], cs[2], bv[2], P3A, s3);

  float* P3cur = P3A;
  float* P3nxt = P3B;
  const float* st3 = s3;

  // ---- unfolding
  for (int u = 0; u < 3; ++u) {
    bwd_fused<<<dim3(3, 128), 256, 0, stream>>>(
        P3cur, st3, g1[2], be1[2], F[2], F[1], R2, R1);
    float* sA = SS + (4 + 3 * u) * SLOTSZ;
    fwd_fused<16><<<dim3(3, 128), 256, 0, stream>>>(
        R1, nullptr, nullptr, nullptr, 0,
        P0, SS, bn0_g, bn0_b, 0,
        F[0], cs[0], bv[0], P1, sA);
    float* sB = SS + (5 + 3 * u) * SLOTSZ;
    fwd_fused<48><<<dim3(3, 128), 256, 0, stream>>>(
        R2, nullptr, nullptr, nullptr, 0,
        P1, sA, g1[0], be1[0], 1,
        F[1], cs[1], bv[1], P2, sB);
    float* sC = SS + (6 + 3 * u) * SLOTSZ;
    fwd_fused<80><<<dim3(3, 128), 256, 0, stream>>>(
        P3cur, st3, g1[2], be1[2], 1,
        P2, sB, g1[1], be1[1], 1,
        F[2], cs[2], bv[2], P3nxt, sC);
    st3 = sC;
    float* tmp = P3cur; P3cur = P3nxt; P3nxt = tmp;
  }

  // ---- eSE (fused mean + act)
  ese_fused<<<128, 256, 0, stream>>>(P3cur, st3, g1[2], be1[2], ese_w, ese_b, am);

  // ---- fc1 (bf16 MFMA split-K) + fc2 + log_softmax
  wb_pack<<<(int)(((size_t)128 * FC1K / 8 + 255) / 256), 256, 0, stream>>>(fc1_w, wb);
  zb_pack<<<dim3(5, 128), 256, 0, stream>>>(P3cur, st3, g1[2], be1[2], am, zb);
  fc1_mfma<<<NKBLK, 256, 0, stream>>>(zb, wb, parts);
  fc1_red<<<64, 256, 0, stream>>>(parts, y1);
  fc2_lsm<<<128, 128, 0, stream>>>(y1, fc1_b, fc2_w, fc2_b, (float*)d_out);
}

// Round 15
// 403.102 us; speedup vs baseline: 1.1477x; 1.0831x over previous
//
#include <hip/hip_runtime.h>
#include <hip/hip_bf16.h>

#define LSEQ 318
#define NBATCH 128
#define NE (NBATCH * LSEQ)
#define FC1K 35616
#define NKBLK 224   // 224 * 159 == 35616
#define KCH 159
#define NSLOT 16
#define SLOTW 256   // floats per slot row

typedef __attribute__((ext_vector_type(4))) float f32x4;
typedef __attribute__((ext_vector_type(8))) short bf16x8;
typedef __attribute__((ext_vector_type(4))) unsigned int u32x4;

__device__ inline unsigned short f2bf(float v) {
  unsigned int a = __builtin_bit_cast(unsigned int, v);
  return (unsigned short)((a + 0x7FFFu + ((a >> 16) & 1u)) >> 16);
}
__device__ inline float bf2f(unsigned short u) {
  unsigned int a = ((unsigned int)u) << 16;
  return __builtin_bit_cast(float, a);
}
__device__ inline unsigned int packbf2(float lo, float hi) {
  return (unsigned int)f2bf(lo) | ((unsigned int)f2bf(hi) << 16);
}
__device__ inline bf16x8 ldfrag(const unsigned int* xb, int j0) {
  u32x4 uu = {xb[j0], xb[j0 + 1], xb[j0 + 2], xb[j0 + 3]};
  return __builtin_bit_cast(bf16x8, uu);
}

// per-channel affine from NSLOT partial stats
__device__ inline void load_affine16(const float* pstat, const float* g, const float* b,
                                     float* sc, float* sh, int C) {
  for (int c = threadIdx.x; c < C; c += blockDim.x) {
    if (pstat) {
      float s1 = 0.f, s2 = 0.f;
#pragma unroll
      for (int s = 0; s < NSLOT; ++s) {
        s1 += pstat[s * SLOTW + 2 * c];
        s2 += pstat[s * SLOTW + 2 * c + 1];
      }
      float m = s1 * (1.f / NE);
      float var = s2 * (1.f / NE) - m * m;
      float sv = g[c] * rsqrtf(var + 1e-5f);
      sc[c] = sv; sh[c] = b[c] - m * sv;
    } else { sc[c] = 1.f; sh[c] = 0.f; }
  }
}

// pre-pack stem W (f32 [16][1700]) -> bf16 [16][1736] (zero-pad tail)
__global__ __launch_bounds__(256) void wstem_pack(const float* __restrict__ w,
                                                  unsigned short* __restrict__ wsb)
{
  int i = blockIdx.x * 256 + threadIdx.x;  // dword index over 16*868
  if (i >= 16 * 868) return;
  int co = i / 868, kd = (i - co * 868) * 2;
  float v0 = (kd < 1700) ? w[co * 1700 + kd] : 0.f;
  float v1 = (kd + 1 < 1700) ? w[co * 1700 + kd + 1] : 0.f;
  ((unsigned int*)wsb)[i] = packbf2(v0, v1);
}

// ---------------------------------------------------------------------------
// Stem (verified, W pre-packed): conv1d + b0 + maxpool16 -> P0 [n][l][16]
// channels-last + slot stats. Rolling rings, p<10, reload p<9.
// ---------------------------------------------------------------------------
__global__ __launch_bounds__(256) void stem_mfma(
    const float* __restrict__ x, const unsigned short* __restrict__ wsb,
    const float* __restrict__ b0, float* __restrict__ pre,
    float* __restrict__ pstat)
{
  __shared__ __align__(16) unsigned short wsh[16 * 1736];
  __shared__ __align__(16) unsigned int xs2[2 * 1520];
  int t = threadIdx.x;
  int pblk = blockIdx.x, n = blockIdx.y;
  int P0 = pblk * 1280;

  for (int e = t; e < 16 * 217; e += 256)
    *reinterpret_cast<bf16x8*>(&wsh[e * 8]) = *reinterpret_cast<const bf16x8*>(&wsb[e * 8]);
  const float* xn = x + (size_t)n * 5087;
  for (int i = t; i < 1520; i += 256) {
    int m = 2 * i;
    int g0 = P0 - 850 + m;
    float v0 = (g0 >= 0 && g0 < 5087) ? xn[g0] : 0.f;
    float v1 = (g0 + 1 >= 0 && g0 + 1 < 5087) ? xn[g0 + 1] : 0.f;
    float v2 = (g0 + 2 >= 0 && g0 + 2 < 5087) ? xn[g0 + 2] : 0.f;
    xs2[i] = packbf2(v0, v1);
    xs2[1520 + i] = packbf2(v1, v2);
  }
  __syncthreads();

  int wv = t >> 6, lane = t & 63;
  int row = lane & 15, grp = lane >> 4;
  int tb = wv * 20;
  const unsigned int* xb = xs2 + (row & 1) * 1520;
  int eb0 = 16 * tb + row + 8 * grp;

  f32x4 acc[20];
#pragma unroll
  for (int i = 0; i < 20; ++i) acc[i] = (f32x4){0.f, 0.f, 0.f, 0.f};

  for (int kg = 0; kg < 6; ++kg) {
    bf16x8 bf[9];
#pragma unroll
    for (int c = 0; c < 9; ++c)
      bf[c] = *reinterpret_cast<const bf16x8*>(&wsh[row * 1736 + kg * 288 + c * 32 + grp * 8]);
    int eb = eb0 + 288 * kg;
    bf16x8 re[9], ro[9];
#pragma unroll
    for (int c = 0; c < 9; ++c) {
      re[c] = ldfrag(xb, (eb + 32 * c) >> 1);
      ro[c] = ldfrag(xb, (eb + 16 + 32 * c) >> 1);
    }
#pragma unroll
    for (int p = 0; p < 10; ++p) {
#pragma unroll
      for (int c = 0; c < 9; ++c)
        acc[2 * p] = __builtin_amdgcn_mfma_f32_16x16x32_bf16(re[c], bf[c], acc[2 * p], 0, 0, 0);
#pragma unroll
      for (int c = 0; c < 9; ++c)
        acc[2 * p + 1] = __builtin_amdgcn_mfma_f32_16x16x32_bf16(ro[c], bf[c], acc[2 * p + 1], 0, 0, 0);
      if (p < 9) {
#pragma unroll
        for (int c = 0; c < 8; ++c) { re[c] = re[c + 1]; ro[c] = ro[c + 1]; }
        re[8] = ldfrag(xb, (eb + 32 * p + 288) >> 1);
        ro[8] = ldfrag(xb, (eb + 32 * p + 304) >> 1);
      }
    }
  }

  float b0v = b0[row];
  float ssum = 0.f, ssq = 0.f;
#pragma unroll
  for (int mt = 0; mt < 20; ++mt) {
    int q = pblk * 80 + tb + mt;
    f32x4 d = acc[mt];
    float m = fmaxf(fmaxf(d[0], d[1]), fmaxf(d[2], d[3]));
    m = fmaxf(m, __shfl_xor(m, 16));
    m = fmaxf(m, __shfl_xor(m, 32));
    if (lane < 16 && q < LSEQ) {
      float val = m + b0v;
      pre[((size_t)n * LSEQ + q) * 16 + lane] = val;
      ssum += val; ssq += val * val;
    }
  }
  if (lane < 16) {
    float* slot = pstat + (n & (NSLOT - 1)) * SLOTW;
    atomicAdd(&slot[2 * lane], ssum);
    atomicAdd(&slot[2 * lane + 1], ssq);
  }
}

// ---------------------------------------------------------------------------
// ista_stage (verified; MODE 0 only), slot stats.
// ---------------------------------------------------------------------------
template <int CIN, int MODE>
__global__ __launch_bounds__(256) void ista_stage(
    const float* __restrict__ t2,
    const float* __restrict__ fiP, const float* __restrict__ fiStats,
    const float* __restrict__ fiG, const float* __restrict__ fiB, int fiRelu,
    const float* __restrict__ fi1P, const float* __restrict__ fi1Stats,
    const float* __restrict__ fi1G, const float* __restrict__ fi1B, int fi1Relu,
    const float* __restrict__ F, const float* __restrict__ cs,
    const float* __restrict__ bv,
    float* __restrict__ P, float* __restrict__ statsOut)
{
  const int CT = CIN + 32;
  const int K3 = 3 * CIN;
  const int KPAD = ((K3 + 31) / 32) * 32;
  const int KROWP = KPAD + (((KPAD / 8) % 2 == 0) ? 8 : 0);
  const int CINP = CIN + (((CIN / 8) % 2 == 0) ? 8 : 0);
  const int TS = 128, ROWS = TS + 3;
  const int KSTEPS = KPAD / 32;

  __shared__ __align__(16) unsigned short sW[32 * KROWP];
  __shared__ __align__(16) unsigned short sS[ROWS * CINP];
  __shared__ float scF[CIN], shF[CIN];
  __shared__ float sc1[CT], sh1[CT], sbv[CT];
  __shared__ float lstat[2 * CT];

  int t = threadIdx.x;
  int l0 = blockIdx.x * TS, n = blockIdx.y;

  load_affine16(fiStats, fiG, fiB, scF, shF, CIN);
  load_affine16(fi1Stats, fi1G, fi1B, sc1, sh1, CT);
  for (int c = t; c < CT; c += 256) sbv[c] = bv[c];
  for (int c = t; c < 2 * CT; c += 256) lstat[c] = 0.f;
  __syncthreads();

  for (int e = t; e < 32 * (KPAD / 8); e += 256) {
    int co = e / (KPAD / 8), kc = (e - co * (KPAD / 8)) * 8;
    int dt = kc / CIN, ci = kc - dt * CIN;
    bf16x8 v;
    if (dt < 3) {
#pragma unroll
      for (int jj = 0; jj < 8; ++jj)
        v[jj] = (short)f2bf(F[((size_t)co * CIN + ci + jj) * 3 + dt]);
    } else {
#pragma unroll
      for (int jj = 0; jj < 8; ++jj) v[jj] = 0;
    }
    *reinterpret_cast<bf16x8*>(&sW[co * KROWP + kc]) = v;
  }
  const float* fib = fiP + (size_t)n * LSEQ * CIN;
  const float* t2b = MODE ? (t2 + (size_t)n * LSEQ * CIN) : nullptr;
  const int NCH8 = CIN / 8;
  for (int e = t; e < ROWS * NCH8; e += 256) {
    int r = e / NCH8, c8 = (e - r * NCH8) * 8;
    int gl = l0 - 1 + r;
    bf16x8 v;
    if (gl >= 0 && gl < LSEQ) {
      const float* p = fib + (size_t)gl * CIN + c8;
#pragma unroll
      for (int jj = 0; jj < 8; ++jj) {
        float f = scF[c8 + jj] * p[jj] + shF[c8 + jj];
        if (fiRelu) f = fmaxf(f, 0.f);
        if (MODE) f = t2b[(size_t)gl * CIN + c8 + jj] - f;
        v[jj] = (short)f2bf(f);
      }
    } else {
#pragma unroll
      for (int jj = 0; jj < 8; ++jj) v[jj] = 0;
    }
    *reinterpret_cast<bf16x8*>(&sS[r * CINP + c8]) = v;
  }
  __syncthreads();

  int wv = t >> 6, lane = t & 63, col = lane & 15, grp = lane >> 4;
  float cV = cs[0];

  bf16x8 a[2][KSTEPS];
#pragma unroll
  for (int m = 0; m < 2; ++m)
#pragma unroll
    for (int ks = 0; ks < KSTEPS; ++ks)
      a[m][ks] = *reinterpret_cast<const bf16x8*>(&sW[(m * 16 + col) * KROWP + ks * 32 + grp * 8]);

  f32x4 acc[2][2];
#pragma unroll
  for (int m = 0; m < 2; ++m)
#pragma unroll
    for (int nf = 0; nf < 2; ++nf) acc[m][nf] = (f32x4){0.f, 0.f, 0.f, 0.f};

#pragma unroll
  for (int ks = 0; ks < KSTEPS; ++ks) {
    int kkb = ks * 32 + grp * 8;
    int dt = kkb / CIN, ci = kkb - dt * CIN;
#pragma unroll
    for (int nf = 0; nf < 2; ++nf) {
      int row = wv * 32 + nf * 16 + col + dt;
      bf16x8 bfrag = *reinterpret_cast<const bf16x8*>(&sS[row * CINP + ci]);
      acc[0][nf] = __builtin_amdgcn_mfma_f32_16x16x32_bf16(a[0][ks], bfrag, acc[0][nf], 0, 0, 0);
      acc[1][nf] = __builtin_amdgcn_mfma_f32_16x16x32_bf16(a[1][ks], bfrag, acc[1][nf], 0, 0, 0);
    }
  }

  const float* fi1b = fi1P ? (fi1P + (size_t)n * LSEQ * CT) : nullptr;
  float* Pb = P + (size_t)n * LSEQ * CT;
  float ts1[2][4], ts2[2][4];
#pragma unroll
  for (int m = 0; m < 2; ++m)
#pragma unroll
    for (int i = 0; i < 4; ++i) { ts1[m][i] = 0.f; ts2[m][i] = 0.f; }

#pragma unroll
  for (int nf = 0; nf < 2; ++nf) {
    int siteL = wv * 32 + nf * 16 + col;
    int gl = l0 + siteL;
    bool valid = (gl < LSEQ);
#pragma unroll
    for (int m = 0; m < 2; ++m) {
      int ch0 = CIN + m * 16 + grp * 4;
      f32x4 f1v = {0.f, 0.f, 0.f, 0.f};
      if (MODE && valid) {
        f1v = *reinterpret_cast<const f32x4*>(&fi1b[(size_t)gl * CT + ch0]);
#pragma unroll
        for (int i = 0; i < 4; ++i) {
          float f = sc1[ch0 + i] * f1v[i] + sh1[ch0 + i];
          if (fi1Relu) f = fmaxf(f, 0.f);
          f1v[i] = f;
        }
      }
      f32x4 pre4;
#pragma unroll
      for (int i = 0; i < 4; ++i) {
        float pv = MODE ? (f1v[i] - cV * acc[m][nf][i] + sbv[ch0 + i])
                        : (cV * acc[m][nf][i] + sbv[ch0 + i]);
        pre4[i] = pv;
        if (valid) { ts1[m][i] += pv; ts2[m][i] += pv * pv; }
      }
      if (valid) *reinterpret_cast<f32x4*>(&Pb[(size_t)gl * CT + ch0]) = pre4;
    }
  }
#pragma unroll
  for (int m = 0; m < 2; ++m)
#pragma unroll
    for (int i = 0; i < 4; ++i) {
      float s1 = ts1[m][i], s2 = ts2[m][i];
      s1 += __shfl_xor(s1, 1); s2 += __shfl_xor(s2, 1);
      s1 += __shfl_xor(s1, 2); s2 += __shfl_xor(s2, 2);
      s1 += __shfl_xor(s1, 4); s2 += __shfl_xor(s2, 4);
      s1 += __shfl_xor(s1, 8); s2 += __shfl_xor(s2, 8);
      if (col == 0) {
        int ch = CIN + m * 16 + grp * 4 + i;
        atomicAdd(&lstat[2 * ch], s1);
        atomicAdd(&lstat[2 * ch + 1], s2);
      }
    }

  {
    const int Q = CIN / 4;
    const int SPT = 256 / Q;
    int quad = t % Q, srow = t / Q;
    if (srow < SPT) {
      int c0 = quad * 4;
      float hb1[4] = {0.f, 0.f, 0.f, 0.f}, hb2[4] = {0.f, 0.f, 0.f, 0.f};
      for (int site = srow; site < TS; site += SPT) {
        int gl = l0 + site;
        if (gl >= LSEQ) break;
        float sv[4];
#pragma unroll
        for (int j = 0; j < 4; ++j) sv[j] = bf2f((unsigned short)sS[(site + 1) * CINP + c0 + j]);
        f32x4 pr;
        if (MODE) {
          f32x4 f1 = *reinterpret_cast<const f32x4*>(&fi1b[(size_t)gl * CT + c0]);
#pragma unroll
          for (int j = 0; j < 4; ++j) {
            float f = sc1[c0 + j] * f1[j] + sh1[c0 + j];
            if (fi1Relu) f = fmaxf(f, 0.f);
            pr[j] = f - cV * sv[j] + sbv[c0 + j];
          }
        } else {
#pragma unroll
          for (int j = 0; j < 4; ++j) pr[j] = cV * sv[j] + sbv[c0 + j];
        }
        *reinterpret_cast<f32x4*>(&Pb[(size_t)gl * CT + c0]) = pr;
#pragma unroll
        for (int j = 0; j < 4; ++j) { hb1[j] += pr[j]; hb2[j] += pr[j] * pr[j]; }
      }
#pragma unroll
      for (int j = 0; j < 4; ++j) {
        atomicAdd(&lstat[2 * (c0 + j)], hb1[j]);
        atomicAdd(&lstat[2 * (c0 + j) + 1], hb2[j]);
      }
    }
  }
  __syncthreads();
  float* slot = statsOut + (n & (NSLOT - 1)) * SLOTW;
  for (int ch = t; ch < CT; ch += 256) {
    atomicAdd(&slot[2 * ch], lstat[2 * ch]);
    atomicAdd(&slot[2 * ch + 1], lstat[2 * ch + 1]);
  }
}

// ---------------------------------------------------------------------------
// bwd_fused (verified): R2 = convT80(act(f3)); R1 = convT48(R2). Slot affine.
// ---------------------------------------------------------------------------
__global__ __launch_bounds__(256) void bwd_fused(
    const float* __restrict__ f3P, const float* __restrict__ st3,
    const float* __restrict__ g3, const float* __restrict__ b3,
    const float* __restrict__ F2, const float* __restrict__ F1,
    float* __restrict__ R2, float* __restrict__ R1)
{
  __shared__ __align__(16) unsigned short X3[130 * 40];
  __shared__ __align__(16) unsigned short sW2[80 * 104];
  __shared__ __align__(16) unsigned short sW1[48 * 104];
  __shared__ __align__(16) unsigned short R2t[130 * 40];
  __shared__ __align__(16) float R2h[128 * 52];
  __shared__ float sc3[112], sh3[112];
  int t = threadIdx.x;
  int l0 = blockIdx.x * 126, n = blockIdx.y;
  load_affine16(st3, g3, b3, sc3, sh3, 112);
  __syncthreads();

  const float* f3b = f3P + (size_t)n * LSEQ * 112;
  for (int e = t; e < 130 * 4; e += 256) {
    int r = e >> 2, c8 = (e & 3) * 8;
    int gl = l0 - 2 + r;
    bf16x8 v;
    if (gl >= 0 && gl < LSEQ) {
      const float* p = f3b + (size_t)gl * 112 + 80 + c8;
#pragma unroll
      for (int jj = 0; jj < 8; ++jj)
        v[jj] = (short)f2bf(fmaxf(sc3[80 + c8 + jj] * p[jj] + sh3[80 + c8 + jj], 0.f));
    } else {
#pragma unroll
      for (int jj = 0; jj < 8; ++jj) v[jj] = 0;
    }
    *reinterpret_cast<bf16x8*>(&X3[r * 40 + c8]) = v;
  }
  for (int e = t; e < 80 * 12; e += 256) {
    int co = e / 12, kc = (e - co * 12) * 8;
    int dt = kc >> 5, j0 = kc & 31;
    bf16x8 v;
#pragma unroll
    for (int jj = 0; jj < 8; ++jj)
      v[jj] = (short)f2bf(F2[((size_t)(j0 + jj) * 80 + co) * 3 + (2 - dt)]);
    *reinterpret_cast<bf16x8*>(&sW2[co * 104 + kc]) = v;
  }
  for (int e = t; e < 48 * 12; e += 256) {
    int co = e / 12, kc = (e - co * 12) * 8;
    int dt = kc >> 5, j0 = kc & 31;
    bf16x8 v;
#pragma unroll
    for (int jj = 0; jj < 8; ++jj)
      v[jj] = (short)f2bf(F1[((size_t)(j0 + jj) * 48 + co) * 3 + (2 - dt)]);
    *reinterpret_cast<bf16x8*>(&sW1[co * 104 + kc]) = v;
  }
  if (t < 10) {
    int r = 128 + t / 5, c8 = (t % 5) * 8;
    bf16x8 z;
#pragma unroll
    for (int jj = 0; jj < 8; ++jj) z[jj] = 0;
    *reinterpret_cast<bf16x8*>(&R2t[r * 40 + c8]) = z;
  }
  __syncthreads();

  int wv = t >> 6, lane = t & 63, col = lane & 15, grp = lane >> 4;
  f32x4 acc2[5][2];
#pragma unroll
  for (int m = 0; m < 5; ++m)
#pragma unroll
    for (int nf = 0; nf < 2; ++nf) acc2[m][nf] = (f32x4){0.f, 0.f, 0.f, 0.f};
#pragma unroll
  for (int ks = 0; ks < 3; ++ks) {
    bf16x8 bA = *reinterpret_cast<const bf16x8*>(&X3[(wv * 32 + col + ks) * 40 + grp * 8]);
    bf16x8 bB = *reinterpret_cast<const bf16x8*>(&X3[(wv * 32 + 16 + col + ks) * 40 + grp * 8]);
#pragma unroll
    for (int m = 0; m < 5; ++m) {
      bf16x8 af = *reinterpret_cast<const bf16x8*>(&sW2[(m * 16 + col) * 104 + ks * 32 + grp * 8]);
      acc2[m][0] = __builtin_amdgcn_mfma_f32_16x16x32_bf16(af, bA, acc2[m][0], 0, 0, 0);
      acc2[m][1] = __builtin_amdgcn_mfma_f32_16x16x32_bf16(af, bB, acc2[m][1], 0, 0, 0);
    }
  }
#pragma unroll
  for (int nf = 0; nf < 2; ++nf) {
    int sr = wv * 32 + nf * 16 + col;
    int gl = l0 - 1 + sr;
    bool v = (gl >= 0 && gl < LSEQ);
#pragma unroll
    for (int m = 0; m < 5; ++m) {
      int c0 = m * 16 + grp * 4;
      f32x4 o = {0.f, 0.f, 0.f, 0.f};
      if (v) {
        f32x4 hv = *reinterpret_cast<const f32x4*>(&f3b[(size_t)gl * 112 + c0]);
#pragma unroll
        for (int i = 0; i < 4; ++i)
          o[i] = fmaxf(sc3[c0 + i] * hv[i] + sh3[c0 + i], 0.f) + acc2[m][nf][i];
        *reinterpret_cast<f32x4*>(&R2[((size_t)n * LSEQ + gl) * 80 + c0]) = o;
      }
      if (c0 < 48) {
        *reinterpret_cast<f32x4*>(&R2h[sr * 52 + c0]) = o;
      } else {
        int j = c0 - 48;
        *reinterpret_cast<unsigned int*>(&R2t[sr * 40 + j]) = packbf2(o[0], o[1]);
        *reinterpret_cast<unsigned int*>(&R2t[sr * 40 + j + 2]) = packbf2(o[2], o[3]);
      }
    }
  }
  __syncthreads();

  f32x4 acc1[3][2];
#pragma unroll
  for (int m = 0; m < 3; ++m)
#pragma unroll
    for (int nf = 0; nf < 2; ++nf) acc1[m][nf] = (f32x4){0.f, 0.f, 0.f, 0.f};
#pragma unroll
  for (int ks = 0; ks < 3; ++ks) {
    bf16x8 bA = *reinterpret_cast<const bf16x8*>(&R2t[(wv * 32 + col + ks) * 40 + grp * 8]);
    bf16x8 bB = *reinterpret_cast<const bf16x8*>(&R2t[(wv * 32 + 16 + col + ks) * 40 + grp * 8]);
#pragma unroll
    for (int m = 0; m < 3; ++m) {
      bf16x8 af = *reinterpret_cast<const bf16x8*>(&sW1[(m * 16 + col) * 104 + ks * 32 + grp * 8]);
      acc1[m][0] = __builtin_amdgcn_mfma_f32_16x16x32_bf16(af, bA, acc1[m][0], 0, 0, 0);
      acc1[m][1] = __builtin_amdgcn_mfma_f32_16x16x32_bf16(af, bB, acc1[m][1], 0, 0, 0);
    }
  }
#pragma unroll
  for (int nf = 0; nf < 2; ++nf) {
    int osr = wv * 32 + nf * 16 + col;
    int gl = l0 + osr;
    if (osr < 126 && gl < LSEQ) {
#pragma unroll
      for (int m = 0; m < 3; ++m) {
        int c0 = m * 16 + grp * 4;
        f32x4 h = *reinterpret_cast<const f32x4*>(&R2h[(osr + 1) * 52 + c0]);
        f32x4 o;
#pragma unroll
        for (int i = 0; i < 4; ++i) o[i] = h[i] + acc1[m][nf][i];
        *reinterpret_cast<f32x4*>(&R1[((size_t)n * LSEQ + gl) * 48 + c0]) = o;
      }
    }
  }
}

// ---------------------------------------------------------------------------
// fwd_fused (verified 256-thread TS=126), slot stats.
// ---------------------------------------------------------------------------
template <int CIN>
__global__ __launch_bounds__(256) void fwd_fused(
    const float* __restrict__ fi1P, const float* __restrict__ fi1S,
    const float* __restrict__ fi1G, const float* __restrict__ fi1B, int fi1Relu,
    const float* __restrict__ fPP, const float* __restrict__ fPS,
    const float* __restrict__ fPG, const float* __restrict__ fPB, int fPRelu,
    const float* __restrict__ F, const float* __restrict__ cs,
    const float* __restrict__ bv,
    float* __restrict__ P, float* __restrict__ statsOut)
{
  const int CT = CIN + 32;
  const int K3 = 3 * CIN;
  const int KPAD = ((K3 + 31) / 32) * 32;
  const int KROWP = KPAD + (((KPAD / 8) % 2 == 0) ? 8 : 0);
  const int CINP = CIN + (((CIN / 8) % 2 == 0) ? 8 : 0);
  const int KSTEPS = KPAD / 32;
  const int MFT = CIN / 16;
  const int TS = 126;

  __shared__ __align__(16) unsigned short X1[130 * 40];
  __shared__ __align__(16) unsigned short sS[131 * CINP];
  __shared__ __align__(16) unsigned short sWT[CIN * 104];
  __shared__ __align__(16) unsigned short sWC[32 * KROWP];
  __shared__ float scP[CIN], shP[CIN];
  __shared__ float sc1[CT], sh1[CT], sbv[CT];
  __shared__ float lstat[2 * CT];

  int t = threadIdx.x;
  int l0 = blockIdx.x * TS, n = blockIdx.y;

  load_affine16(fPS, fPG, fPB, scP, shP, CIN);
  load_affine16(fi1S, fi1G, fi1B, sc1, sh1, CT);
  for (int c = t; c < CT; c += 256) sbv[c] = bv[c];
  for (int c = t; c < 2 * CT; c += 256) lstat[c] = 0.f;
  __syncthreads();

  const float* fi1b = fi1P + (size_t)n * LSEQ * CT;
  const float* fPb = fPP + (size_t)n * LSEQ * CIN;
  for (int e = t; e < 130 * 4; e += 256) {
    int r = e >> 2, c8 = (e & 3) * 8;
    int gl = l0 - 2 + r;
    bf16x8 v;
    if (gl >= 0 && gl < LSEQ) {
      const float* p = fi1b + (size_t)gl * CT + CIN + c8;
#pragma unroll
      for (int jj = 0; jj < 8; ++jj) {
        float f = sc1[CIN + c8 + jj] * p[jj] + sh1[CIN + c8 + jj];
        if (fi1Relu) f = fmaxf(f, 0.f);
        v[jj] = (short)f2bf(f);
      }
    } else {
#pragma unroll
      for (int jj = 0; jj < 8; ++jj) v[jj] = 0;
    }
    *reinterpret_cast<bf16x8*>(&X1[r * 40 + c8]) = v;
  }
  for (int e = t; e < CIN * 12; e += 256) {
    int co = e / 12, kc = (e - co * 12) * 8;
    int dt = kc >> 5, j0 = kc & 31;
    bf16x8 v;
#pragma unroll
    for (int jj = 0; jj < 8; ++jj)
      v[jj] = (short)f2bf(F[((size_t)(j0 + jj) * CIN + co) * 3 + (2 - dt)]);
    *reinterpret_cast<bf16x8*>(&sWT[co * 104 + kc]) = v;
  }
  for (int e = t; e < 32 * (KPAD / 8); e += 256) {
    int co = e / (KPAD / 8), kc = (e - co * (KPAD / 8)) * 8;
    int dt = kc / CIN, ci = kc - dt * CIN;
    bf16x8 v;
    if (dt < 3) {
#pragma unroll
      for (int jj = 0; jj < 8; ++jj)
        v[jj] = (short)f2bf(F[((size_t)co * CIN + ci + jj) * 3 + dt]);
    } else {
#pragma unroll
      for (int jj = 0; jj < 8; ++jj) v[jj] = 0;
    }
    *reinterpret_cast<bf16x8*>(&sWC[co * KROWP + kc]) = v;
  }
  for (int e = t; e < 3 * (CINP / 8); e += 256) {
    int r = 128 + e / (CINP / 8), c8 = (e % (CINP / 8)) * 8;
    bf16x8 z;
#pragma unroll
    for (int jj = 0; jj < 8; ++jj) z[jj] = 0;
    *reinterpret_cast<bf16x8*>(&sS[r * CINP + c8]) = z;
  }
  __syncthreads();

  int wv = t >> 6, lane = t & 63, col = lane & 15, grp = lane >> 4;
  float cV = cs[0];

  // phase 2: convT -> s (sS rows 0..127, gl = l0-1+sr)
  {
    f32x4 accT[MFT][2];
#pragma unroll
    for (int m = 0; m < MFT; ++m)
#pragma unroll
      for (int nf = 0; nf < 2; ++nf) accT[m][nf] = (f32x4){0.f, 0.f, 0.f, 0.f};
#pragma unroll
    for (int ks = 0; ks < 3; ++ks) {
      bf16x8 bA = *reinterpret_cast<const bf16x8*>(&X1[(wv * 32 + col + ks) * 40 + grp * 8]);
      bf16x8 bB = *reinterpret_cast<const bf16x8*>(&X1[(wv * 32 + 16 + col + ks) * 40 + grp * 8]);
#pragma unroll
      for (int m = 0; m < MFT; ++m) {
        bf16x8 af = *reinterpret_cast<const bf16x8*>(&sWT[(m * 16 + col) * 104 + ks * 32 + grp * 8]);
        accT[m][0] = __builtin_amdgcn_mfma_f32_16x16x32_bf16(af, bA, accT[m][0], 0, 0, 0);
        accT[m][1] = __builtin_amdgcn_mfma_f32_16x16x32_bf16(af, bB, accT[m][1], 0, 0, 0);
      }
    }
#pragma unroll
    for (int nf = 0; nf < 2; ++nf) {
      int sr = wv * 32 + nf * 16 + col;
      int gl = l0 - 1 + sr;
      bool v = (gl >= 0 && gl < LSEQ);
#pragma unroll
      for (int m = 0; m < MFT; ++m) {
        int c0 = m * 16 + grp * 4;
        f32x4 sv = {0.f, 0.f, 0.f, 0.f};
        if (v) {
          f32x4 base = *reinterpret_cast<const f32x4*>(&fi1b[(size_t)gl * CT + c0]);
          f32x4 pv = *reinterpret_cast<const f32x4*>(&fPb[(size_t)gl * CIN + c0]);
#pragma unroll
          for (int i = 0; i < 4; ++i) {
            float tbv = sc1[c0 + i] * base[i] + sh1[c0 + i];
            if (fi1Relu) tbv = fmaxf(tbv, 0.f);
            float t2v = tbv + accT[m][nf][i];
            float fp = scP[c0 + i] * pv[i] + shP[c0 + i];
            if (fPRelu) fp = fmaxf(fp, 0.f);
            sv[i] = t2v - fp;
          }
        }
        *reinterpret_cast<unsigned int*>(&sS[sr * CINP + c0]) = packbf2(sv[0], sv[1]);
        *reinterpret_cast<unsigned int*>(&sS[sr * CINP + c0 + 2]) = packbf2(sv[2], sv[3]);
      }
    }
  }
  __syncthreads();

  // phase 3: conv(s) + epilogue (tail)
  bf16x8 aW[2][KSTEPS];
#pragma unroll
  for (int m = 0; m < 2; ++m)
#pragma unroll
    for (int ks = 0; ks < KSTEPS; ++ks)
      aW[m][ks] = *reinterpret_cast<const bf16x8*>(&sWC[(m * 16 + col) * KROWP + ks * 32 + grp * 8]);

  f32x4 accC[2][2];
#pragma unroll
  for (int m = 0; m < 2; ++m)
#pragma unroll
    for (int nf = 0; nf < 2; ++nf) accC[m][nf] = (f32x4){0.f, 0.f, 0.f, 0.f};
#pragma unroll
  for (int ks = 0; ks < KSTEPS; ++ks) {
    int kkb = ks * 32 + grp * 8;
    int dt = kkb / CIN, ci = kkb - dt * CIN;
#pragma unroll
    for (int nf = 0; nf < 2; ++nf) {
      int row = wv * 32 + nf * 16 + col + dt;
      bf16x8 bfrag = *reinterpret_cast<const bf16x8*>(&sS[row * CINP + ci]);
      accC[0][nf] = __builtin_amdgcn_mfma_f32_16x16x32_bf16(aW[0][ks], bfrag, accC[0][nf], 0, 0, 0);
      accC[1][nf] = __builtin_amdgcn_mfma_f32_16x16x32_bf16(aW[1][ks], bfrag, accC[1][nf], 0, 0, 0);
    }
  }

  float* Pb = P + (size_t)n * LSEQ * CT;
  float ts1[2][4], ts2[2][4];
#pragma unroll
  for (int m = 0; m < 2; ++m)
#pragma unroll
    for (int i = 0; i < 4; ++i) { ts1[m][i] = 0.f; ts2[m][i] = 0.f; }

#pragma unroll
  for (int nf = 0; nf < 2; ++nf) {
    int osr = wv * 32 + nf * 16 + col;
    int gl = l0 + osr;
    bool owned = (osr < TS) && (gl < LSEQ);
#pragma unroll
    for (int m = 0; m < 2; ++m) {
      int ch0 = CIN + m * 16 + grp * 4;
      f32x4 f1v = {0.f, 0.f, 0.f, 0.f};
      if (owned) {
        f1v = *reinterpret_cast<const f32x4*>(&fi1b[(size_t)gl * CT + ch0]);
#pragma unroll
        for (int i = 0; i < 4; ++i) {
          float f = sc1[ch0 + i] * f1v[i] + sh1[ch0 + i];
          if (fi1Relu) f = fmaxf(f, 0.f);
          f1v[i] = f;
        }
      }
      f32x4 pre4;
#pragma unroll
      for (int i = 0; i < 4; ++i) {
        float pv = f1v[i] - cV * accC[m][nf][i] + sbv[ch0 + i];
        pre4[i] = pv;
        if (owned) { ts1[m][i] += pv; ts2[m][i] += pv * pv; }
      }
      if (owned) *reinterpret_cast<f32x4*>(&Pb[(size_t)gl * CT + ch0]) = pre4;
    }
  }
#pragma unroll
  for (int m = 0; m < 2; ++m)
#pragma unroll
    for (int i = 0; i < 4; ++i) {
      float s1 = ts1[m][i], s2 = ts2[m][i];
      s1 += __shfl_xor(s1, 1); s2 += __shfl_xor(s2, 1);
      s1 += __shfl_xor(s1, 2); s2 += __shfl_xor(s2, 2);
      s1 += __shfl_xor(s1, 4); s2 += __shfl_xor(s2, 4);
      s1 += __shfl_xor(s1, 8); s2 += __shfl_xor(s2, 8);
      if (col == 0) {
        int ch = CIN + m * 16 + grp * 4 + i;
        atomicAdd(&lstat[2 * ch], s1);
        atomicAdd(&lstat[2 * ch + 1], s2);
      }
    }

  // head: pre = act1(fi1) - c*s + bv (s from sS, row = site+1)
  {
    const int Q = CIN / 4;
    const int SPT = 256 / Q;
    int quad = t % Q, srow = t / Q;
    if (srow < SPT) {
      int c0 = quad * 4;
      float hb1[4] = {0.f, 0.f, 0.f, 0.f}, hb2[4] = {0.f, 0.f, 0.f, 0.f};
      for (int site = srow; site < TS; site += SPT) {
        int gl = l0 + site;
        if (gl >= LSEQ) break;
        float sv[4];
#pragma unroll
        for (int j = 0; j < 4; ++j) sv[j] = bf2f((unsigned short)sS[(site + 1) * CINP + c0 + j]);
        f32x4 f1 = *reinterpret_cast<const f32x4*>(&fi1b[(size_t)gl * CT + c0]);
        f32x4 pr;
#pragma unroll
        for (int j = 0; j < 4; ++j) {
          float f = sc1[c0 + j] * f1[j] + sh1[c0 + j];
          if (fi1Relu) f = fmaxf(f, 0.f);
          pr[j] = f - cV * sv[j] + sbv[c0 + j];
        }
        *reinterpret_cast<f32x4*>(&Pb[(size_t)gl * CT + c0]) = pr;
#pragma unroll
        for (int j = 0; j < 4; ++j) { hb1[j] += pr[j]; hb2[j] += pr[j] * pr[j]; }
      }
#pragma unroll
      for (int j = 0; j < 4; ++j) {
        atomicAdd(&lstat[2 * (c0 + j)], hb1[j]);
        atomicAdd(&lstat[2 * (c0 + j) + 1], hb2[j]);
      }
    }
  }
  __syncthreads();
  float* slot = statsOut + (n & (NSLOT - 1)) * SLOTW;
  for (int ch = t; ch < CT; ch += 256) {
    atomicAdd(&slot[2 * ch], lstat[2 * ch]);
    atomicAdd(&slot[2 * ch + 1], lstat[2 * ch + 1]);
  }
}

// eSE mean, parallel over l: grid (8, 128); partial sums -> atomic smP[n][c]
__global__ __launch_bounds__(256) void ese_mean_part(
    const float* __restrict__ z, const float* __restrict__ stats,
    const float* __restrict__ g, const float* __restrict__ b,
    float* __restrict__ smP)
{
  __shared__ float sc[112], sh[112];
  __shared__ float red[224];
  int q = blockIdx.x, n = blockIdx.y, t = threadIdx.x;
  load_affine16(stats, g, b, sc, sh, 112);
  __syncthreads();
  float acc = 0.f;
  if (t < 224) {
    int c = t % 112, p = t / 112;
    const float* zb = z + (size_t)n * LSEQ * 112;
    float scv = sc[c], shv = sh[c];
    for (int l = q * 40 + p; l < (q + 1) * 40 && l < LSEQ; l += 2)
      acc += fmaxf(scv * zb[(size_t)l * 112 + c] + shv, 0.f);
    red[t] = acc;
  }
  __syncthreads();
  if (t < 112) atomicAdd(&smP[n * 112 + t], red[t] + red[t + 112]);
}

// eSE act: a = hsigmoid(smP/LSEQ @ W.T + b)
__global__ __launch_bounds__(128) void ese_act(const float* __restrict__ smP,
                                               const float* __restrict__ W,
                                               const float* __restrict__ eb,
                                               float* __restrict__ am)
{
  __shared__ float sl[112];
  int n = blockIdx.x, c = threadIdx.x;
  if (c < 112) sl[c] = smP[n * 112 + c] * (1.f / LSEQ);
  __syncthreads();
  if (c >= 112) return;
  float a = eb[c] + 3.0f;
  for (int cc = 0; cc < 112; ++cc) a = fmaf(sl[cc], W[c * 112 + cc], a);
  a = fminf(fmaxf(a, 0.f), 6.f) * (1.f / 6.f);
  am[n * 112 + c] = a;
}

// ---- fc1 path (verified) ----
__global__ __launch_bounds__(256) void zb_pack(
    const float* __restrict__ P3, const float* __restrict__ stats,
    const float* __restrict__ g, const float* __restrict__ b,
    const float* __restrict__ am, unsigned short* __restrict__ zb)
{
  __shared__ float sc[112], sh[112];
  __shared__ unsigned short sT[112 * 72];
  int t = threadIdx.x;
  int lt = blockIdx.x, n = blockIdx.y;
  int l0 = lt * 64;
  load_affine16(stats, g, b, sc, sh, 112);
  __syncthreads();
  const float* zr = P3 + ((size_t)n * LSEQ + l0) * 112;
  const float* amr = am + n * 112;
  for (int e = t; e < 64 * 112; e += 256) {
    int l = e / 112, c = e - (e / 112) * 112;
    float v = 0.f;
    if (l0 + l < LSEQ) v = fmaxf(sc[c] * zr[(size_t)l * 112 + c] + sh[c], 0.f) * amr[c];
    sT[c * 72 + l] = f2bf(v);
  }
  __syncthreads();
  unsigned short* zo = zb + (size_t)n * FC1K;
  for (int e = t; e < 112 * 8; e += 256) {
    int c = e >> 3, seg = e & 7;
    int l = seg * 8;
    int gl = l0 + l;
    if (gl >= LSEQ) continue;
    if (gl + 8 <= LSEQ) {
      bf16x8 v = *reinterpret_cast<const bf16x8*>(&sT[c * 72 + l]);
      *reinterpret_cast<bf16x8*>(&zo[(size_t)c * LSEQ + gl]) = v;
    } else {
      for (int jj = 0; jj < 8 && gl + jj < LSEQ; ++jj)
        zo[(size_t)c * LSEQ + gl + jj] = sT[c * 72 + l + jj];
    }
  }
}

__global__ __launch_bounds__(256) void wb_pack(const float* __restrict__ w1,
                                               unsigned short* __restrict__ wb)
{
  size_t i = (size_t)blockIdx.x * 256 + threadIdx.x;
  if (i >= (size_t)128 * FC1K / 8) return;
  const float* p = w1 + i * 8;
  bf16x8 v;
#pragma unroll
  for (int jj = 0; jj < 8; ++jj) v[jj] = (short)f2bf(p[jj]);
  *reinterpret_cast<bf16x8*>(&wb[i * 8]) = v;
}

__global__ __launch_bounds__(256) void fc1_mfma(
    const unsigned short* __restrict__ zb,
    const unsigned short* __restrict__ wb,
    float* __restrict__ parts)
{
  const int SLOT = 104;
  __shared__ __align__(16) unsigned short sA[128 * SLOT];
  __shared__ __align__(16) unsigned short sB[128 * SLOT];
  int t = threadIdx.x, b = blockIdx.x;
  int k0 = b * KCH;
  int wv = t >> 6, lane = t & 63, col = lane & 15, grp = lane >> 4;
  int jq = (wv >> 1) * 64, nq = (wv & 1) * 64;

  f32x4 acc[4][4];
#pragma unroll
  for (int m = 0; m < 4; ++m)
#pragma unroll
    for (int nn = 0; nn < 4; ++nn) acc[m][nn] = (f32x4){0.f, 0.f, 0.f, 0.f};

#pragma unroll
  for (int half = 0; half < 2; ++half) {
    int kh = k0 + half * 96;
    int kwid = half ? (KCH - 96) : 96;
    int nslots = half ? 8 : 12;
    __syncthreads();
    for (int e = t; e < 128 * 12; e += 256) {
      int row = e / 12, g2 = e - (e / 12) * 12;
      int kk = g2 * 8;
      bf16x8 va = {0, 0, 0, 0, 0, 0, 0, 0}, vb2 = va;
      if (g2 < nslots) {
        va = *reinterpret_cast<const bf16x8*>(&wb[(size_t)row * FC1K + kh + kk]);
        vb2 = *reinterpret_cast<const bf16x8*>(&zb[(size_t)row * FC1K + kh + kk]);
#pragma unroll
        for (int jj = 0; jj < 8; ++jj)
          if (kk + jj >= kwid) { va[jj] = 0; vb2[jj] = 0; }
      }
      *reinterpret_cast<bf16x8*>(&sA[row * SLOT + kk]) = va;
      *reinterpret_cast<bf16x8*>(&sB[row * SLOT + kk]) = vb2;
    }
    __syncthreads();
    int ksteps = half ? 2 : 3;
    for (int ks = 0; ks < ksteps; ++ks) {
      bf16x8 af[4], bfr[4];
#pragma unroll
      for (int m = 0; m < 4; ++m)
        af[m] = *reinterpret_cast<const bf16x8*>(&sA[(jq + m * 16 + col) * SLOT + ks * 32 + grp * 8]);
#pragma unroll
      for (int nn = 0; nn < 4; ++nn)
        bfr[nn] = *reinterpret_cast<const bf16x8*>(&sB[(nq + nn * 16 + col) * SLOT + ks * 32 + grp * 8]);
#pragma unroll
      for (int m = 0; m < 4; ++m)
#pragma unroll
        for (int nn = 0; nn < 4; ++nn)
          acc[m][nn] = __builtin_amdgcn_mfma_f32_16x16x32_bf16(af[m], bfr[nn], acc[m][nn], 0, 0, 0);
    }
  }
  float* pb = parts + (size_t)b * 16384;
#pragma unroll
  for (int nn = 0; nn < 4; ++nn)
#pragma unroll
    for (int m = 0; m < 4; ++m)
      *reinterpret_cast<f32x4*>(&pb[(nq + nn * 16 + col) * 128 + jq + m * 16 + grp * 4]) = acc[m][nn];
}

__global__ __launch_bounds__(256) void fc1_red(const float* __restrict__ parts,
                                               float* __restrict__ y1)
{
  int o = blockIdx.x * 256 + threadIdx.x;
  float s = 0.f;
  for (int b = 0; b < NKBLK; ++b) s += parts[(size_t)b * 16384 + o];
  y1[o] = s;
}

__global__ __launch_bounds__(128) void fc2_lsm(const float* __restrict__ y1,
                                               const float* __restrict__ b1,
                                               const float* __restrict__ w2,
                                               const float* __restrict__ b2,
                                               float* __restrict__ out)
{
  int n = blockIdx.x;
  int t = threadIdx.x;
  __shared__ float part[10][128];
  float v = fmaxf(y1[n * 128 + t] + b1[t], 0.f);
#pragma unroll
  for (int k = 0; k < 10; ++k) part[k][t] = v * w2[k * 128 + t];
  __syncthreads();
  for (int st = 64; st > 0; st >>= 1) {
    if (t < st) {
#pragma unroll
      for (int k = 0; k < 10; ++k) part[k][t] += part[k][t + st];
    }
    __syncthreads();
  }
  if (t == 0) {
    float lg[10];
    float mx = -1e30f;
#pragma unroll
    for (int k = 0; k < 10; ++k) { lg[k] = part[k][0] + b2[k]; mx = fmaxf(mx, lg[k]); }
    float s = 0.f;
#pragma unroll
    for (int k = 0; k < 10; ++k) s += expf(lg[k] - mx);
    float ls = logf(s) + mx;
#pragma unroll
    for (int k = 0; k < 10; ++k) {
      out[n * 10 + k] = lg[k] - ls;
      out[1280 + n * 10 + k] = lg[k];
    }
  }
}

extern "C" void kernel_launch(void* const* d_in, const int* in_sizes, int n_in,
                              void* d_out, int out_size, void* d_ws, size_t ws_size,
                              hipStream_t stream)
{
  (void)in_sizes; (void)n_in; (void)out_size; (void)ws_size;
  const float* x       = (const float*)d_in[0];
  const float* filter0 = (const float*)d_in[1];
  const float* b0      = (const float*)d_in[2];
  const float* bn0_g   = (const float*)d_in[3];
  const float* bn0_b   = (const float*)d_in[4];
  const float* ese_w   = (const float*)d_in[5];
  const float* ese_b   = (const float*)d_in[6];
  const float* fc1_w   = (const float*)d_in[7];
  const float* fc1_b   = (const float*)d_in[8];
  const float* fc2_w   = (const float*)d_in[9];
  const float* fc2_b   = (const float*)d_in[10];
  const float* F[3]    = {(const float*)d_in[11], (const float*)d_in[16], (const float*)d_in[21]};
  const float* bv[3]   = {(const float*)d_in[12], (const float*)d_in[17], (const float*)d_in[22]};
  const float* g1[3]   = {(const float*)d_in[13], (const float*)d_in[18], (const float*)d_in[23]};
  const float* be1[3]  = {(const float*)d_in[14], (const float*)d_in[19], (const float*)d_in[24]};
  const float* cs[3]   = {(const float*)d_in[15], (const float*)d_in[20], (const float*)d_in[25]};

  const size_t NL = (size_t)NBATCH * LSEQ;
  const int SLOTSZ = NSLOT * SLOTW;          // 4096 floats per stage
  float* wsf = (float*)d_ws;
  size_t o = 0;
  float* SS  = wsf + o;  o += 13 * SLOTSZ;
  float* smP = wsf + o;  o += 128 * 112;     // zeroed with SS
  float* y1  = wsf + o;  o += 128 * 128;
  float* wsbF = wsf + o; o += 16 * 868;      // stem W bf16 (16*1736 ushorts)
  float* P0  = wsf + o;  o += NL * 16;
  float* P3A = wsf + o;  o += NL * 112;
  float* P3B = wsf + o;  o += NL * 112;
  float* am  = wsf + o;  o += 128 * 112;
  size_t reuse0 = o;             // P1,P2,R1,R2 region = NL*256 floats
  float* P1  = wsf + o;  o += NL * 48;
  float* P2  = wsf + o;  o += NL * 80;
  float* R1  = wsf + o;  o += NL * 48;
  float* R2  = wsf + o;  o += NL * 80;

  unsigned short* wsb = (unsigned short*)wsbF;
  // fc1 scratch aliases P1/P2/R1/R2 (dead at fc1 time)
  unsigned short* zb = (unsigned short*)(wsf + reuse0);
  unsigned short* wb = zb + (size_t)128 * FC1K;
  float* parts = wsf + reuse0 + (size_t)128 * FC1K;

  hipMemsetAsync(SS, 0, (13 * SLOTSZ + 128 * 112) * sizeof(float), stream);

  // ---- stem W pre-pack + stem -> P0 + stats slot 0
  wstem_pack<<<(16 * 868 + 255) / 256, 256, 0, stream>>>(filter0, wsb);
  stem_mfma<<<dim3(4, 128), 256, 0, stream>>>(x, wsb, b0, P0, SS);

  // ---- init stages (MODE 0)
  float* s1 = SS + 1 * SLOTSZ;
  ista_stage<16, 0><<<dim3(3, 128), 256, 0, stream>>>(
      nullptr, P0, SS, bn0_g, bn0_b, 0,
      nullptr, nullptr, nullptr, nullptr, 0,
      F[0], cs[0], bv[0], P1, s1);
  float* s2 = SS + 2 * SLOTSZ;
  ista_stage<48, 0><<<dim3(3, 128), 256, 0, stream>>>(
      nullptr, P1, s1, g1[0], be1[0], 1,
      nullptr, nullptr, nullptr, nullptr, 0,
      F[1], cs[1], bv[1], P2, s2);
  float* s3 = SS + 3 * SLOTSZ;
  ista_stage<80, 0><<<dim3(3, 128), 256, 0, stream>>>(
      nullptr, P2, s2, g1[1], be1[1], 1,
      nullptr, nullptr, nullptr, nullptr, 0,
      F[2], cs[2], bv[2], P3A, s3);

  float* P3cur = P3A;
  float* P3nxt = P3B;
  const float* st3 = s3;

  // ---- unfolding
  for (int u = 0; u < 3; ++u) {
    bwd_fused<<<dim3(3, 128), 256, 0, stream>>>(
        P3cur, st3, g1[2], be1[2], F[2], F[1], R2, R1);
    float* sA = SS + (4 + 3 * u) * SLOTSZ;
    fwd_fused<16><<<dim3(3, 128), 256, 0, stream>>>(
        R1, nullptr, nullptr, nullptr, 0,
        P0, SS, bn0_g, bn0_b, 0,
        F[0], cs[0], bv[0], P1, sA);
    float* sB = SS + (5 + 3 * u) * SLOTSZ;
    fwd_fused<48><<<dim3(3, 128), 256, 0, stream>>>(
        R2, nullptr, nullptr, nullptr, 0,
        P1, sA, g1[0], be1[0], 1,
        F[1], cs[1], bv[1], P2, sB);
    float* sC = SS + (6 + 3 * u) * SLOTSZ;
    fwd_fused<80><<<dim3(3, 128), 256, 0, stream>>>(
        P3cur, st3, g1[2], be1[2], 1,
        P2, sB, g1[1], be1[1], 1,
        F[2], cs[2], bv[2], P3nxt, sC);
    st3 = sC;
    float* tmp = P3cur; P3cur = P3nxt; P3nxt = tmp;
  }

  // ---- eSE (parallel mean + act)
  ese_mean_part<<<dim3(8, 128), 256, 0, stream>>>(P3cur, st3, g1[2], be1[2], smP);
  ese_act<<<128, 128, 0, stream>>>(smP, ese_w, ese_b, am);

  // ---- fc1 (bf16 MFMA split-K) + fc2 + log_softmax
  wb_pack<<<(int)(((size_t)128 * FC1K / 8 + 255) / 256), 256, 0, stream>>>(fc1_w, wb);
  zb_pack<<<dim3(5, 128), 256, 0, stream>>>(P3cur, st3, g1[2], be1[2], am, zb);
  fc1_mfma<<<NKBLK, 256, 0, stream>>>(zb, wb, parts);
  fc1_red<<<64, 256, 0, stream>>>(parts, y1);
  fc2_lsm<<<128, 128, 0, stream>>>(y1, fc1_b, fc2_w, fc2_b, (float*)d_out);
}

// Round 16
// 400.840 us; speedup vs baseline: 1.1542x; 1.0056x over previous
//
#include <hip/hip_runtime.h>
#include <hip/hip_bf16.h>

#define LSEQ 318
#define NBATCH 128
#define NE (NBATCH * LSEQ)
#define FC1K 35616
#define NKBLK 224   // 224 * 159 == 35616
#define KCH 159
#define NSLOT 16
#define SLOTW 256   // floats per slot row

typedef __attribute__((ext_vector_type(4))) float f32x4;
typedef __attribute__((ext_vector_type(8))) short bf16x8;
typedef __attribute__((ext_vector_type(4))) unsigned int u32x4;

__device__ inline unsigned short f2bf(float v) {
  unsigned int a = __builtin_bit_cast(unsigned int, v);
  return (unsigned short)((a + 0x7FFFu + ((a >> 16) & 1u)) >> 16);
}
__device__ inline float bf2f(unsigned short u) {
  unsigned int a = ((unsigned int)u) << 16;
  return __builtin_bit_cast(float, a);
}
__device__ inline unsigned int packbf2(float lo, float hi) {
  return (unsigned int)f2bf(lo) | ((unsigned int)f2bf(hi) << 16);
}
__device__ inline bf16x8 ldfrag(const unsigned int* xb, int j0) {
  u32x4 uu = {xb[j0], xb[j0 + 1], xb[j0 + 2], xb[j0 + 3]};
  return __builtin_bit_cast(bf16x8, uu);
}

// per-channel affine from NSLOT partial stats
__device__ inline void load_affine16(const float* pstat, const float* g, const float* b,
                                     float* sc, float* sh, int C) {
  for (int c = threadIdx.x; c < C; c += blockDim.x) {
    if (pstat) {
      float s1 = 0.f, s2 = 0.f;
#pragma unroll
      for (int s = 0; s < NSLOT; ++s) {
        s1 += pstat[s * SLOTW + 2 * c];
        s2 += pstat[s * SLOTW + 2 * c + 1];
      }
      float m = s1 * (1.f / NE);
      float var = s2 * (1.f / NE) - m * m;
      float sv = g[c] * rsqrtf(var + 1e-5f);
      sc[c] = sv; sh[c] = b[c] - m * sv;
    } else { sc[c] = 1.f; sh[c] = 0.f; }
  }
}

// pre-pack stem W (f32 [16][1700]) -> bf16 [16][1736] (zero-pad tail)
__global__ __launch_bounds__(256) void wstem_pack(const float* __restrict__ w,
                                                  unsigned short* __restrict__ wsb)
{
  int i = blockIdx.x * 256 + threadIdx.x;  // dword index over 16*868
  if (i >= 16 * 868) return;
  int co = i / 868, kd = (i - co * 868) * 2;
  float v0 = (kd < 1700) ? w[co * 1700 + kd] : 0.f;
  float v1 = (kd + 1 < 1700) ? w[co * 1700 + kd + 1] : 0.f;
  ((unsigned int*)wsb)[i] = packbf2(v0, v1);
}

// ---------------------------------------------------------------------------
// Stem (verified, W pre-packed): conv1d + b0 + maxpool16 -> P0 [n][l][16]
// channels-last + slot stats. Rolling rings, p<10, reload p<9.
// ---------------------------------------------------------------------------
__global__ __launch_bounds__(256) void stem_mfma(
    const float* __restrict__ x, const unsigned short* __restrict__ wsb,
    const float* __restrict__ b0, float* __restrict__ pre,
    float* __restrict__ pstat)
{
  __shared__ __align__(16) unsigned short wsh[16 * 1736];
  __shared__ __align__(16) unsigned int xs2[2 * 1520];
  int t = threadIdx.x;
  int pblk = blockIdx.x, n = blockIdx.y;
  int P0 = pblk * 1280;

  for (int e = t; e < 16 * 217; e += 256)
    *reinterpret_cast<bf16x8*>(&wsh[e * 8]) = *reinterpret_cast<const bf16x8*>(&wsb[e * 8]);
  const float* xn = x + (size_t)n * 5087;
  for (int i = t; i < 1520; i += 256) {
    int m = 2 * i;
    int g0 = P0 - 850 + m;
    float v0 = (g0 >= 0 && g0 < 5087) ? xn[g0] : 0.f;
    float v1 = (g0 + 1 >= 0 && g0 + 1 < 5087) ? xn[g0 + 1] : 0.f;
    float v2 = (g0 + 2 >= 0 && g0 + 2 < 5087) ? xn[g0 + 2] : 0.f;
    xs2[i] = packbf2(v0, v1);
    xs2[1520 + i] = packbf2(v1, v2);
  }
  __syncthreads();

  int wv = t >> 6, lane = t & 63;
  int row = lane & 15, grp = lane >> 4;
  int tb = wv * 20;
  const unsigned int* xb = xs2 + (row & 1) * 1520;
  int eb0 = 16 * tb + row + 8 * grp;

  f32x4 acc[20];
#pragma unroll
  for (int i = 0; i < 20; ++i) acc[i] = (f32x4){0.f, 0.f, 0.f, 0.f};

  for (int kg = 0; kg < 6; ++kg) {
    bf16x8 bf[9];
#pragma unroll
    for (int c = 0; c < 9; ++c)
      bf[c] = *reinterpret_cast<const bf16x8*>(&wsh[row * 1736 + kg * 288 + c * 32 + grp * 8]);
    int eb = eb0 + 288 * kg;
    bf16x8 re[9], ro[9];
#pragma unroll
    for (int c = 0; c < 9; ++c) {
      re[c] = ldfrag(xb, (eb + 32 * c) >> 1);
      ro[c] = ldfrag(xb, (eb + 16 + 32 * c) >> 1);
    }
#pragma unroll
    for (int p = 0; p < 10; ++p) {
#pragma unroll
      for (int c = 0; c < 9; ++c)
        acc[2 * p] = __builtin_amdgcn_mfma_f32_16x16x32_bf16(re[c], bf[c], acc[2 * p], 0, 0, 0);
#pragma unroll
      for (int c = 0; c < 9; ++c)
        acc[2 * p + 1] = __builtin_amdgcn_mfma_f32_16x16x32_bf16(ro[c], bf[c], acc[2 * p + 1], 0, 0, 0);
      if (p < 9) {
#pragma unroll
        for (int c = 0; c < 8; ++c) { re[c] = re[c + 1]; ro[c] = ro[c + 1]; }
        re[8] = ldfrag(xb, (eb + 32 * p + 288) >> 1);
        ro[8] = ldfrag(xb, (eb + 32 * p + 304) >> 1);
      }
    }
  }

  float b0v = b0[row];
  float ssum = 0.f, ssq = 0.f;
#pragma unroll
  for (int mt = 0; mt < 20; ++mt) {
    int q = pblk * 80 + tb + mt;
    f32x4 d = acc[mt];
    float m = fmaxf(fmaxf(d[0], d[1]), fmaxf(d[2], d[3]));
    m = fmaxf(m, __shfl_xor(m, 16));
    m = fmaxf(m, __shfl_xor(m, 32));
    if (lane < 16 && q < LSEQ) {
      float val = m + b0v;
      pre[((size_t)n * LSEQ + q) * 16 + lane] = val;
      ssum += val; ssq += val * val;
    }
  }
  if (lane < 16) {
    float* slot = pstat + (n & (NSLOT - 1)) * SLOTW;
    atomicAdd(&slot[2 * lane], ssum);
    atomicAdd(&slot[2 * lane + 1], ssq);
  }
}

// ---------------------------------------------------------------------------
// ista_stage (verified; MODE 0 only), slot stats.
// ---------------------------------------------------------------------------
template <int CIN, int MODE>
__global__ __launch_bounds__(256) void ista_stage(
    const float* __restrict__ t2,
    const float* __restrict__ fiP, const float* __restrict__ fiStats,
    const float* __restrict__ fiG, const float* __restrict__ fiB, int fiRelu,
    const float* __restrict__ fi1P, const float* __restrict__ fi1Stats,
    const float* __restrict__ fi1G, const float* __restrict__ fi1B, int fi1Relu,
    const float* __restrict__ F, const float* __restrict__ cs,
    const float* __restrict__ bv,
    float* __restrict__ P, float* __restrict__ statsOut)
{
  const int CT = CIN + 32;
  const int K3 = 3 * CIN;
  const int KPAD = ((K3 + 31) / 32) * 32;
  const int KROWP = KPAD + (((KPAD / 8) % 2 == 0) ? 8 : 0);
  const int CINP = CIN + (((CIN / 8) % 2 == 0) ? 8 : 0);
  const int TS = 128, ROWS = TS + 3;
  const int KSTEPS = KPAD / 32;

  __shared__ __align__(16) unsigned short sW[32 * KROWP];
  __shared__ __align__(16) unsigned short sS[ROWS * CINP];
  __shared__ float scF[CIN], shF[CIN];
  __shared__ float sc1[CT], sh1[CT], sbv[CT];
  __shared__ float lstat[2 * CT];

  int t = threadIdx.x;
  int l0 = blockIdx.x * TS, n = blockIdx.y;

  load_affine16(fiStats, fiG, fiB, scF, shF, CIN);
  load_affine16(fi1Stats, fi1G, fi1B, sc1, sh1, CT);
  for (int c = t; c < CT; c += 256) sbv[c] = bv[c];
  for (int c = t; c < 2 * CT; c += 256) lstat[c] = 0.f;
  __syncthreads();

  for (int e = t; e < 32 * (KPAD / 8); e += 256) {
    int co = e / (KPAD / 8), kc = (e - co * (KPAD / 8)) * 8;
    int dt = kc / CIN, ci = kc - dt * CIN;
    bf16x8 v;
    if (dt < 3) {
#pragma unroll
      for (int jj = 0; jj < 8; ++jj)
        v[jj] = (short)f2bf(F[((size_t)co * CIN + ci + jj) * 3 + dt]);
    } else {
#pragma unroll
      for (int jj = 0; jj < 8; ++jj) v[jj] = 0;
    }
    *reinterpret_cast<bf16x8*>(&sW[co * KROWP + kc]) = v;
  }
  const float* fib = fiP + (size_t)n * LSEQ * CIN;
  const float* t2b = MODE ? (t2 + (size_t)n * LSEQ * CIN) : nullptr;
  const int NCH8 = CIN / 8;
  for (int e = t; e < ROWS * NCH8; e += 256) {
    int r = e / NCH8, c8 = (e - r * NCH8) * 8;
    int gl = l0 - 1 + r;
    bf16x8 v;
    if (gl >= 0 && gl < LSEQ) {
      const float* p = fib + (size_t)gl * CIN + c8;
#pragma unroll
      for (int jj = 0; jj < 8; ++jj) {
        float f = scF[c8 + jj] * p[jj] + shF[c8 + jj];
        if (fiRelu) f = fmaxf(f, 0.f);
        if (MODE) f = t2b[(size_t)gl * CIN + c8 + jj] - f;
        v[jj] = (short)f2bf(f);
      }
    } else {
#pragma unroll
      for (int jj = 0; jj < 8; ++jj) v[jj] = 0;
    }
    *reinterpret_cast<bf16x8*>(&sS[r * CINP + c8]) = v;
  }
  __syncthreads();

  int wv = t >> 6, lane = t & 63, col = lane & 15, grp = lane >> 4;
  float cV = cs[0];

  bf16x8 a[2][KSTEPS];
#pragma unroll
  for (int m = 0; m < 2; ++m)
#pragma unroll
    for (int ks = 0; ks < KSTEPS; ++ks)
      a[m][ks] = *reinterpret_cast<const bf16x8*>(&sW[(m * 16 + col) * KROWP + ks * 32 + grp * 8]);

  f32x4 acc[2][2];
#pragma unroll
  for (int m = 0; m < 2; ++m)
#pragma unroll
    for (int nf = 0; nf < 2; ++nf) acc[m][nf] = (f32x4){0.f, 0.f, 0.f, 0.f};

#pragma unroll
  for (int ks = 0; ks < KSTEPS; ++ks) {
    int kkb = ks * 32 + grp * 8;
    int dt = kkb / CIN, ci = kkb - dt * CIN;
#pragma unroll
    for (int nf = 0; nf < 2; ++nf) {
      int row = wv * 32 + nf * 16 + col + dt;
      bf16x8 bfrag = *reinterpret_cast<const bf16x8*>(&sS[row * CINP + ci]);
      acc[0][nf] = __builtin_amdgcn_mfma_f32_16x16x32_bf16(a[0][ks], bfrag, acc[0][nf], 0, 0, 0);
      acc[1][nf] = __builtin_amdgcn_mfma_f32_16x16x32_bf16(a[1][ks], bfrag, acc[1][nf], 0, 0, 0);
    }
  }

  const float* fi1b = fi1P ? (fi1P + (size_t)n * LSEQ * CT) : nullptr;
  float* Pb = P + (size_t)n * LSEQ * CT;
  float ts1[2][4], ts2[2][4];
#pragma unroll
  for (int m = 0; m < 2; ++m)
#pragma unroll
    for (int i = 0; i < 4; ++i) { ts1[m][i] = 0.f; ts2[m][i] = 0.f; }

#pragma unroll
  for (int nf = 0; nf < 2; ++nf) {
    int siteL = wv * 32 + nf * 16 + col;
    int gl = l0 + siteL;
    bool valid = (gl < LSEQ);
#pragma unroll
    for (int m = 0; m < 2; ++m) {
      int ch0 = CIN + m * 16 + grp * 4;
      f32x4 f1v = {0.f, 0.f, 0.f, 0.f};
      if (MODE && valid) {
        f1v = *reinterpret_cast<const f32x4*>(&fi1b[(size_t)gl * CT + ch0]);
#pragma unroll
        for (int i = 0; i < 4; ++i) {
          float f = sc1[ch0 + i] * f1v[i] + sh1[ch0 + i];
          if (fi1Relu) f = fmaxf(f, 0.f);
          f1v[i] = f;
        }
      }
      f32x4 pre4;
#pragma unroll
      for (int i = 0; i < 4; ++i) {
        float pv = MODE ? (f1v[i] - cV * acc[m][nf][i] + sbv[ch0 + i])
                        : (cV * acc[m][nf][i] + sbv[ch0 + i]);
        pre4[i] = pv;
        if (valid) { ts1[m][i] += pv; ts2[m][i] += pv * pv; }
      }
      if (valid) *reinterpret_cast<f32x4*>(&Pb[(size_t)gl * CT + ch0]) = pre4;
    }
  }
#pragma unroll
  for (int m = 0; m < 2; ++m)
#pragma unroll
    for (int i = 0; i < 4; ++i) {
      float s1 = ts1[m][i], s2 = ts2[m][i];
      s1 += __shfl_xor(s1, 1); s2 += __shfl_xor(s2, 1);
      s1 += __shfl_xor(s1, 2); s2 += __shfl_xor(s2, 2);
      s1 += __shfl_xor(s1, 4); s2 += __shfl_xor(s2, 4);
      s1 += __shfl_xor(s1, 8); s2 += __shfl_xor(s2, 8);
      if (col == 0) {
        int ch = CIN + m * 16 + grp * 4 + i;
        atomicAdd(&lstat[2 * ch], s1);
        atomicAdd(&lstat[2 * ch + 1], s2);
      }
    }

  {
    const int Q = CIN / 4;
    const int SPT = 256 / Q;
    int quad = t % Q, srow = t / Q;
    if (srow < SPT) {
      int c0 = quad * 4;
      float hb1[4] = {0.f, 0.f, 0.f, 0.f}, hb2[4] = {0.f, 0.f, 0.f, 0.f};
      for (int site = srow; site < TS; site += SPT) {
        int gl = l0 + site;
        if (gl >= LSEQ) break;
        float sv[4];
#pragma unroll
        for (int j = 0; j < 4; ++j) sv[j] = bf2f((unsigned short)sS[(site + 1) * CINP + c0 + j]);
        f32x4 pr;
        if (MODE) {
          f32x4 f1 = *reinterpret_cast<const f32x4*>(&fi1b[(size_t)gl * CT + c0]);
#pragma unroll
          for (int j = 0; j < 4; ++j) {
            float f = sc1[c0 + j] * f1[j] + sh1[c0 + j];
            if (fi1Relu) f = fmaxf(f, 0.f);
            pr[j] = f - cV * sv[j] + sbv[c0 + j];
          }
        } else {
#pragma unroll
          for (int j = 0; j < 4; ++j) pr[j] = cV * sv[j] + sbv[c0 + j];
        }
        *reinterpret_cast<f32x4*>(&Pb[(size_t)gl * CT + c0]) = pr;
#pragma unroll
        for (int j = 0; j < 4; ++j) { hb1[j] += pr[j]; hb2[j] += pr[j] * pr[j]; }
      }
#pragma unroll
      for (int j = 0; j < 4; ++j) {
        atomicAdd(&lstat[2 * (c0 + j)], hb1[j]);
        atomicAdd(&lstat[2 * (c0 + j) + 1], hb2[j]);
      }
    }
  }
  __syncthreads();
  float* slot = statsOut + (n & (NSLOT - 1)) * SLOTW;
  for (int ch = t; ch < CT; ch += 256) {
    atomicAdd(&slot[2 * ch], lstat[2 * ch]);
    atomicAdd(&slot[2 * ch + 1], lstat[2 * ch + 1]);
  }
}

// ---------------------------------------------------------------------------
// bwd_fused (verified): R2 = convT80(act(f3)); R1 = convT48(R2). Slot affine.
// ---------------------------------------------------------------------------
__global__ __launch_bounds__(256) void bwd_fused(
    const float* __restrict__ f3P, const float* __restrict__ st3,
    const float* __restrict__ g3, const float* __restrict__ b3,
    const float* __restrict__ F2, const float* __restrict__ F1,
    float* __restrict__ R2, float* __restrict__ R1)
{
  __shared__ __align__(16) unsigned short X3[130 * 40];
  __shared__ __align__(16) unsigned short sW2[80 * 104];
  __shared__ __align__(16) unsigned short sW1[48 * 104];
  __shared__ __align__(16) unsigned short R2t[130 * 40];
  __shared__ __align__(16) float R2h[128 * 52];
  __shared__ float sc3[112], sh3[112];
  int t = threadIdx.x;
  int l0 = blockIdx.x * 126, n = blockIdx.y;
  load_affine16(st3, g3, b3, sc3, sh3, 112);
  __syncthreads();

  const float* f3b = f3P + (size_t)n * LSEQ * 112;
  for (int e = t; e < 130 * 4; e += 256) {
    int r = e >> 2, c8 = (e & 3) * 8;
    int gl = l0 - 2 + r;
    bf16x8 v;
    if (gl >= 0 && gl < LSEQ) {
      const float* p = f3b + (size_t)gl * 112 + 80 + c8;
#pragma unroll
      for (int jj = 0; jj < 8; ++jj)
        v[jj] = (short)f2bf(fmaxf(sc3[80 + c8 + jj] * p[jj] + sh3[80 + c8 + jj], 0.f));
    } else {
#pragma unroll
      for (int jj = 0; jj < 8; ++jj) v[jj] = 0;
    }
    *reinterpret_cast<bf16x8*>(&X3[r * 40 + c8]) = v;
  }
  for (int e = t; e < 80 * 12; e += 256) {
    int co = e / 12, kc = (e - co * 12) * 8;
    int dt = kc >> 5, j0 = kc & 31;
    bf16x8 v;
#pragma unroll
    for (int jj = 0; jj < 8; ++jj)
      v[jj] = (short)f2bf(F2[((size_t)(j0 + jj) * 80 + co) * 3 + (2 - dt)]);
    *reinterpret_cast<bf16x8*>(&sW2[co * 104 + kc]) = v;
  }
  for (int e = t; e < 48 * 12; e += 256) {
    int co = e / 12, kc = (e - co * 12) * 8;
    int dt = kc >> 5, j0 = kc & 31;
    bf16x8 v;
#pragma unroll
    for (int jj = 0; jj < 8; ++jj)
      v[jj] = (short)f2bf(F1[((size_t)(j0 + jj) * 48 + co) * 3 + (2 - dt)]);
    *reinterpret_cast<bf16x8*>(&sW1[co * 104 + kc]) = v;
  }
  if (t < 10) {
    int r = 128 + t / 5, c8 = (t % 5) * 8;
    bf16x8 z;
#pragma unroll
    for (int jj = 0; jj < 8; ++jj) z[jj] = 0;
    *reinterpret_cast<bf16x8*>(&R2t[r * 40 + c8]) = z;
  }
  __syncthreads();

  int wv = t >> 6, lane = t & 63, col = lane & 15, grp = lane >> 4;
  f32x4 acc2[5][2];
#pragma unroll
  for (int m = 0; m < 5; ++m)
#pragma unroll
    for (int nf = 0; nf < 2; ++nf) acc2[m][nf] = (f32x4){0.f, 0.f, 0.f, 0.f};
#pragma unroll
  for (int ks = 0; ks < 3; ++ks) {
    bf16x8 bA = *reinterpret_cast<const bf16x8*>(&X3[(wv * 32 + col + ks) * 40 + grp * 8]);
    bf16x8 bB = *reinterpret_cast<const bf16x8*>(&X3[(wv * 32 + 16 + col + ks) * 40 + grp * 8]);
#pragma unroll
    for (int m = 0; m < 5; ++m) {
      bf16x8 af = *reinterpret_cast<const bf16x8*>(&sW2[(m * 16 + col) * 104 + ks * 32 + grp * 8]);
      acc2[m][0] = __builtin_amdgcn_mfma_f32_16x16x32_bf16(af, bA, acc2[m][0], 0, 0, 0);
      acc2[m][1] = __builtin_amdgcn_mfma_f32_16x16x32_bf16(af, bB, acc2[m][1], 0, 0, 0);
    }
  }
#pragma unroll
  for (int nf = 0; nf < 2; ++nf) {
    int sr = wv * 32 + nf * 16 + col;
    int gl = l0 - 1 + sr;
    bool v = (gl >= 0 && gl < LSEQ);
#pragma unroll
    for (int m = 0; m < 5; ++m) {
      int c0 = m * 16 + grp * 4;
      f32x4 o = {0.f, 0.f, 0.f, 0.f};
      if (v) {
        f32x4 hv = *reinterpret_cast<const f32x4*>(&f3b[(size_t)gl * 112 + c0]);
#pragma unroll
        for (int i = 0; i < 4; ++i)
          o[i] = fmaxf(sc3[c0 + i] * hv[i] + sh3[c0 + i], 0.f) + acc2[m][nf][i];
        *reinterpret_cast<f32x4*>(&R2[((size_t)n * LSEQ + gl) * 80 + c0]) = o;
      }
      if (c0 < 48) {
        *reinterpret_cast<f32x4*>(&R2h[sr * 52 + c0]) = o;
      } else {
        int j = c0 - 48;
        *reinterpret_cast<unsigned int*>(&R2t[sr * 40 + j]) = packbf2(o[0], o[1]);
        *reinterpret_cast<unsigned int*>(&R2t[sr * 40 + j + 2]) = packbf2(o[2], o[3]);
      }
    }
  }
  __syncthreads();

  f32x4 acc1[3][2];
#pragma unroll
  for (int m = 0; m < 3; ++m)
#pragma unroll
    for (int nf = 0; nf < 2; ++nf) acc1[m][nf] = (f32x4){0.f, 0.f, 0.f, 0.f};
#pragma unroll
  for (int ks = 0; ks < 3; ++ks) {
    bf16x8 bA = *reinterpret_cast<const bf16x8*>(&R2t[(wv * 32 + col + ks) * 40 + grp * 8]);
    bf16x8 bB = *reinterpret_cast<const bf16x8*>(&R2t[(wv * 32 + 16 + col + ks) * 40 + grp * 8]);
#pragma unroll
    for (int m = 0; m < 3; ++m) {
      bf16x8 af = *reinterpret_cast<const bf16x8*>(&sW1[(m * 16 + col) * 104 + ks * 32 + grp * 8]);
      acc1[m][0] = __builtin_amdgcn_mfma_f32_16x16x32_bf16(af, bA, acc1[m][0], 0, 0, 0);
      acc1[m][1] = __builtin_amdgcn_mfma_f32_16x16x32_bf16(af, bB, acc1[m][1], 0, 0, 0);
    }
  }
#pragma unroll
  for (int nf = 0; nf < 2; ++nf) {
    int osr = wv * 32 + nf * 16 + col;
    int gl = l0 + osr;
    if (osr < 126 && gl < LSEQ) {
#pragma unroll
      for (int m = 0; m < 3; ++m) {
        int c0 = m * 16 + grp * 4;
        f32x4 h = *reinterpret_cast<const f32x4*>(&R2h[(osr + 1) * 52 + c0]);
        f32x4 o;
#pragma unroll
        for (int i = 0; i < 4; ++i) o[i] = h[i] + acc1[m][nf][i];
        *reinterpret_cast<f32x4*>(&R1[((size_t)n * LSEQ + gl) * 48 + c0]) = o;
      }
    }
  }
}

// ---------------------------------------------------------------------------
// fwd_fused (verified 256-thread TS=126), slot stats.
// ---------------------------------------------------------------------------
template <int CIN>
__global__ __launch_bounds__(256) void fwd_fused(
    const float* __restrict__ fi1P, const float* __restrict__ fi1S,
    const float* __restrict__ fi1G, const float* __restrict__ fi1B, int fi1Relu,
    const float* __restrict__ fPP, const float* __restrict__ fPS,
    const float* __restrict__ fPG, const float* __restrict__ fPB, int fPRelu,
    const float* __restrict__ F, const float* __restrict__ cs,
    const float* __restrict__ bv,
    float* __restrict__ P, float* __restrict__ statsOut)
{
  const int CT = CIN + 32;
  const int K3 = 3 * CIN;
  const int KPAD = ((K3 + 31) / 32) * 32;
  const int KROWP = KPAD + (((KPAD / 8) % 2 == 0) ? 8 : 0);
  const int CINP = CIN + (((CIN / 8) % 2 == 0) ? 8 : 0);
  const int KSTEPS = KPAD / 32;
  const int MFT = CIN / 16;
  const int TS = 126;

  __shared__ __align__(16) unsigned short X1[130 * 40];
  __shared__ __align__(16) unsigned short sS[131 * CINP];
  __shared__ __align__(16) unsigned short sWT[CIN * 104];
  __shared__ __align__(16) unsigned short sWC[32 * KROWP];
  __shared__ float scP[CIN], shP[CIN];
  __shared__ float sc1[CT], sh1[CT], sbv[CT];
  __shared__ float lstat[2 * CT];

  int t = threadIdx.x;
  int l0 = blockIdx.x * TS, n = blockIdx.y;

  load_affine16(fPS, fPG, fPB, scP, shP, CIN);
  load_affine16(fi1S, fi1G, fi1B, sc1, sh1, CT);
  for (int c = t; c < CT; c += 256) sbv[c] = bv[c];
  for (int c = t; c < 2 * CT; c += 256) lstat[c] = 0.f;
  __syncthreads();

  const float* fi1b = fi1P + (size_t)n * LSEQ * CT;
  const float* fPb = fPP + (size_t)n * LSEQ * CIN;
  for (int e = t; e < 130 * 4; e += 256) {
    int r = e >> 2, c8 = (e & 3) * 8;
    int gl = l0 - 2 + r;
    bf16x8 v;
    if (gl >= 0 && gl < LSEQ) {
      const float* p = fi1b + (size_t)gl * CT + CIN + c8;
#pragma unroll
      for (int jj = 0; jj < 8; ++jj) {
        float f = sc1[CIN + c8 + jj] * p[jj] + sh1[CIN + c8 + jj];
        if (fi1Relu) f = fmaxf(f, 0.f);
        v[jj] = (short)f2bf(f);
      }
    } else {
#pragma unroll
      for (int jj = 0; jj < 8; ++jj) v[jj] = 0;
    }
    *reinterpret_cast<bf16x8*>(&X1[r * 40 + c8]) = v;
  }
  for (int e = t; e < CIN * 12; e += 256) {
    int co = e / 12, kc = (e - co * 12) * 8;
    int dt = kc >> 5, j0 = kc & 31;
    bf16x8 v;
#pragma unroll
    for (int jj = 0; jj < 8; ++jj)
      v[jj] = (short)f2bf(F[((size_t)(j0 + jj) * CIN + co) * 3 + (2 - dt)]);
    *reinterpret_cast<bf16x8*>(&sWT[co * 104 + kc]) = v;
  }
  for (int e = t; e < 32 * (KPAD / 8); e += 256) {
    int co = e / (KPAD / 8), kc = (e - co * (KPAD / 8)) * 8;
    int dt = kc / CIN, ci = kc - dt * CIN;
    bf16x8 v;
    if (dt < 3) {
#pragma unroll
      for (int jj = 0; jj < 8; ++jj)
        v[jj] = (short)f2bf(F[((size_t)co * CIN + ci + jj) * 3 + dt]);
    } else {
#pragma unroll
      for (int jj = 0; jj < 8; ++jj) v[jj] = 0;
    }
    *reinterpret_cast<bf16x8*>(&sWC[co * KROWP + kc]) = v;
  }
  for (int e = t; e < 3 * (CINP / 8); e += 256) {
    int r = 128 + e / (CINP / 8), c8 = (e % (CINP / 8)) * 8;
    bf16x8 z;
#pragma unroll
    for (int jj = 0; jj < 8; ++jj) z[jj] = 0;
    *reinterpret_cast<bf16x8*>(&sS[r * CINP + c8]) = z;
  }
  __syncthreads();

  int wv = t >> 6, lane = t & 63, col = lane & 15, grp = lane >> 4;
  float cV = cs[0];

  // phase 2: convT -> s (sS rows 0..127, gl = l0-1+sr)
  {
    f32x4 accT[MFT][2];
#pragma unroll
    for (int m = 0; m < MFT; ++m)
#pragma unroll
      for (int nf = 0; nf < 2; ++nf) accT[m][nf] = (f32x4){0.f, 0.f, 0.f, 0.f};
#pragma unroll
    for (int ks = 0; ks < 3; ++ks) {
      bf16x8 bA = *reinterpret_cast<const bf16x8*>(&X1[(wv * 32 + col + ks) * 40 + grp * 8]);
      bf16x8 bB = *reinterpret_cast<const bf16x8*>(&X1[(wv * 32 + 16 + col + ks) * 40 + grp * 8]);
#pragma unroll
      for (int m = 0; m < MFT; ++m) {
        bf16x8 af = *reinterpret_cast<const bf16x8*>(&sWT[(m * 16 + col) * 104 + ks * 32 + grp * 8]);
        accT[m][0] = __builtin_amdgcn_mfma_f32_16x16x32_bf16(af, bA, accT[m][0], 0, 0, 0);
        accT[m][1] = __builtin_amdgcn_mfma_f32_16x16x32_bf16(af, bB, accT[m][1], 0, 0, 0);
      }
    }
#pragma unroll
    for (int nf = 0; nf < 2; ++nf) {
      int sr = wv * 32 + nf * 16 + col;
      int gl = l0 - 1 + sr;
      bool v = (gl >= 0 && gl < LSEQ);
#pragma unroll
      for (int m = 0; m < MFT; ++m) {
        int c0 = m * 16 + grp * 4;
        f32x4 sv = {0.f, 0.f, 0.f, 0.f};
        if (v) {
          f32x4 base = *reinterpret_cast<const f32x4*>(&fi1b[(size_t)gl * CT + c0]);
          f32x4 pv = *reinterpret_cast<const f32x4*>(&fPb[(size_t)gl * CIN + c0]);
#pragma unroll
          for (int i = 0; i < 4; ++i) {
            float tbv = sc1[c0 + i] * base[i] + sh1[c0 + i];
            if (fi1Relu) tbv = fmaxf(tbv, 0.f);
            float t2v = tbv + accT[m][nf][i];
            float fp = scP[c0 + i] * pv[i] + shP[c0 + i];
            if (fPRelu) fp = fmaxf(fp, 0.f);
            sv[i] = t2v - fp;
          }
        }
        *reinterpret_cast<unsigned int*>(&sS[sr * CINP + c0]) = packbf2(sv[0], sv[1]);
        *reinterpret_cast<unsigned int*>(&sS[sr * CINP + c0 + 2]) = packbf2(sv[2], sv[3]);
      }
    }
  }
  __syncthreads();

  // phase 3: conv(s) + epilogue (tail)
  bf16x8 aW[2][KSTEPS];
#pragma unroll
  for (int m = 0; m < 2; ++m)
#pragma unroll
    for (int ks = 0; ks < KSTEPS; ++ks)
      aW[m][ks] = *reinterpret_cast<const bf16x8*>(&sWC[(m * 16 + col) * KROWP + ks * 32 + grp * 8]);

  f32x4 accC[2][2];
#pragma unroll
  for (int m = 0; m < 2; ++m)
#pragma unroll
    for (int nf = 0; nf < 2; ++nf) accC[m][nf] = (f32x4){0.f, 0.f, 0.f, 0.f};
#pragma unroll
  for (int ks = 0; ks < KSTEPS; ++ks) {
    int kkb = ks * 32 + grp * 8;
    int dt = kkb / CIN, ci = kkb - dt * CIN;
#pragma unroll
    for (int nf = 0; nf < 2; ++nf) {
      int row = wv * 32 + nf * 16 + col + dt;
      bf16x8 bfrag = *reinterpret_cast<const bf16x8*>(&sS[row * CINP + ci]);
      accC[0][nf] = __builtin_amdgcn_mfma_f32_16x16x32_bf16(aW[0][ks], bfrag, accC[0][nf], 0, 0, 0);
      accC[1][nf] = __builtin_amdgcn_mfma_f32_16x16x32_bf16(aW[1][ks], bfrag, accC[1][nf], 0, 0, 0);
    }
  }

  float* Pb = P + (size_t)n * LSEQ * CT;
  float ts1[2][4], ts2[2][4];
#pragma unroll
  for (int m = 0; m < 2; ++m)
#pragma unroll
    for (int i = 0; i < 4; ++i) { ts1[m][i] = 0.f; ts2[m][i] = 0.f; }

#pragma unroll
  for (int nf = 0; nf < 2; ++nf) {
    int osr = wv * 32 + nf * 16 + col;
    int gl = l0 + osr;
    bool owned = (osr < TS) && (gl < LSEQ);
#pragma unroll
    for (int m = 0; m < 2; ++m) {
      int ch0 = CIN + m * 16 + grp * 4;
      f32x4 f1v = {0.f, 0.f, 0.f, 0.f};
      if (owned) {
        f1v = *reinterpret_cast<const f32x4*>(&fi1b[(size_t)gl * CT + ch0]);
#pragma unroll
        for (int i = 0; i < 4; ++i) {
          float f = sc1[ch0 + i] * f1v[i] + sh1[ch0 + i];
          if (fi1Relu) f = fmaxf(f, 0.f);
          f1v[i] = f;
        }
      }
      f32x4 pre4;
#pragma unroll
      for (int i = 0; i < 4; ++i) {
        float pv = f1v[i] - cV * accC[m][nf][i] + sbv[ch0 + i];
        pre4[i] = pv;
        if (owned) { ts1[m][i] += pv; ts2[m][i] += pv * pv; }
      }
      if (owned) *reinterpret_cast<f32x4*>(&Pb[(size_t)gl * CT + ch0]) = pre4;
    }
  }
#pragma unroll
  for (int m = 0; m < 2; ++m)
#pragma unroll
    for (int i = 0; i < 4; ++i) {
      float s1 = ts1[m][i], s2 = ts2[m][i];
      s1 += __shfl_xor(s1, 1); s2 += __shfl_xor(s2, 1);
      s1 += __shfl_xor(s1, 2); s2 += __shfl_xor(s2, 2);
      s1 += __shfl_xor(s1, 4); s2 += __shfl_xor(s2, 4);
      s1 += __shfl_xor(s1, 8); s2 += __shfl_xor(s2, 8);
      if (col == 0) {
        int ch = CIN + m * 16 + grp * 4 + i;
        atomicAdd(&lstat[2 * ch], s1);
        atomicAdd(&lstat[2 * ch + 1], s2);
      }
    }

  // head: pre = act1(fi1) - c*s + bv (s from sS, row = site+1)
  {
    const int Q = CIN / 4;
    const int SPT = 256 / Q;
    int quad = t % Q, srow = t / Q;
    if (srow < SPT) {
      int c0 = quad * 4;
      float hb1[4] = {0.f, 0.f, 0.f, 0.f}, hb2[4] = {0.f, 0.f, 0.f, 0.f};
      for (int site = srow; site < TS; site += SPT) {
        int gl = l0 + site;
        if (gl >= LSEQ) break;
        float sv[4];
#pragma unroll
        for (int j = 0; j < 4; ++j) sv[j] = bf2f((unsigned short)sS[(site + 1) * CINP + c0 + j]);
        f32x4 f1 = *reinterpret_cast<const f32x4*>(&fi1b[(size_t)gl * CT + c0]);
        f32x4 pr;
#pragma unroll
        for (int j = 0; j < 4; ++j) {
          float f = sc1[c0 + j] * f1[j] + sh1[c0 + j];
          if (fi1Relu) f = fmaxf(f, 0.f);
          pr[j] = f - cV * sv[j] + sbv[c0 + j];
        }
        *reinterpret_cast<f32x4*>(&Pb[(size_t)gl * CT + c0]) = pr;
#pragma unroll
        for (int j = 0; j < 4; ++j) { hb1[j] += pr[j]; hb2[j] += pr[j] * pr[j]; }
      }
#pragma unroll
      for (int j = 0; j < 4; ++j) {
        atomicAdd(&lstat[2 * (c0 + j)], hb1[j]);
        atomicAdd(&lstat[2 * (c0 + j) + 1], hb2[j]);
      }
    }
  }
  __syncthreads();
  float* slot = statsOut + (n & (NSLOT - 1)) * SLOTW;
  for (int ch = t; ch < CT; ch += 256) {
    atomicAdd(&slot[2 * ch], lstat[2 * ch]);
    atomicAdd(&slot[2 * ch + 1], lstat[2 * ch + 1]);
  }
}

// eSE mean, parallel over l: grid (8, 128); partial sums -> atomic smP[n][c]
__global__ __launch_bounds__(256) void ese_mean_part(
    const float* __restrict__ z, const float* __restrict__ stats,
    const float* __restrict__ g, const float* __restrict__ b,
    float* __restrict__ smP)
{
  __shared__ float sc[112], sh[112];
  __shared__ float red[224];
  int q = blockIdx.x, n = blockIdx.y, t = threadIdx.x;
  load_affine16(stats, g, b, sc, sh, 112);
  __syncthreads();
  float acc = 0.f;
  if (t < 224) {
    int c = t % 112, p = t / 112;
    const float* zb = z + (size_t)n * LSEQ * 112;
    float scv = sc[c], shv = sh[c];
    for (int l = q * 40 + p; l < (q + 1) * 40 && l < LSEQ; l += 2)
      acc += fmaxf(scv * zb[(size_t)l * 112 + c] + shv, 0.f);
    red[t] = acc;
  }
  __syncthreads();
  if (t < 112) atomicAdd(&smP[n * 112 + t], red[t] + red[t + 112]);
}

// ---- fc1 path: zb_pack with eSE-act fused in-prologue ----
__global__ __launch_bounds__(256) void zb_pack(
    const float* __restrict__ P3, const float* __restrict__ stats,
    const float* __restrict__ g, const float* __restrict__ b,
    const float* __restrict__ smP, const float* __restrict__ eseW,
    const float* __restrict__ eseB, unsigned short* __restrict__ zb)
{
  __shared__ float sc[112], sh[112];
  __shared__ float sl[112], amL[112];
  __shared__ unsigned short sT[112 * 72];
  int t = threadIdx.x;
  int lt = blockIdx.x, n = blockIdx.y;
  int l0 = lt * 64;
  load_affine16(stats, g, b, sc, sh, 112);
  if (t < 112) sl[t] = smP[n * 112 + t] * (1.f / LSEQ);
  __syncthreads();
  if (t < 112) {
    float a = eseB[t] + 3.0f;
    for (int cc = 0; cc < 112; ++cc) a = fmaf(sl[cc], eseW[t * 112 + cc], a);
    amL[t] = fminf(fmaxf(a, 0.f), 6.f) * (1.f / 6.f);
  }
  __syncthreads();
  const float* zr = P3 + ((size_t)n * LSEQ + l0) * 112;
  for (int e = t; e < 64 * 112; e += 256) {
    int l = e / 112, c = e - (e / 112) * 112;
    float v = 0.f;
    if (l0 + l < LSEQ) v = fmaxf(sc[c] * zr[(size_t)l * 112 + c] + sh[c], 0.f) * amL[c];
    sT[c * 72 + l] = f2bf(v);
  }
  __syncthreads();
  unsigned short* zo = zb + (size_t)n * FC1K;
  for (int e = t; e < 112 * 8; e += 256) {
    int c = e >> 3, seg = e & 7;
    int l = seg * 8;
    int gl = l0 + l;
    if (gl >= LSEQ) continue;
    if (gl + 8 <= LSEQ) {
      bf16x8 v = *reinterpret_cast<const bf16x8*>(&sT[c * 72 + l]);
      *reinterpret_cast<bf16x8*>(&zo[(size_t)c * LSEQ + gl]) = v;
    } else {
      for (int jj = 0; jj < 8 && gl + jj < LSEQ; ++jj)
        zo[(size_t)c * LSEQ + gl + jj] = sT[c * 72 + l + jj];
    }
  }
}

__global__ __launch_bounds__(256) void wb_pack(const float* __restrict__ w1,
                                               unsigned short* __restrict__ wb)
{
  size_t i = (size_t)blockIdx.x * 256 + threadIdx.x;
  if (i >= (size_t)128 * FC1K / 8) return;
  const float* p = w1 + i * 8;
  bf16x8 v;
#pragma unroll
  for (int jj = 0; jj < 8; ++jj) v[jj] = (short)f2bf(p[jj]);
  *reinterpret_cast<bf16x8*>(&wb[i * 8]) = v;
}

__global__ __launch_bounds__(256) void fc1_mfma(
    const unsigned short* __restrict__ zb,
    const unsigned short* __restrict__ wb,
    float* __restrict__ parts)
{
  const int SLOT = 104;
  __shared__ __align__(16) unsigned short sA[128 * SLOT];
  __shared__ __align__(16) unsigned short sB[128 * SLOT];
  int t = threadIdx.x, b = blockIdx.x;
  int k0 = b * KCH;
  int wv = t >> 6, lane = t & 63, col = lane & 15, grp = lane >> 4;
  int jq = (wv >> 1) * 64, nq = (wv & 1) * 64;

  f32x4 acc[4][4];
#pragma unroll
  for (int m = 0; m < 4; ++m)
#pragma unroll
    for (int nn = 0; nn < 4; ++nn) acc[m][nn] = (f32x4){0.f, 0.f, 0.f, 0.f};

#pragma unroll
  for (int half = 0; half < 2; ++half) {
    int kh = k0 + half * 96;
    int kwid = half ? (KCH - 96) : 96;
    int nslots = half ? 8 : 12;
    __syncthreads();
    for (int e = t; e < 128 * 12; e += 256) {
      int row = e / 12, g2 = e - (e / 12) * 12;
      int kk = g2 * 8;
      bf16x8 va = {0, 0, 0, 0, 0, 0, 0, 0}, vb2 = va;
      if (g2 < nslots) {
        va = *reinterpret_cast<const bf16x8*>(&wb[(size_t)row * FC1K + kh + kk]);
        vb2 = *reinterpret_cast<const bf16x8*>(&zb[(size_t)row * FC1K + kh + kk]);
#pragma unroll
        for (int jj = 0; jj < 8; ++jj)
          if (kk + jj >= kwid) { va[jj] = 0; vb2[jj] = 0; }
      }
      *reinterpret_cast<bf16x8*>(&sA[row * SLOT + kk]) = va;
      *reinterpret_cast<bf16x8*>(&sB[row * SLOT + kk]) = vb2;
    }
    __syncthreads();
    int ksteps = half ? 2 : 3;
    for (int ks = 0; ks < ksteps; ++ks) {
      bf16x8 af[4], bfr[4];
#pragma unroll
      for (int m = 0; m < 4; ++m)
        af[m] = *reinterpret_cast<const bf16x8*>(&sA[(jq + m * 16 + col) * SLOT + ks * 32 + grp * 8]);
#pragma unroll
      for (int nn = 0; nn < 4; ++nn)
        bfr[nn] = *reinterpret_cast<const bf16x8*>(&sB[(nq + nn * 16 + col) * SLOT + ks * 32 + grp * 8]);
#pragma unroll
      for (int m = 0; m < 4; ++m)
#pragma unroll
        for (int nn = 0; nn < 4; ++nn)
          acc[m][nn] = __builtin_amdgcn_mfma_f32_16x16x32_bf16(af[m], bfr[nn], acc[m][nn], 0, 0, 0);
    }
  }
  float* pb = parts + (size_t)b * 16384;
#pragma unroll
  for (int nn = 0; nn < 4; ++nn)
#pragma unroll
    for (int m = 0; m < 4; ++m)
      *reinterpret_cast<f32x4*>(&pb[(nq + nn * 16 + col) * 128 + jq + m * 16 + grp * 4]) = acc[m][nn];
}

// fc2 + log_softmax, with fc1 partial reduction fused (same ascending-b sum)
__global__ __launch_bounds__(128) void fc2_lsm(const float* __restrict__ parts,
                                               const float* __restrict__ b1,
                                               const float* __restrict__ w2,
                                               const float* __restrict__ b2,
                                               float* __restrict__ out)
{
  int n = blockIdx.x;
  int t = threadIdx.x;
  __shared__ float part[10][128];
  float y = 0.f;
  for (int b = 0; b < NKBLK; ++b) y += parts[(size_t)b * 16384 + n * 128 + t];
  float v = fmaxf(y + b1[t], 0.f);
#pragma unroll
  for (int k = 0; k < 10; ++k) part[k][t] = v * w2[k * 128 + t];
  __syncthreads();
  for (int st = 64; st > 0; st >>= 1) {
    if (t < st) {
#pragma unroll
      for (int k = 0; k < 10; ++k) part[k][t] += part[k][t + st];
    }
    __syncthreads();
  }
  if (t == 0) {
    float lg[10];
    float mx = -1e30f;
#pragma unroll
    for (int k = 0; k < 10; ++k) { lg[k] = part[k][0] + b2[k]; mx = fmaxf(mx, lg[k]); }
    float s = 0.f;
#pragma unroll
    for (int k = 0; k < 10; ++k) s += expf(lg[k] - mx);
    float ls = logf(s) + mx;
#pragma unroll
    for (int k = 0; k < 10; ++k) {
      out[n * 10 + k] = lg[k] - ls;
      out[1280 + n * 10 + k] = lg[k];
    }
  }
}

extern "C" void kernel_launch(void* const* d_in, const int* in_sizes, int n_in,
                              void* d_out, int out_size, void* d_ws, size_t ws_size,
                              hipStream_t stream)
{
  (void)in_sizes; (void)n_in; (void)out_size; (void)ws_size;
  const float* x       = (const float*)d_in[0];
  const float* filter0 = (const float*)d_in[1];
  const float* b0      = (const float*)d_in[2];
  const float* bn0_g   = (const float*)d_in[3];
  const float* bn0_b   = (const float*)d_in[4];
  const float* ese_w   = (const float*)d_in[5];
  const float* ese_b   = (const float*)d_in[6];
  const float* fc1_w   = (const float*)d_in[7];
  const float* fc1_b   = (const float*)d_in[8];
  const float* fc2_w   = (const float*)d_in[9];
  const float* fc2_b   = (const float*)d_in[10];
  const float* F[3]    = {(const float*)d_in[11], (const float*)d_in[16], (const float*)d_in[21]};
  const float* bv[3]   = {(const float*)d_in[12], (const float*)d_in[17], (const float*)d_in[22]};
  const float* g1[3]   = {(const float*)d_in[13], (const float*)d_in[18], (const float*)d_in[23]};
  const float* be1[3]  = {(const float*)d_in[14], (const float*)d_in[19], (const float*)d_in[24]};
  const float* cs[3]   = {(const float*)d_in[15], (const float*)d_in[20], (const float*)d_in[25]};

  const size_t NL = (size_t)NBATCH * LSEQ;
  const int SLOTSZ = NSLOT * SLOTW;          // 4096 floats per stage
  float* wsf = (float*)d_ws;
  size_t o = 0;
  float* SS  = wsf + o;  o += 13 * SLOTSZ;
  float* smP = wsf + o;  o += 128 * 112;     // zeroed with SS
  float* wsbF = wsf + o; o += 16 * 868;      // stem W bf16 (16*1736 ushorts)
  float* P0  = wsf + o;  o += NL * 16;
  float* P3A = wsf + o;  o += NL * 112;
  float* P3B = wsf + o;  o += NL * 112;
  size_t reuse0 = o;             // P1,P2,R1,R2 region = NL*256 floats
  float* P1  = wsf + o;  o += NL * 48;
  float* P2  = wsf + o;  o += NL * 80;
  float* R1  = wsf + o;  o += NL * 48;
  float* R2  = wsf + o;  o += NL * 80;

  unsigned short* wsb = (unsigned short*)wsbF;
  // fc1 scratch aliases P1/P2/R1/R2 (dead at fc1 time)
  unsigned short* zb = (unsigned short*)(wsf + reuse0);
  unsigned short* wb = zb + (size_t)128 * FC1K;
  float* parts = wsf + reuse0 + (size_t)128 * FC1K;

  hipMemsetAsync(SS, 0, (13 * SLOTSZ + 128 * 112) * sizeof(float), stream);

  // ---- stem W pre-pack + stem -> P0 + stats slot 0
  wstem_pack<<<(16 * 868 + 255) / 256, 256, 0, stream>>>(filter0, wsb);
  stem_mfma<<<dim3(4, 128), 256, 0, stream>>>(x, wsb, b0, P0, SS);

  // ---- init stages (MODE 0)
  float* s1 = SS + 1 * SLOTSZ;
  ista_stage<16, 0><<<dim3(3, 128), 256, 0, stream>>>(
      nullptr, P0, SS, bn0_g, bn0_b, 0,
      nullptr, nullptr, nullptr, nullptr, 0,
      F[0], cs[0], bv[0], P1, s1);
  float* s2 = SS + 2 * SLOTSZ;
  ista_stage<48, 0><<<dim3(3, 128), 256, 0, stream>>>(
      nullptr, P1, s1, g1[0], be1[0], 1,
      nullptr, nullptr, nullptr, nullptr, 0,
      F[1], cs[1], bv[1], P2, s2);
  float* s3 = SS + 3 * SLOTSZ;
  ista_stage<80, 0><<<dim3(3, 128), 256, 0, stream>>>(
      nullptr, P2, s2, g1[1], be1[1], 1,
      nullptr, nullptr, nullptr, nullptr, 0,
      F[2], cs[2], bv[2], P3A, s3);

  float* P3cur = P3A;
  float* P3nxt = P3B;
  const float* st3 = s3;

  // ---- unfolding
  for (int u = 0; u < 3; ++u) {
    bwd_fused<<<dim3(3, 128), 256, 0, stream>>>(
        P3cur, st3, g1[2], be1[2], F[2], F[1], R2, R1);
    float* sA = SS + (4 + 3 * u) * SLOTSZ;
    fwd_fused<16><<<dim3(3, 128), 256, 0, stream>>>(
        R1, nullptr, nullptr, nullptr, 0,
        P0, SS, bn0_g, bn0_b, 0,
        F[0], cs[0], bv[0], P1, sA);
    float* sB = SS + (5 + 3 * u) * SLOTSZ;
    fwd_fused<48><<<dim3(3, 128), 256, 0, stream>>>(
        R2, nullptr, nullptr, nullptr, 0,
        P1, sA, g1[0], be1[0], 1,
        F[1], cs[1], bv[1], P2, sB);
    float* sC = SS + (6 + 3 * u) * SLOTSZ;
    fwd_fused<80><<<dim3(3, 128), 256, 0, stream>>>(
        P3cur, st3, g1[2], be1[2], 1,
        P2, sB, g1[1], be1[1], 1,
        F[2], cs[2], bv[2], P3nxt, sC);
    st3 = sC;
    float* tmp = P3cur; P3cur = P3nxt; P3nxt = tmp;
  }

  // ---- eSE (parallel mean; act fused into zb_pack)
  ese_mean_part<<<dim3(8, 128), 256, 0, stream>>>(P3cur, st3, g1[2], be1[2], smP);

  // ---- fc1 (bf16 MFMA split-K) + fc2 + log_softmax (red fused)
  wb_pack<<<(int)(((size_t)128 * FC1K / 8 + 255) / 256), 256, 0, stream>>>(fc1_w, wb);
  zb_pack<<<dim3(5, 128), 256, 0, stream>>>(P3cur, st3, g1[2], be1[2], smP, ese_w, ese_b, zb);
  fc1_mfma<<<NKBLK, 256, 0, stream>>>(zb, wb, parts);
  fc2_lsm<<<128, 128, 0, stream>>>(parts, fc1_b, fc2_w, fc2_b, (float*)d_out);
}